// Round 6
// baseline (1141.123 us; speedup 1.0000x reference)
//
#include <hip/hip_runtime.h>

// ============================================================================
// SignLLM forward, fp32. B=4, T=32 -> nc=16 clips, D=512.
// Output: d_out[0..31] = widx (4,8) as float, d_out[32] = total loss.
// R16: conv2/conv3 inner loop gets explicit register prefetch. Evidence:
// conv3 VALUBusy 49%, occupancy 22% (grid-capped at 2 waves/SIMD - total
// waves = outputs/thread-tile = 8/CU, unchangeable without worsening the
// FMA:LDS ratio), VGPR=52 -> compiler interleaves each ds_read_b128 weight
// load with dependent FMAs (serialized ~120cyc lgkmcnt stalls). At 2
// waves/SIMD the VGPR budget is free to 256 -> load all 9 weight float4s
// into registers up front + #pragma unroll 2 on the c-loop so c+1's loads
// issue under c's 288 FMAs. Loads only - FP accumulation order unchanged,
// outputs bit-identical. GRU pipeline = R15 (1118us, -63 vs R13).
// Zero atomics anywhere (deterministic).
// ============================================================================

// ---- workspace layout (float offsets), peak ~12.62M floats = 50.5 MB ----
static const size_t OFF_X1P  = 0;         // (64,64,32,32)  4,194,304  [dead after conv2]
static const size_t OFF_Y2   = 4194304;   // (64,128,32,32) 8,388,608  -> ends 12,582,912
static const size_t OFF_X2P  = 0;         // (64,128,16,16) 2,097,152  [x1p dead]
static const size_t OFF_Y3   = 4194304;   // (64,256,16,16) 4,194,304  [y2 dead]
static const size_t OFF_X3P  = 2097152;   // 262,144
static const size_t OFF_Y4   = 2359296;   // 262,144
static const size_t OFF_X4   = 2621440;   // 262,144
static const size_t OFF_FEAT = 2883584;   // (64,512) 32,768
static const size_t OFF_QUANT= 2916352;   // 32,768
static const size_t OFF_GI1  = 2949120;   // (64,1536) 98,304 (rows b*16+t)
static const size_t OFF_GI2  = 3047424;   // 98,304
static const size_t OFF_H1   = 3145728;   // (64,512) rows b*16+t
static const size_t OFF_H2   = 3178496;   // 32,768
static const size_t OFF_WEMB = 3211264;   // (32,512) 16,384
static const size_t OFF_CTX  = 3227648;   // 2,048
static const size_t OFF_HH1  = 3229696;   // 2,048
static const size_t OFF_HH2  = 3231744;   // 4,096
static const size_t OFF_LOG  = 3235840;   // 12,000 -> ends 3,247,840
static const size_t OFF_PP   = 3247840;   // proj partials (8,64,512) 262,144
// long-lived block PAST y2's end (12,582,912):
static const size_t OFF_SC    = 12582912; // 4,096
static const size_t OFF_SH    = 12587008; // 4,096
static const size_t OFF_ACCP  = 12591104; // 32,768: conv1 stats (s:16384, q:16384)
static const size_t OFF_COMMIT= 12623872; // 64
static const size_t OFF_CTXA  = 12623936; // 120
static const size_t OFF_ALIGNA= 12624056; // 32

// ============================================================================
// conv1 (IC=3, 64x64, pad 1, mid temporal slice). Block = (ocg, rq, n),
// 256 thr = 2x2px x 16oc. Deterministic per-(c,oc,b,rq) stats partials.
// ============================================================================
__global__ __launch_bounds__(256) void k_conv1_stats3(
        const float* __restrict__ videos, const float* __restrict__ w1,
        const float* __restrict__ b1, float* __restrict__ accP) {
    __shared__ float sP[3 * 18 * 66];
    __shared__ float wsm[3 * 9 * 16];
    __shared__ float sRed[4][16], qRed[4][16];
    int oc0 = blockIdx.x * 16, rq = blockIdx.y, n = blockIdx.z;
    int c = n >> 2, b = n & 3;
    int tid = threadIdx.x;
    int rp = tid >> 5, cq = tid & 31;
    for (int e = tid; e < 3564; e += 256) {
        int ic = e / 1188, rem = e % 1188;
        int r = rem / 66, col = rem % 66;
        int gr = rq * 16 - 1 + r, gc = col - 1;
        float v = 0.f;
        if (gr >= 0 && gr < 64 && gc >= 0 && gc < 64)
            v = videos[((size_t)(b * 3 + ic) * 32 + 2 * c) * 4096 + gr * 64 + gc];
        sP[e] = v;
    }
    for (int e = tid; e < 432; e += 256) {
        int ic = e / 144, rem = e % 144, k = rem / 16, j = rem % 16;
        wsm[e] = w1[((size_t)((oc0 + j) * 3 + ic) * 3 + 1) * 9 + k];
    }
    __syncthreads();
    float acc[4][16];
#pragma unroll
    for (int p = 0; p < 4; ++p)
#pragma unroll
        for (int j = 0; j < 16; ++j) acc[p][j] = 0.f;
#pragma unroll
    for (int ic = 0; ic < 3; ++ic) {
        const float* base = &sP[ic * 1188 + (2 * rp) * 66 + 2 * cq];
        float patch[4][4];
#pragma unroll
        for (int r = 0; r < 4; ++r)
#pragma unroll
            for (int q = 0; q < 4; ++q) patch[r][q] = base[r * 66 + q];
#pragma unroll
        for (int k = 0; k < 9; ++k) {
            int kr = k / 3, kc = k % 3;
            float4 w0 = *(const float4*)&wsm[(ic * 9 + k) * 16 + 0];
            float4 w1v = *(const float4*)&wsm[(ic * 9 + k) * 16 + 4];
            float4 w2 = *(const float4*)&wsm[(ic * 9 + k) * 16 + 8];
            float4 w3 = *(const float4*)&wsm[(ic * 9 + k) * 16 + 12];
#pragma unroll
            for (int p = 0; p < 4; ++p) {
                float vv = patch[(p >> 1) + kr][(p & 1) + kc];
                acc[p][0]  += vv * w0.x; acc[p][1]  += vv * w0.y;
                acc[p][2]  += vv * w0.z; acc[p][3]  += vv * w0.w;
                acc[p][4]  += vv * w1v.x; acc[p][5]  += vv * w1v.y;
                acc[p][6]  += vv * w1v.z; acc[p][7]  += vv * w1v.w;
                acc[p][8]  += vv * w2.x; acc[p][9]  += vv * w2.y;
                acc[p][10] += vv * w2.z; acc[p][11] += vv * w2.w;
                acc[p][12] += vv * w3.x; acc[p][13] += vv * w3.y;
                acc[p][14] += vv * w3.z; acc[p][15] += vv * w3.w;
            }
        }
    }
    int lane = tid & 63, wave = tid >> 6;
#pragma unroll
    for (int j = 0; j < 16; ++j) {
        float bj = b1[oc0 + j];
        float s = 0.f, q = 0.f;
#pragma unroll
        for (int p = 0; p < 4; ++p) {
            float a = acc[p][j] + bj;
            s += a; q += a * a;
        }
#pragma unroll
        for (int m = 1; m < 64; m <<= 1) {
            s += __shfl_xor(s, m);
            q += __shfl_xor(q, m);
        }
        if (lane == 0) { sRed[wave][j] = s; qRed[wave][j] = q; }
    }
    __syncthreads();
    if (tid < 16) {
        float s = ((sRed[0][tid] + sRed[1][tid]) + (sRed[2][tid] + sRed[3][tid]));
        float q = ((qRed[0][tid] + qRed[1][tid]) + (qRed[2][tid] + qRed[3][tid]));
        int oc = oc0 + tid;
        size_t slot = (((size_t)(c * 64 + oc)) * 4 + b) * 4 + rq;
        accP[slot] = s;
        accP[16384 + slot] = q;
    }
}

__global__ void k_conv1_fin(const float* __restrict__ accP, const float* __restrict__ g1,
                            const float* __restrict__ be1, float* __restrict__ sc,
                            float* __restrict__ sh) {
    int e = blockIdx.x * 256 + threadIdx.x;
    if (e >= 1024) return;
    int oc = e & 63;
    const float* ps = accP + (size_t)e * 16;
    const float* pq = accP + 16384 + (size_t)e * 16;
    float s = 0.f, q = 0.f;
#pragma unroll
    for (int i = 0; i < 16; ++i) { s += ps[i]; q += pq[i]; }
    float m = s * (1.f / 16384.f);
    float var = q * (1.f / 16384.f) - m * m;
    float sf = g1[oc] * rsqrtf(var + 1e-5f);
    sc[e] = sf;
    sh[e] = be1[oc] - m * sf;
}

__global__ __launch_bounds__(256) void k_conv1_apply3(
        const float* __restrict__ videos, const float* __restrict__ w1,
        const float* __restrict__ b1, const float* __restrict__ sc,
        const float* __restrict__ sh, float* __restrict__ x1p) {
    __shared__ float sP[3 * 18 * 66];
    __shared__ float wsm[3 * 9 * 16];
    int oc0 = blockIdx.x * 16, rq = blockIdx.y, n = blockIdx.z;
    int c = n >> 2, b = n & 3;
    int tid = threadIdx.x;
    int rp = tid >> 5, cq = tid & 31;
    for (int e = tid; e < 3564; e += 256) {
        int ic = e / 1188, rem = e % 1188;
        int r = rem / 66, col = rem % 66;
        int gr = rq * 16 - 1 + r, gc = col - 1;
        float v = 0.f;
        if (gr >= 0 && gr < 64 && gc >= 0 && gc < 64)
            v = videos[((size_t)(b * 3 + ic) * 32 + 2 * c) * 4096 + gr * 64 + gc];
        sP[e] = v;
    }
    for (int e = tid; e < 432; e += 256) {
        int ic = e / 144, rem = e % 144, k = rem / 16, j = rem % 16;
        wsm[e] = w1[((size_t)((oc0 + j) * 3 + ic) * 3 + 1) * 9 + k];
    }
    __syncthreads();
    float acc[4][16];
#pragma unroll
    for (int p = 0; p < 4; ++p)
#pragma unroll
        for (int j = 0; j < 16; ++j) acc[p][j] = 0.f;
#pragma unroll
    for (int ic = 0; ic < 3; ++ic) {
        const float* base = &sP[ic * 1188 + (2 * rp) * 66 + 2 * cq];
        float patch[4][4];
#pragma unroll
        for (int r = 0; r < 4; ++r)
#pragma unroll
            for (int q = 0; q < 4; ++q) patch[r][q] = base[r * 66 + q];
#pragma unroll
        for (int k = 0; k < 9; ++k) {
            int kr = k / 3, kc = k % 3;
            float4 w0 = *(const float4*)&wsm[(ic * 9 + k) * 16 + 0];
            float4 w1v = *(const float4*)&wsm[(ic * 9 + k) * 16 + 4];
            float4 w2 = *(const float4*)&wsm[(ic * 9 + k) * 16 + 8];
            float4 w3 = *(const float4*)&wsm[(ic * 9 + k) * 16 + 12];
#pragma unroll
            for (int p = 0; p < 4; ++p) {
                float vv = patch[(p >> 1) + kr][(p & 1) + kc];
                acc[p][0]  += vv * w0.x; acc[p][1]  += vv * w0.y;
                acc[p][2]  += vv * w0.z; acc[p][3]  += vv * w0.w;
                acc[p][4]  += vv * w1v.x; acc[p][5]  += vv * w1v.y;
                acc[p][6]  += vv * w1v.z; acc[p][7]  += vv * w1v.w;
                acc[p][8]  += vv * w2.x; acc[p][9]  += vv * w2.y;
                acc[p][10] += vv * w2.z; acc[p][11] += vv * w2.w;
                acc[p][12] += vv * w3.x; acc[p][13] += vv * w3.y;
                acc[p][14] += vv * w3.z; acc[p][15] += vv * w3.w;
            }
        }
    }
#pragma unroll
    for (int j = 0; j < 16; ++j) {
        int oc = oc0 + j;
        float bj = b1[oc];
        float scj = sc[c * 64 + oc], shj = sh[c * 64 + oc];
        float m = -1e30f;
#pragma unroll
        for (int p = 0; p < 4; ++p) m = fmaxf(m, (acc[p][j] + bj) * scj + shj);
        x1p[((size_t)n * 64 + oc) * 1024 + (rq * 8 + rp) * 32 + cq] = fmaxf(m, 0.f);
    }
}

// ============================================================================
// conv2: IC=64, 32x32, OC=128. Block = 32 oc x 8-row slab x 1 clip.
// grid (4 ocg, 4 slab, 64 n) = 1024 blocks. Thread = 4 oc x (2x4 px).
// R16: explicit weight-register prefetch + unroll-2 c-loop (loads only;
// FP accumulation order identical).
// ============================================================================
__global__ __launch_bounds__(256) void k_conv2(
        const float* __restrict__ in, const float* __restrict__ wt,
        const float* __restrict__ bias, float* __restrict__ out) {
    __shared__ __align__(16) float sIn[8 * 10 * 36];   // 2880
    __shared__ __align__(16) float sW[8 * 9 * 32];     // 2304
    int oc0 = blockIdx.x * 32, r0 = blockIdx.y * 8, n = blockIdx.z;
    int tid = threadIdx.x;
    int ocq = tid >> 5;          // 0..7
    int rg = (tid >> 3) & 3;     // rows r0+2rg, r0+2rg+1
    int cg = tid & 7;            // cols 4cg..4cg+3
    float acc[4][8];
#pragma unroll
    for (int j = 0; j < 4; ++j)
#pragma unroll
        for (int p = 0; p < 8; ++p) acc[j][p] = 0.f;

    for (int ic0 = 0; ic0 < 64; ic0 += 8) {
        __syncthreads();
        for (int e = tid; e < 2720; e += 256) {      // 8 ch x 10 rows x 34 cols
            int ch = e / 340, rem = e % 340;
            int r = rem / 34, col = rem % 34;
            int gr = r0 - 1 + r, gc = col - 1;
            float v = 0.f;
            if (gr >= 0 && gr < 32 && gc >= 0 && gc < 32)
                v = in[((size_t)(n * 64 + ic0 + ch) * 32 + gr) * 32 + gc];
            sIn[ch * 360 + r * 36 + col] = v;
        }
        for (int e = tid; e < 2304; e += 256) {
            int c = e / 288, r1 = e % 288, k = r1 / 32, j = r1 % 32;
            sW[e] = wt[((size_t)(oc0 + j) * 64 + ic0 + c) * 27 + 9 + k];
        }
        __syncthreads();
#pragma unroll 2
        for (int c = 0; c < 8; ++c) {
            const float* base = &sIn[c * 360 + (2 * rg) * 36 + 4 * cg];
            float patch[4][6];
#pragma unroll
            for (int r = 0; r < 4; ++r) {
                float4 p4 = *(const float4*)&base[r * 36];
                float2 p2 = *(const float2*)&base[r * 36 + 4];
                patch[r][0] = p4.x; patch[r][1] = p4.y; patch[r][2] = p4.z;
                patch[r][3] = p4.w; patch[r][4] = p2.x; patch[r][5] = p2.y;
            }
            float4 wv[9];
#pragma unroll
            for (int k = 0; k < 9; ++k)
                wv[k] = *(const float4*)&sW[c * 288 + k * 32 + ocq * 4];
#pragma unroll
            for (int k = 0; k < 9; ++k) {
                int kr = k / 3, kc = k % 3;
                float4 w4 = wv[k];
#pragma unroll
                for (int p = 0; p < 8; ++p) {
                    int pr = p >> 2, pcq = p & 3;
                    float vv = patch[pr + kr][pcq + kc];
                    acc[0][p] += vv * w4.x; acc[1][p] += vv * w4.y;
                    acc[2][p] += vv * w4.z; acc[3][p] += vv * w4.w;
                }
            }
        }
    }
#pragma unroll
    for (int j = 0; j < 4; ++j) {
        int oc = oc0 + ocq * 4 + j;
        float bj = bias[oc];
#pragma unroll
        for (int pr = 0; pr < 2; ++pr) {
            float4 o4 = make_float4(acc[j][pr * 4 + 0] + bj, acc[j][pr * 4 + 1] + bj,
                                    acc[j][pr * 4 + 2] + bj, acc[j][pr * 4 + 3] + bj);
            *(float4*)&out[((size_t)(n * 128 + oc) * 32 + r0 + 2 * rg + pr) * 32 + 4 * cg] = o4;
        }
    }
}

// ============================================================================
// conv3: IC=128, 16x16, OC=256. Block = 32 oc x full plane x 1 clip,
// grid (8 ocg, 64 n). Thread = 4 oc x (2x4 px). Halo stride 20.
// R16: explicit weight-register prefetch + unroll-2 c-loop.
// ============================================================================
__global__ __launch_bounds__(256) void k_conv3k(
        const float* __restrict__ in, const float* __restrict__ wt,
        const float* __restrict__ bias, float* __restrict__ out) {
    __shared__ __align__(16) float sIn[8 * 18 * 20];   // 2880
    __shared__ __align__(16) float sW[8 * 9 * 32];     // 2304
    int oc0 = blockIdx.x * 32, n = blockIdx.y;
    int tid = threadIdx.x;
    int ocq = tid >> 5;          // 0..7
    int rg = (tid >> 2) & 7;     // rows 2rg, 2rg+1
    int cg = tid & 3;            // cols 4cg..4cg+3
    float acc[4][8];
#pragma unroll
    for (int j = 0; j < 4; ++j)
#pragma unroll
        for (int p = 0; p < 8; ++p) acc[j][p] = 0.f;

    for (int ic0 = 0; ic0 < 128; ic0 += 8) {
        __syncthreads();
        for (int e = tid; e < 2592; e += 256) {      // 8 ch x 18 rows x 18 cols
            int ch = e / 324, rem = e % 324;
            int r = rem / 18, cc = rem % 18;
            int gr = r - 1, gc = cc - 1;
            float v = 0.f;
            if (gr >= 0 && gr < 16 && gc >= 0 && gc < 16)
                v = in[((size_t)(n * 128 + ic0 + ch) * 16 + gr) * 16 + gc];
            sIn[ch * 360 + r * 20 + cc] = v;
        }
        for (int e = tid; e < 2304; e += 256) {
            int c = e / 288, r1 = e % 288, k = r1 / 32, j = r1 % 32;
            sW[e] = wt[((size_t)(oc0 + j) * 128 + ic0 + c) * 27 + 9 + k];
        }
        __syncthreads();
#pragma unroll 2
        for (int c = 0; c < 8; ++c) {
            const float* base = &sIn[c * 360 + (2 * rg) * 20 + 4 * cg];
            float patch[4][6];
#pragma unroll
            for (int r = 0; r < 4; ++r) {
                float4 p4 = *(const float4*)&base[r * 20];
                float2 p2 = *(const float2*)&base[r * 20 + 4];
                patch[r][0] = p4.x; patch[r][1] = p4.y; patch[r][2] = p4.z;
                patch[r][3] = p4.w; patch[r][4] = p2.x; patch[r][5] = p2.y;
            }
            float4 wv[9];
#pragma unroll
            for (int k = 0; k < 9; ++k)
                wv[k] = *(const float4*)&sW[c * 288 + k * 32 + ocq * 4];
#pragma unroll
            for (int k = 0; k < 9; ++k) {
                int kr = k / 3, kc = k % 3;
                float4 w4 = wv[k];
#pragma unroll
                for (int p = 0; p < 8; ++p) {
                    int pr = p >> 2, pcq = p & 3;
                    float vv = patch[pr + kr][pcq + kc];
                    acc[0][p] += vv * w4.x; acc[1][p] += vv * w4.y;
                    acc[2][p] += vv * w4.z; acc[3][p] += vv * w4.w;
                }
            }
        }
    }
#pragma unroll
    for (int j = 0; j < 4; ++j) {
        int oc = oc0 + ocq * 4 + j;
        float bj = bias[oc];
#pragma unroll
        for (int pr = 0; pr < 2; ++pr) {
            float4 o4 = make_float4(acc[j][pr * 4 + 0] + bj, acc[j][pr * 4 + 1] + bj,
                                    acc[j][pr * 4 + 2] + bj, acc[j][pr * 4 + 3] + bj);
            *(float4*)&out[((size_t)(n * 256 + oc) * 16 + 2 * rg + pr) * 16 + 4 * cg] = o4;
        }
    }
}

// per-(clip,channel) BN stats
__global__ void k_bn_stats(const float* __restrict__ buf, const float* __restrict__ g,
                           const float* __restrict__ be, float* __restrict__ scale,
                           float* __restrict__ shift, int C, int HW) {
    int c = blockIdx.x, ch = blockIdx.y, tid = threadIdx.x;
    float s = 0.f, s2 = 0.f;
    for (int b = 0; b < 4; ++b) {
        const float* p = buf + ((size_t)(c * 4 + b) * C + ch) * HW;
        for (int i = tid; i < HW; i += 256) { float v = p[i]; s += v; s2 += v * v; }
    }
    __shared__ float rs[256], rq[256];
    rs[tid] = s; rq[tid] = s2; __syncthreads();
    for (int k = 128; k > 0; k >>= 1) {
        if (tid < k) { rs[tid] += rs[tid + k]; rq[tid] += rq[tid + k]; }
        __syncthreads();
    }
    if (tid == 0) {
        float inv = 1.f / (float)(4 * HW);
        float m = rs[0] * inv, var = rq[0] * inv - m * m;
        float sc = g[ch] * rsqrtf(var + 1e-5f);
        scale[c * C + ch] = sc;
        shift[c * C + ch] = be[ch] - m * sc;
    }
}

__global__ void k_bn_apply_pool(const float* __restrict__ in, const float* __restrict__ scale,
                                const float* __restrict__ shift, float* __restrict__ out,
                                int C, int H, int W) {
    int OH = H >> 1, OW = W >> 1;
    size_t idx = (size_t)blockIdx.x * 256 + threadIdx.x;
    int ow = (int)(idx % OW);
    size_t r = idx / OW;
    int oh = (int)(r % OH); r /= OH;
    int ch = (int)(r % C);
    int n = (int)(r / C);
    int c = n >> 2;
    float sc = scale[c * C + ch], sh = shift[c * C + ch];
    const float* p = in + (((size_t)n * C + ch) * H + 2 * oh) * W + 2 * ow;
    float m = 0.f;
    m = fmaxf(m, p[0] * sc + sh);
    m = fmaxf(m, p[1] * sc + sh);
    m = fmaxf(m, p[W] * sc + sh);
    m = fmaxf(m, p[W + 1] * sc + sh);
    out[idx] = m;
}

// ---- post-conv3 chain ----
__global__ void k_bn_apply_avgpool4(const float* __restrict__ in, const float* __restrict__ scale,
                                    const float* __restrict__ shift, float* __restrict__ out) {
    size_t idx = (size_t)blockIdx.x * 256 + threadIdx.x;  // 262,144
    int j = (int)(idx & 3), i = (int)(idx >> 2) & 3;
    int ch = (int)(idx >> 4) & 255, n = (int)(idx >> 12);
    int c = n >> 2;
    float sc = scale[c * 256 + ch], sh = shift[c * 256 + ch];
    const float* p = in + (((size_t)n * 256 + ch) * 16 + i * 4) * 16 + j * 4;
    float s = 0.f;
#pragma unroll
    for (int r = 0; r < 4; ++r)
#pragma unroll
        for (int q = 0; q < 4; ++q) s += fmaxf(p[r * 16 + q] * sc + sh, 0.f);
    out[idx] = s * (1.f / 16.f);
}

__global__ void k_tconv(const float* __restrict__ x3p, const float* __restrict__ tw,
                        const float* __restrict__ tb, float* __restrict__ y4) {
    size_t idx = (size_t)blockIdx.x * 256 + threadIdx.x;  // 262,144
    int p = (int)(idx & 15), o = (int)(idx >> 4) & 255, n = (int)(idx >> 12);
    const float* xr = x3p + (size_t)n * 4096 + p;
    float a = tb[o];
    for (int i = 0; i < 256; ++i) a += xr[i * 16] * tw[((size_t)o * 256 + i) * 3 + 1];
    y4[idx] = a;
}

__global__ void k_bn_apply(const float* __restrict__ in, const float* __restrict__ scale,
                           const float* __restrict__ shift, float* __restrict__ out) {
    size_t idx = (size_t)blockIdx.x * 256 + threadIdx.x;  // 262,144
    int ch = (int)(idx >> 4) & 255, n = (int)(idx >> 12);
    int c = n >> 2;
    float sc = scale[c * 256 + ch], sh = shift[c * 256 + ch];
    out[idx] = fmaxf(in[idx] * sc + sh, 0.f);
}

// ============================================================================
// proj as deterministic split-K GEMM with row permutation in fin.
// ============================================================================
__global__ __launch_bounds__(256) void k_proj_part(
        const float* __restrict__ A, const float* __restrict__ B, float* __restrict__ PP) {
    __shared__ __align__(16) float As[64 * 68];
    __shared__ __align__(16) float Bs[64 * 68];
    int n0 = blockIdx.x * 64, ks = blockIdx.y;
    int tid = threadIdx.x, tm = tid >> 4, tn = tid & 15;
    float acc[4][4];
#pragma unroll
    for (int i = 0; i < 4; ++i)
#pragma unroll
        for (int j = 0; j < 4; ++j) acc[i][j] = 0.f;
    int kb = ks * 512;
    for (int k0 = kb; k0 < kb + 512; k0 += 64) {
        __syncthreads();
        for (int e = tid; e < 4096; e += 256) {
            int m = e >> 6, k = e & 63;
            As[k * 68 + m] = A[(size_t)m * 4096 + k0 + k];
            Bs[k * 68 + m] = B[(size_t)(n0 + m) * 4096 + k0 + k];
        }
        __syncthreads();
        for (int k = 0; k < 64; ++k) {
            float4 a4 = *(const float4*)&As[k * 68 + tm * 4];
            float4 b4 = *(const float4*)&Bs[k * 68 + tn * 4];
            acc[0][0] += a4.x * b4.x; acc[0][1] += a4.x * b4.y;
            acc[0][2] += a4.x * b4.z; acc[0][3] += a4.x * b4.w;
            acc[1][0] += a4.y * b4.x; acc[1][1] += a4.y * b4.y;
            acc[1][2] += a4.y * b4.z; acc[1][3] += a4.y * b4.w;
            acc[2][0] += a4.z * b4.x; acc[2][1] += a4.z * b4.y;
            acc[2][2] += a4.z * b4.z; acc[2][3] += a4.z * b4.w;
            acc[3][0] += a4.w * b4.x; acc[3][1] += a4.w * b4.y;
            acc[3][2] += a4.w * b4.z; acc[3][3] += a4.w * b4.w;
        }
    }
#pragma unroll
    for (int i = 0; i < 4; ++i)
#pragma unroll
        for (int j = 0; j < 4; ++j)
            PP[((size_t)(ks * 64 + tm * 4 + i)) * 512 + n0 + tn * 4 + j] = acc[i][j];
}

__global__ void k_proj_fin(const float* __restrict__ PP, const float* __restrict__ pb,
                           float* __restrict__ feat) {
    int e = blockIdx.x * 256 + threadIdx.x;  // 32768
    int n = e & 511;
    int m = e >> 9;               // x4 row (clip-major): m = c*4 + b
    float s = pb[n];
#pragma unroll
    for (int ks = 0; ks < 8; ++ks) s += PP[(size_t)ks * 32768 + e];
    int c = m >> 2, b = m & 3;
    int ro = b * 16 + c;          // feat row (batch-major)
    feat[(size_t)ro * 512 + n] = s;
}

// VQ argmin; min distance -> commitArr[row] (deterministic)
__global__ void k_vq(const float* __restrict__ feat, const float* __restrict__ cb,
                     float* __restrict__ quant, float* __restrict__ commitArr) {
    int row = blockIdx.x, tid = threadIdx.x;
    __shared__ float f[512];
    for (int k = tid; k < 512; k += 256) f[k] = feat[(size_t)row * 512 + k];
    __syncthreads();
    float best = 3.4e38f; int bidx = 0;
    for (int j = tid; j < 1024; j += 256) {
        const float* c = cb + (size_t)j * 512;
        float d2 = 0.f;
        for (int k = 0; k < 512; ++k) { float t = f[k] - c[k]; d2 += t * t; }
        if (d2 < best) { best = d2; bidx = j; }
    }
    __shared__ float rd[256]; __shared__ int ri[256];
    rd[tid] = best; ri[tid] = bidx; __syncthreads();
    for (int k = 128; k > 0; k >>= 1) {
        if (tid < k) {
            float od = rd[tid + k]; int oi = ri[tid + k];
            if (od < rd[tid] || (od == rd[tid] && oi < ri[tid])) { rd[tid] = od; ri[tid] = oi; }
        }
        __syncthreads();
    }
    __shared__ int wsel;
    if (tid == 0) { wsel = ri[0]; commitArr[row] = rd[0]; }
    __syncthreads();
    const float* c = cb + (size_t)wsel * 512;
    for (int k = tid; k < 512; k += 256) quant[(size_t)row * 512 + k] = c[k];
}

// ---- GRU helpers -----------------------------------------------------------
// Single-dim gi: gi[row*1536+d] = wih[d]·x + bih[d], exact k_gru_gi order.
__device__ __forceinline__ void gru_gi_one(
        const float* __restrict__ xsRow, const float* __restrict__ wih,
        const float* __restrict__ bih, float* __restrict__ gi, int row, int d) {
    const float4* xp = (const float4*)xsRow;
    const float4* wr = (const float4*)(wih + (size_t)d * 512);
    float a0 = 0.f, a1 = 0.f, a2 = 0.f, a3 = 0.f;
    for (int i = 0; i < 128; i += 4) {
        float4 w0 = wr[i], w1 = wr[i + 1], w2 = wr[i + 2], w3 = wr[i + 3];
        float4 x0 = xp[i], x1 = xp[i + 1], x2 = xp[i + 2], x3 = xp[i + 3];
        a0 += w0.x * x0.x + w0.y * x0.y + w0.z * x0.z + w0.w * x0.w;
        a1 += w1.x * x1.x + w1.y * x1.y + w1.z * x1.z + w1.w * x1.w;
        a2 += w2.x * x2.x + w2.y * x2.y + w2.z * x2.z + w2.w * x2.w;
        a3 += w3.x * x3.x + w3.y * x3.y + w3.z * x3.z + w3.w * x3.w;
    }
    gi[(size_t)row * 1536 + d] = (a0 + a1) + (a2 + a3) + bih[d];
}

// One GRU step for 4 h-dims (blk selects the dim group), exact k_gru_step2.
__device__ __forceinline__ void gru_step_body(
        const float* __restrict__ gi, const float* __restrict__ whh,
        const float* __restrict__ bhh, float* __restrict__ hseq, int t, int blk) {
    int wv = threadIdx.x >> 6, lane = threadIdx.x & 63;
    int d = blk * 4 + wv;
    const float4* w0p = (const float4*)(whh + (size_t)d * 512);
    const float4* w1p = (const float4*)(whh + (size_t)(512 + d) * 512);
    const float4* w2p = (const float4*)(whh + (size_t)(1024 + d) * 512);
    float4 w0a = w0p[lane * 2], w0b = w0p[lane * 2 + 1];
    float4 w1a = w1p[lane * 2], w1b = w1p[lane * 2 + 1];
    float4 w2a = w2p[lane * 2], w2b = w2p[lane * 2 + 1];
    float bh0 = bhh[d], bh1 = bhh[512 + d], bh2 = bhh[1024 + d];
    for (int b = 0; b < 4; ++b) {
        float4 ha = make_float4(0, 0, 0, 0), hb = ha;
        float hpd = 0.f;
        if (t > 0) {
            const float4* hp = (const float4*)(hseq + (size_t)(b * 16 + t - 1) * 512);
            ha = hp[lane * 2]; hb = hp[lane * 2 + 1];
            hpd = hseq[(size_t)(b * 16 + t - 1) * 512 + d];
        }
        float s0 = w0a.x * ha.x + w0a.y * ha.y + w0a.z * ha.z + w0a.w * ha.w
                 + w0b.x * hb.x + w0b.y * hb.y + w0b.z * hb.z + w0b.w * hb.w;
        float s1 = w1a.x * ha.x + w1a.y * ha.y + w1a.z * ha.z + w1a.w * ha.w
                 + w1b.x * hb.x + w1b.y * hb.y + w1b.z * hb.z + w1b.w * hb.w;
        float s2 = w2a.x * ha.x + w2a.y * ha.y + w2a.z * ha.z + w2a.w * ha.w
                 + w2b.x * hb.x + w2b.y * hb.y + w2b.z * hb.z + w2b.w * hb.w;
#pragma unroll
        for (int m = 1; m < 64; m <<= 1) {
            s0 += __shfl_xor(s0, m);
            s1 += __shfl_xor(s1, m);
            s2 += __shfl_xor(s2, m);
        }
        const float* gr = gi + (size_t)(b * 16 + t) * 1536;
        float rr = 1.f / (1.f + expf(-(gr[d] + s0 + bh0)));
        float zz = 1.f / (1.f + expf(-(gr[512 + d] + s1 + bh1)));
        float nn = tanhf(gr[1024 + d] + rr * (s2 + bh2));
        if (lane == 0)
            hseq[(size_t)(b * 16 + t) * 512 + d] = (1.f - zz) * nn + zz * hpd;
    }
}

// Layer-1 gi, spread: grid 360 = 60 rows x 6 parts, 1 dim/thread.
__global__ void k_gru_gi6(const float* __restrict__ x, const float* __restrict__ wih,
                          const float* __restrict__ bih, float* __restrict__ gi) {
    int g = blockIdx.x;
    int r = g / 6, part = g % 6;
    int b = r / 15, t = r % 15;
    int row = b * 16 + t;
    __shared__ float xsRow[512];
    for (int k = threadIdx.x; k < 512; k += 256) xsRow[k] = x[(size_t)row * 512 + k];
    __syncthreads();
    gru_gi_one(xsRow, wih, bih, gi, row, part * 256 + threadIdx.x);
}

// ============================================================================
// GRU pipeline launch t = 0..16 (17 launches replace 30 steps + gi2 kernel):
//   blocks   0..127 : layer-1 step t        (t in [0,14])
//   blocks 128..255 : layer-2 step t-2      (t in [2,16])
//   blocks 256..279 : gi2 rows for time t-1 (t in [1,15]); 6 blocks x 256
//                     dims per batch row, x = h1[t-1] (written last launch).
// All sections touch disjoint rows -> no intra-launch dependency.
// ============================================================================
__global__ __launch_bounds__(256) void k_gru_pipe(
        const float* __restrict__ gi1, const float* __restrict__ whh0,
        const float* __restrict__ bhh0, float* __restrict__ h1,
        const float* __restrict__ wih1, const float* __restrict__ bih1,
        float* __restrict__ gi2, const float* __restrict__ whh1,
        const float* __restrict__ bhh1, float* __restrict__ h2, int t) {
    int bid = blockIdx.x;
    if (bid < 128) {
        if (t < 15) gru_step_body(gi1, whh0, bhh0, h1, t, bid);
    } else if (bid < 256) {
        if (t >= 2) gru_step_body(gi2, whh1, bhh1, h2, t - 2, bid - 128);
    } else {
        if (t >= 1 && t <= 15) {
            int local = bid - 256;          // 0..23
            int b = local / 6, part = local % 6;
            int row = b * 16 + (t - 1);
            __shared__ float xsRow[512];
            for (int k = threadIdx.x; k < 512; k += 256)
                xsRow[k] = h1[(size_t)row * 512 + k];
            __syncthreads();
            gru_gi_one(xsRow, wih1, bih1, gi2, row, part * 256 + threadIdx.x);
        }
    }
}

// ctx loss partials -> ctxArr[block] (deterministic)
__global__ void k_ctx_loss(const float* __restrict__ h2, const float* __restrict__ feat,
                           float* __restrict__ ctxArr) {
    int tid = threadIdx.x;
    size_t idx = (size_t)blockIdx.x * 256 + tid;  // 30720
    int d = (int)(idx & 511);
    int rt = (int)(idx >> 9);
    int t = rt % 15, b = rt / 15;
    float diff = h2[(size_t)(b * 16 + t) * 512 + d] - feat[(size_t)(b * 16 + t + 1) * 512 + d];
    float v = diff * diff;
#pragma unroll
    for (int m = 1; m < 64; m <<= 1) v += __shfl_xor(v, m);
    __shared__ float ws[4];
    if ((tid & 63) == 0) ws[tid >> 6] = v;
    __syncthreads();
    if (tid == 0) ctxArr[blockIdx.x] = ((ws[0] + ws[1]) + (ws[2] + ws[3]));
}

__global__ void k_word_vq(const float* __restrict__ quant, const float* __restrict__ wcb,
                          float* __restrict__ wemb, float* __restrict__ out_widx) {
    int row = blockIdx.x;  // b*8+wi
    int b = row >> 3, wi = row & 7;
    int tid = threadIdx.x;
    __shared__ float f[512];
    for (int k = tid; k < 512; k += 256)
        f[k] = 0.5f * (quant[(size_t)(b * 16 + 2 * wi) * 512 + k] +
                       quant[(size_t)(b * 16 + 2 * wi + 1) * 512 + k]);
    __syncthreads();
    const float* cp = wcb + (size_t)tid * 512;
    float d2 = 0.f;
    for (int k = 0; k < 512; ++k) { float t = f[k] - cp[k]; d2 += t * t; }
    __shared__ float rd[256]; __shared__ int ri[256];
    rd[tid] = d2; ri[tid] = tid; __syncthreads();
    for (int k = 128; k > 0; k >>= 1) {
        if (tid < k) {
            float od = rd[tid + k]; int oi = ri[tid + k];
            if (od < rd[tid] || (od == rd[tid] && oi < ri[tid])) { rd[tid] = od; ri[tid] = oi; }
        }
        __syncthreads();
    }
    __shared__ int wsel;
    if (tid == 0) { wsel = ri[0]; out_widx[row] = (float)ri[0]; }
    __syncthreads();
    const float* cb = wcb + (size_t)wsel * 512;
    for (int k = tid; k < 512; k += 256) wemb[(size_t)row * 512 + k] = cb[k];
}

// alignment partials -> alignArr[row] (deterministic)
__global__ void k_align(const float* __restrict__ wemb, const float* __restrict__ aw,
                        const float* __restrict__ ab, float* __restrict__ alignArr) {
    int row = blockIdx.x, tid = threadIdx.x;
    __shared__ float e[512];
    for (int k = tid; k < 512; k += 256) e[k] = wemb[(size_t)row * 512 + k];
    __syncthreads();
    float local = 0.f;
    for (int d = tid; d < 512; d += 256) {
        const float* wr = aw + (size_t)d * 512;
        float a = ab[d] - e[d];
        for (int k = 0; k < 512; ++k) a += e[k] * wr[k];
        local += a * a;
    }
    __shared__ float rs[256];
    rs[tid] = local; __syncthreads();
    for (int k = 128; k > 0; k >>= 1) { if (tid < k) rs[tid] += rs[tid + k]; __syncthreads(); }
    if (tid == 0) alignArr[row] = rs[0];
}

__global__ void k_ctx(const float* __restrict__ wemb, float* __restrict__ ctx) {
    int e = blockIdx.x * 256 + threadIdx.x;  // 2048
    int b = e >> 9, d = e & 511;
    float s = 0.f;
#pragma unroll
    for (int wi = 0; wi < 8; ++wi) s += wemb[(size_t)(b * 8 + wi) * 512 + d];
    ctx[e] = s * 0.125f;
}

// small-M (M=4) GEMV: C[4,N] = A[4,K] @ B[N,K]^T + bias, optional relu.
__global__ void k_smallM(const float* __restrict__ A, const float* __restrict__ B,
                         const float* __restrict__ bias, float* __restrict__ C,
                         int N, int K, int relu) {
    __shared__ float xs[4096];
    int tid = threadIdx.x;
    for (int e = tid; e < 4 * K; e += 256) xs[e] = A[e];
    __syncthreads();
    int r = tid >> 4, kt = tid & 15;
    int n = blockIdx.x * 16 + r;
    float acc[4] = {0, 0, 0, 0};
    if (n < N) {
        int iters = K >> 6;
        for (int i = 0; i < iters; ++i) {
            int k = i * 64 + kt * 4;
            float4 w = *(const float4*)&B[(size_t)n * K + k];
#pragma unroll
            for (int b = 0; b < 4; ++b) {
                float4 x = *(const float4*)&xs[b * K + k];
                acc[b] += w.x * x.x + w.y * x.y + w.z * x.z + w.w * x.w;
            }
        }
    }
#pragma unroll
    for (int b = 0; b < 4; ++b) {
#pragma unroll
        for (int m = 1; m < 16; m <<= 1) acc[b] += __shfl_xor(acc[b], m);
    }
    if (kt == 0 && n < N) {
#pragma unroll
        for (int b = 0; b < 4; ++b) {
            float v = acc[b] + bias[n];
            if (relu) v = fmaxf(v, 0.f);
            C[(size_t)b * N + n] = v;
        }
    }
}

// log-softmax CE + deterministic fixed-order sum of all loss partials
__global__ void k_final(const float* __restrict__ logits, const int* __restrict__ tokens,
                        const float* __restrict__ commitArr, const float* __restrict__ ctxArr,
                        const float* __restrict__ alignArr, float* __restrict__ out_total) {
    int tid = threadIdx.x;
    __shared__ float rs[256];
    __shared__ float sM;
    float tr = 0.f;
    for (int b = 0; b < 4; ++b) {
        const float* lg = logits + (size_t)b * 3000;
        float m = -1e30f;
        for (int d = tid; d < 3000; d += 256) m = fmaxf(m, lg[d]);
        rs[tid] = m; __syncthreads();
        for (int k = 128; k > 0; k >>= 1) { if (tid < k) rs[tid] = fmaxf(rs[tid], rs[tid + k]); __syncthreads(); }
        if (tid == 0) sM = rs[0];
        __syncthreads();
        float M = sM;
        float s = 0.f;
        for (int d = tid; d < 3000; d += 256) s += expf(lg[d] - M);
        rs[tid] = s; __syncthreads();
        for (int k = 128; k > 0; k >>= 1) { if (tid < k) rs[tid] += rs[tid + k]; __syncthreads(); }
        if (tid == 0) {
            int t0 = tokens[b * 10];
            tr += -(lg[t0] - M - logf(rs[0]));
        }
        __syncthreads();
    }
    if (tid == 0) {
        float c0 = 0.f;
        for (int i = 0; i < 64; ++i) c0 += commitArr[i];
        float c1 = 0.f;
        for (int i = 0; i < 120; ++i) c1 += ctxArr[i];
        float c2 = 0.f;
        for (int i = 0; i < 32; ++i) c2 += alignArr[i];
        float total = 1.25f * c0 * (1.f / 32768.f)
                    + 0.1f  * c1 * (1.f / 30720.f)
                    + 0.1f  * c2 * (1.f / 16384.f)
                    + tr;
        *out_total = total;
    }
}

extern "C" void kernel_launch(void* const* d_in, const int* in_sizes, int n_in,
                              void* d_out, int out_size, void* d_ws, size_t ws_size,
                              hipStream_t stream) {
    (void)in_sizes; (void)n_in; (void)out_size; (void)ws_size;
    const float* videos   = (const float*)d_in[0];
    const float* conv1_w  = (const float*)d_in[1];
    const float* conv1_b  = (const float*)d_in[2];
    const float* bn1_g    = (const float*)d_in[3];
    const float* bn1_b    = (const float*)d_in[4];
    const float* conv2_w  = (const float*)d_in[5];
    const float* conv2_b  = (const float*)d_in[6];
    const float* bn2_g    = (const float*)d_in[7];
    const float* bn2_b    = (const float*)d_in[8];
    const float* conv3_w  = (const float*)d_in[9];
    const float* conv3_b  = (const float*)d_in[10];
    const float* bn3_g    = (const float*)d_in[11];
    const float* bn3_b    = (const float*)d_in[12];
    const float* tconv_w  = (const float*)d_in[13];
    const float* tconv_b  = (const float*)d_in[14];
    const float* bn4_g    = (const float*)d_in[15];
    const float* bn4_b    = (const float*)d_in[16];
    const float* proj_w   = (const float*)d_in[17];
    const float* proj_b   = (const float*)d_in[18];
    const float* codebook = (const float*)d_in[19];
    const float* word_cb  = (const float*)d_in[20];
    const float* align_w  = (const float*)d_in[21];
    const float* align_b  = (const float*)d_in[22];
    const float* gru_wih0 = (const float*)d_in[23];
    const float* gru_whh0 = (const float*)d_in[24];
    const float* gru_bih0 = (const float*)d_in[25];
    const float* gru_bhh0 = (const float*)d_in[26];
    const float* gru_wih1 = (const float*)d_in[27];
    const float* gru_whh1 = (const float*)d_in[28];
    const float* gru_bih1 = (const float*)d_in[29];
    const float* gru_bhh1 = (const float*)d_in[30];
    const float* dec1_w   = (const float*)d_in[31];
    const float* dec1_b   = (const float*)d_in[32];
    const float* dec2_w   = (const float*)d_in[33];
    const float* dec2_b   = (const float*)d_in[34];
    const float* dec3_w   = (const float*)d_in[35];
    const float* dec3_b   = (const float*)d_in[36];
    const int*   tokens   = (const int*)d_in[37];

    float* wsf    = (float*)d_ws;
    float* out    = (float*)d_out;
    float* x1p    = wsf + OFF_X1P;
    float* x2p    = wsf + OFF_X2P;
    float* y2     = wsf + OFF_Y2;
    float* y3     = wsf + OFF_Y3;
    float* x3p    = wsf + OFF_X3P;
    float* y4     = wsf + OFF_Y4;
    float* x4     = wsf + OFF_X4;
    float* feat   = wsf + OFF_FEAT;
    float* quant  = wsf + OFF_QUANT;
    float* gi1    = wsf + OFF_GI1;
    float* gi2    = wsf + OFF_GI2;
    float* h1     = wsf + OFF_H1;
    float* h2     = wsf + OFF_H2;
    float* wemb   = wsf + OFF_WEMB;
    float* ctx    = wsf + OFF_CTX;
    float* hh1    = wsf + OFF_HH1;
    float* hh2    = wsf + OFF_HH2;
    float* logit  = wsf + OFF_LOG;
    float* pp     = wsf + OFF_PP;
    float* sc     = wsf + OFF_SC;
    float* sh     = wsf + OFF_SH;
    float* accP   = wsf + OFF_ACCP;
    float* commitA= wsf + OFF_COMMIT;
    float* ctxA   = wsf + OFF_CTXA;
    float* alignA = wsf + OFF_ALIGNA;

    // conv1 + bn1 + pool
    k_conv1_stats3<<<dim3(4, 4, 64), 256, 0, stream>>>(videos, conv1_w, conv1_b, accP);
    k_conv1_fin<<<4, 256, 0, stream>>>(accP, bn1_g, bn1_b, sc, sh);
    k_conv1_apply3<<<dim3(4, 4, 64), 256, 0, stream>>>(videos, conv1_w, conv1_b, sc, sh, x1p);
    // conv2 + bn2 + pool
    k_conv2<<<dim3(4, 4, 64), 256, 0, stream>>>(x1p, conv2_w, conv2_b, y2);
    k_bn_stats<<<dim3(16, 128), 256, 0, stream>>>(y2, bn2_g, bn2_b, sc, sh, 128, 1024);
    k_bn_apply_pool<<<8192, 256, 0, stream>>>(y2, sc, sh, x2p, 128, 32, 32);
    // conv3 + bn3 + chain
    k_conv3k<<<dim3(8, 64), 256, 0, stream>>>(x2p, conv3_w, conv3_b, y3);
    k_bn_stats<<<dim3(16, 256), 256, 0, stream>>>(y3, bn3_g, bn3_b, sc, sh, 256, 256);
    k_bn_apply_avgpool4<<<1024, 256, 0, stream>>>(y3, sc, sh, x3p);
    k_tconv<<<1024, 256, 0, stream>>>(x3p, tconv_w, tconv_b, y4);
    k_bn_stats<<<dim3(16, 256), 256, 0, stream>>>(y4, bn4_g, bn4_b, sc, sh, 256, 16);
    k_bn_apply<<<1024, 256, 0, stream>>>(y4, sc, sh, x4);
    // projection (deterministic split-K GEMM, row permutation in fin)
    k_proj_part<<<dim3(8, 8), 256, 0, stream>>>(x4, proj_w, pp);
    k_proj_fin<<<128, 256, 0, stream>>>(pp, proj_b, feat);
    k_vq<<<64, 256, 0, stream>>>(feat, codebook, quant, commitA);
    // GRU: layer-1 gi (spread over all CUs), then 17-launch two-layer pipeline
    k_gru_gi6<<<360, 256, 0, stream>>>(quant, gru_wih0, gru_bih0, gi1);
    for (int t = 0; t <= 16; ++t)
        k_gru_pipe<<<280, 256, 0, stream>>>(gi1, gru_whh0, gru_bhh0, h1,
                                            gru_wih1, gru_bih1, gi2,
                                            gru_whh1, gru_bhh1, h2, t);
    k_ctx_loss<<<120, 256, 0, stream>>>(h2, feat, ctxA);
    // word VQ + alignment
    k_word_vq<<<32, 256, 0, stream>>>(quant, word_cb, wemb, out);
    k_align<<<32, 256, 0, stream>>>(wemb, align_w, align_b, alignA);
    // decoder
    k_ctx<<<8, 256, 0, stream>>>(wemb, ctx);
    k_smallM<<<32, 256, 0, stream>>>(ctx, dec1_w, dec1_b, hh1, 512, 512, 1);
    k_smallM<<<64, 256, 0, stream>>>(hh1, dec2_w, dec2_b, hh2, 1024, 512, 1);
    k_smallM<<<188, 256, 0, stream>>>(hh2, dec3_w, dec3_b, logit, 3000, 1024, 0);
    k_final<<<1, 256, 0, stream>>>(logit, tokens, commitA, ctxA, alignA, out + 32);
}

// Round 7
// 1095.969 us; speedup vs baseline: 1.0412x; 1.0412x over previous
//
#include <hip/hip_runtime.h>

// ============================================================================
// SignLLM forward, fp32. B=4, T=32 -> nc=16 clips, D=512.
// Output: d_out[0..31] = widx (4,8) as float, d_out[32] = total loss.
// R17: (a) R16's prefetch/unroll REVERTED (VGPR 52->48 showed compiler folded
// it; 213->221us regression). (b) conv3 split-IC 2-way: same inner loop (so
// per-wave FMA:LDS ratio unchanged - R11's failure mode avoided), grid
// (8,64,2) = 1024 blocks -> 16 waves/CU (was 8); partials P0/P1 in the dead
// y2 region (no ws growth); k_comb3 adds them + bias deterministically.
// NOTE: y3 FP order becomes (sum ic<64)+(sum ic>=64)+bias - not bit-identical
// to the single-sum order, deterministic; expected absmax <=1e-5 via loss.
// conv2 = R13. GRU pipeline = R15. Zero atomics anywhere (deterministic).
// ============================================================================

// ---- workspace layout (float offsets), peak ~12.62M floats = 50.5 MB ----
static const size_t OFF_X1P  = 0;         // (64,64,32,32)  4,194,304  [dead after conv2]
static const size_t OFF_Y2   = 4194304;   // (64,128,32,32) 8,388,608  -> ends 12,582,912
static const size_t OFF_X2P  = 0;         // (64,128,16,16) 2,097,152  [x1p dead]
static const size_t OFF_Y3   = 4194304;   // conv3 partial P0 / final y3 (4,194,304)
static const size_t OFF_Y3P1 = 8388608;   // conv3 partial P1 (4,194,304) -> ends 12,582,912
static const size_t OFF_X3P  = 2097152;   // 262,144
static const size_t OFF_Y4   = 2359296;   // 262,144
static const size_t OFF_X4   = 2621440;   // 262,144
static const size_t OFF_FEAT = 2883584;   // (64,512) 32,768
static const size_t OFF_QUANT= 2916352;   // 32,768
static const size_t OFF_GI1  = 2949120;   // (64,1536) 98,304 (rows b*16+t)
static const size_t OFF_GI2  = 3047424;   // 98,304
static const size_t OFF_H1   = 3145728;   // (64,512) rows b*16+t
static const size_t OFF_H2   = 3178496;   // 32,768
static const size_t OFF_WEMB = 3211264;   // (32,512) 16,384
static const size_t OFF_CTX  = 3227648;   // 2,048
static const size_t OFF_HH1  = 3229696;   // 2,048
static const size_t OFF_HH2  = 3231744;   // 4,096
static const size_t OFF_LOG  = 3235840;   // 12,000 -> ends 3,247,840
static const size_t OFF_PP   = 3247840;   // proj partials (8,64,512) 262,144
// long-lived block PAST y2's end (12,582,912):
static const size_t OFF_SC    = 12582912; // 4,096
static const size_t OFF_SH    = 12587008; // 4,096
static const size_t OFF_ACCP  = 12591104; // 32,768: conv1 stats (s:16384, q:16384)
static const size_t OFF_COMMIT= 12623872; // 64
static const size_t OFF_CTXA  = 12623936; // 120
static const size_t OFF_ALIGNA= 12624056; // 32

// ============================================================================
// conv1 (IC=3, 64x64, pad 1, mid temporal slice). Block = (ocg, rq, n),
// 256 thr = 2x2px x 16oc. Deterministic per-(c,oc,b,rq) stats partials.
// ============================================================================
__global__ __launch_bounds__(256) void k_conv1_stats3(
        const float* __restrict__ videos, const float* __restrict__ w1,
        const float* __restrict__ b1, float* __restrict__ accP) {
    __shared__ float sP[3 * 18 * 66];
    __shared__ float wsm[3 * 9 * 16];
    __shared__ float sRed[4][16], qRed[4][16];
    int oc0 = blockIdx.x * 16, rq = blockIdx.y, n = blockIdx.z;
    int c = n >> 2, b = n & 3;
    int tid = threadIdx.x;
    int rp = tid >> 5, cq = tid & 31;
    for (int e = tid; e < 3564; e += 256) {
        int ic = e / 1188, rem = e % 1188;
        int r = rem / 66, col = rem % 66;
        int gr = rq * 16 - 1 + r, gc = col - 1;
        float v = 0.f;
        if (gr >= 0 && gr < 64 && gc >= 0 && gc < 64)
            v = videos[((size_t)(b * 3 + ic) * 32 + 2 * c) * 4096 + gr * 64 + gc];
        sP[e] = v;
    }
    for (int e = tid; e < 432; e += 256) {
        int ic = e / 144, rem = e % 144, k = rem / 16, j = rem % 16;
        wsm[e] = w1[((size_t)((oc0 + j) * 3 + ic) * 3 + 1) * 9 + k];
    }
    __syncthreads();
    float acc[4][16];
#pragma unroll
    for (int p = 0; p < 4; ++p)
#pragma unroll
        for (int j = 0; j < 16; ++j) acc[p][j] = 0.f;
#pragma unroll
    for (int ic = 0; ic < 3; ++ic) {
        const float* base = &sP[ic * 1188 + (2 * rp) * 66 + 2 * cq];
        float patch[4][4];
#pragma unroll
        for (int r = 0; r < 4; ++r)
#pragma unroll
            for (int q = 0; q < 4; ++q) patch[r][q] = base[r * 66 + q];
#pragma unroll
        for (int k = 0; k < 9; ++k) {
            int kr = k / 3, kc = k % 3;
            float4 w0 = *(const float4*)&wsm[(ic * 9 + k) * 16 + 0];
            float4 w1v = *(const float4*)&wsm[(ic * 9 + k) * 16 + 4];
            float4 w2 = *(const float4*)&wsm[(ic * 9 + k) * 16 + 8];
            float4 w3 = *(const float4*)&wsm[(ic * 9 + k) * 16 + 12];
#pragma unroll
            for (int p = 0; p < 4; ++p) {
                float vv = patch[(p >> 1) + kr][(p & 1) + kc];
                acc[p][0]  += vv * w0.x; acc[p][1]  += vv * w0.y;
                acc[p][2]  += vv * w0.z; acc[p][3]  += vv * w0.w;
                acc[p][4]  += vv * w1v.x; acc[p][5]  += vv * w1v.y;
                acc[p][6]  += vv * w1v.z; acc[p][7]  += vv * w1v.w;
                acc[p][8]  += vv * w2.x; acc[p][9]  += vv * w2.y;
                acc[p][10] += vv * w2.z; acc[p][11] += vv * w2.w;
                acc[p][12] += vv * w3.x; acc[p][13] += vv * w3.y;
                acc[p][14] += vv * w3.z; acc[p][15] += vv * w3.w;
            }
        }
    }
    int lane = tid & 63, wave = tid >> 6;
#pragma unroll
    for (int j = 0; j < 16; ++j) {
        float bj = b1[oc0 + j];
        float s = 0.f, q = 0.f;
#pragma unroll
        for (int p = 0; p < 4; ++p) {
            float a = acc[p][j] + bj;
            s += a; q += a * a;
        }
#pragma unroll
        for (int m = 1; m < 64; m <<= 1) {
            s += __shfl_xor(s, m);
            q += __shfl_xor(q, m);
        }
        if (lane == 0) { sRed[wave][j] = s; qRed[wave][j] = q; }
    }
    __syncthreads();
    if (tid < 16) {
        float s = ((sRed[0][tid] + sRed[1][tid]) + (sRed[2][tid] + sRed[3][tid]));
        float q = ((qRed[0][tid] + qRed[1][tid]) + (qRed[2][tid] + qRed[3][tid]));
        int oc = oc0 + tid;
        size_t slot = (((size_t)(c * 64 + oc)) * 4 + b) * 4 + rq;
        accP[slot] = s;
        accP[16384 + slot] = q;
    }
}

__global__ void k_conv1_fin(const float* __restrict__ accP, const float* __restrict__ g1,
                            const float* __restrict__ be1, float* __restrict__ sc,
                            float* __restrict__ sh) {
    int e = blockIdx.x * 256 + threadIdx.x;
    if (e >= 1024) return;
    int oc = e & 63;
    const float* ps = accP + (size_t)e * 16;
    const float* pq = accP + 16384 + (size_t)e * 16;
    float s = 0.f, q = 0.f;
#pragma unroll
    for (int i = 0; i < 16; ++i) { s += ps[i]; q += pq[i]; }
    float m = s * (1.f / 16384.f);
    float var = q * (1.f / 16384.f) - m * m;
    float sf = g1[oc] * rsqrtf(var + 1e-5f);
    sc[e] = sf;
    sh[e] = be1[oc] - m * sf;
}

__global__ __launch_bounds__(256) void k_conv1_apply3(
        const float* __restrict__ videos, const float* __restrict__ w1,
        const float* __restrict__ b1, const float* __restrict__ sc,
        const float* __restrict__ sh, float* __restrict__ x1p) {
    __shared__ float sP[3 * 18 * 66];
    __shared__ float wsm[3 * 9 * 16];
    int oc0 = blockIdx.x * 16, rq = blockIdx.y, n = blockIdx.z;
    int c = n >> 2, b = n & 3;
    int tid = threadIdx.x;
    int rp = tid >> 5, cq = tid & 31;
    for (int e = tid; e < 3564; e += 256) {
        int ic = e / 1188, rem = e % 1188;
        int r = rem / 66, col = rem % 66;
        int gr = rq * 16 - 1 + r, gc = col - 1;
        float v = 0.f;
        if (gr >= 0 && gr < 64 && gc >= 0 && gc < 64)
            v = videos[((size_t)(b * 3 + ic) * 32 + 2 * c) * 4096 + gr * 64 + gc];
        sP[e] = v;
    }
    for (int e = tid; e < 432; e += 256) {
        int ic = e / 144, rem = e % 144, k = rem / 16, j = rem % 16;
        wsm[e] = w1[((size_t)((oc0 + j) * 3 + ic) * 3 + 1) * 9 + k];
    }
    __syncthreads();
    float acc[4][16];
#pragma unroll
    for (int p = 0; p < 4; ++p)
#pragma unroll
        for (int j = 0; j < 16; ++j) acc[p][j] = 0.f;
#pragma unroll
    for (int ic = 0; ic < 3; ++ic) {
        const float* base = &sP[ic * 1188 + (2 * rp) * 66 + 2 * cq];
        float patch[4][4];
#pragma unroll
        for (int r = 0; r < 4; ++r)
#pragma unroll
            for (int q = 0; q < 4; ++q) patch[r][q] = base[r * 66 + q];
#pragma unroll
        for (int k = 0; k < 9; ++k) {
            int kr = k / 3, kc = k % 3;
            float4 w0 = *(const float4*)&wsm[(ic * 9 + k) * 16 + 0];
            float4 w1v = *(const float4*)&wsm[(ic * 9 + k) * 16 + 4];
            float4 w2 = *(const float4*)&wsm[(ic * 9 + k) * 16 + 8];
            float4 w3 = *(const float4*)&wsm[(ic * 9 + k) * 16 + 12];
#pragma unroll
            for (int p = 0; p < 4; ++p) {
                float vv = patch[(p >> 1) + kr][(p & 1) + kc];
                acc[p][0]  += vv * w0.x; acc[p][1]  += vv * w0.y;
                acc[p][2]  += vv * w0.z; acc[p][3]  += vv * w0.w;
                acc[p][4]  += vv * w1v.x; acc[p][5]  += vv * w1v.y;
                acc[p][6]  += vv * w1v.z; acc[p][7]  += vv * w1v.w;
                acc[p][8]  += vv * w2.x; acc[p][9]  += vv * w2.y;
                acc[p][10] += vv * w2.z; acc[p][11] += vv * w2.w;
                acc[p][12] += vv * w3.x; acc[p][13] += vv * w3.y;
                acc[p][14] += vv * w3.z; acc[p][15] += vv * w3.w;
            }
        }
    }
#pragma unroll
    for (int j = 0; j < 16; ++j) {
        int oc = oc0 + j;
        float bj = b1[oc];
        float scj = sc[c * 64 + oc], shj = sh[c * 64 + oc];
        float m = -1e30f;
#pragma unroll
        for (int p = 0; p < 4; ++p) m = fmaxf(m, (acc[p][j] + bj) * scj + shj);
        x1p[((size_t)n * 64 + oc) * 1024 + (rq * 8 + rp) * 32 + cq] = fmaxf(m, 0.f);
    }
}

// ============================================================================
// conv2: IC=64, 32x32, OC=128. Block = 32 oc x 8-row slab x 1 clip.
// grid (4 ocg, 4 slab, 64 n) = 1024 blocks. Thread = 4 oc x (2x4 px).
// Input halo stride 36 -> patch rows load as b128+b64. (R13 form.)
// ============================================================================
__global__ __launch_bounds__(256) void k_conv2(
        const float* __restrict__ in, const float* __restrict__ wt,
        const float* __restrict__ bias, float* __restrict__ out) {
    __shared__ __align__(16) float sIn[8 * 10 * 36];   // 2880
    __shared__ __align__(16) float sW[8 * 9 * 32];     // 2304
    int oc0 = blockIdx.x * 32, r0 = blockIdx.y * 8, n = blockIdx.z;
    int tid = threadIdx.x;
    int ocq = tid >> 5;          // 0..7
    int rg = (tid >> 3) & 3;     // rows r0+2rg, r0+2rg+1
    int cg = tid & 7;            // cols 4cg..4cg+3
    float acc[4][8];
#pragma unroll
    for (int j = 0; j < 4; ++j)
#pragma unroll
        for (int p = 0; p < 8; ++p) acc[j][p] = 0.f;

    for (int ic0 = 0; ic0 < 64; ic0 += 8) {
        __syncthreads();
        for (int e = tid; e < 2720; e += 256) {      // 8 ch x 10 rows x 34 cols
            int ch = e / 340, rem = e % 340;
            int r = rem / 34, col = rem % 34;
            int gr = r0 - 1 + r, gc = col - 1;
            float v = 0.f;
            if (gr >= 0 && gr < 32 && gc >= 0 && gc < 32)
                v = in[((size_t)(n * 64 + ic0 + ch) * 32 + gr) * 32 + gc];
            sIn[ch * 360 + r * 36 + col] = v;
        }
        for (int e = tid; e < 2304; e += 256) {
            int c = e / 288, r1 = e % 288, k = r1 / 32, j = r1 % 32;
            sW[e] = wt[((size_t)(oc0 + j) * 64 + ic0 + c) * 27 + 9 + k];
        }
        __syncthreads();
        for (int c = 0; c < 8; ++c) {
            const float* base = &sIn[c * 360 + (2 * rg) * 36 + 4 * cg];
            float patch[4][6];
#pragma unroll
            for (int r = 0; r < 4; ++r) {
                float4 p4 = *(const float4*)&base[r * 36];
                float2 p2 = *(const float2*)&base[r * 36 + 4];
                patch[r][0] = p4.x; patch[r][1] = p4.y; patch[r][2] = p4.z;
                patch[r][3] = p4.w; patch[r][4] = p2.x; patch[r][5] = p2.y;
            }
#pragma unroll
            for (int k = 0; k < 9; ++k) {
                int kr = k / 3, kc = k % 3;
                float4 w4 = *(const float4*)&sW[c * 288 + k * 32 + ocq * 4];
#pragma unroll
                for (int p = 0; p < 8; ++p) {
                    int pr = p >> 2, pcq = p & 3;
                    float vv = patch[pr + kr][pcq + kc];
                    acc[0][p] += vv * w4.x; acc[1][p] += vv * w4.y;
                    acc[2][p] += vv * w4.z; acc[3][p] += vv * w4.w;
                }
            }
        }
    }
#pragma unroll
    for (int j = 0; j < 4; ++j) {
        int oc = oc0 + ocq * 4 + j;
        float bj = bias[oc];
#pragma unroll
        for (int pr = 0; pr < 2; ++pr) {
            float4 o4 = make_float4(acc[j][pr * 4 + 0] + bj, acc[j][pr * 4 + 1] + bj,
                                    acc[j][pr * 4 + 2] + bj, acc[j][pr * 4 + 3] + bj);
            *(float4*)&out[((size_t)(n * 128 + oc) * 32 + r0 + 2 * rg + pr) * 32 + 4 * cg] = o4;
        }
    }
}

// ============================================================================
// conv3 split-IC partial: grid (8 ocg, 64 n, 2 half) = 1024 blocks -> 16
// waves/CU (2x R13's 8; same per-wave FMA:LDS ratio - only the ic range is
// halved). Writes NO-bias partial sums to P[half]. Inner loop = R13 exactly
// (halo stride 20, b128+b64 patch loads). ic order within a half ascending.
// ============================================================================
__global__ __launch_bounds__(256) void k_conv3p(
        const float* __restrict__ in, const float* __restrict__ wt,
        float* __restrict__ outP) {
    __shared__ __align__(16) float sIn[8 * 18 * 20];   // 2880
    __shared__ __align__(16) float sW[8 * 9 * 32];     // 2304
    int oc0 = blockIdx.x * 32, n = blockIdx.y, half = blockIdx.z;
    int tid = threadIdx.x;
    int ocq = tid >> 5;          // 0..7
    int rg = (tid >> 2) & 7;     // rows 2rg, 2rg+1
    int cg = tid & 3;            // cols 4cg..4cg+3
    float acc[4][8];
#pragma unroll
    for (int j = 0; j < 4; ++j)
#pragma unroll
        for (int p = 0; p < 8; ++p) acc[j][p] = 0.f;

    int icB = half * 64;
    for (int ic0 = icB; ic0 < icB + 64; ic0 += 8) {
        __syncthreads();
        for (int e = tid; e < 2592; e += 256) {      // 8 ch x 18 rows x 18 cols
            int ch = e / 324, rem = e % 324;
            int r = rem / 18, cc = rem % 18;
            int gr = r - 1, gc = cc - 1;
            float v = 0.f;
            if (gr >= 0 && gr < 16 && gc >= 0 && gc < 16)
                v = in[((size_t)(n * 128 + ic0 + ch) * 16 + gr) * 16 + gc];
            sIn[ch * 360 + r * 20 + cc] = v;
        }
        for (int e = tid; e < 2304; e += 256) {
            int c = e / 288, r1 = e % 288, k = r1 / 32, j = r1 % 32;
            sW[e] = wt[((size_t)(oc0 + j) * 128 + ic0 + c) * 27 + 9 + k];
        }
        __syncthreads();
        for (int c = 0; c < 8; ++c) {
            const float* base = &sIn[c * 360 + (2 * rg) * 20 + 4 * cg];
            float patch[4][6];
#pragma unroll
            for (int r = 0; r < 4; ++r) {
                float4 p4 = *(const float4*)&base[r * 20];
                float2 p2 = *(const float2*)&base[r * 20 + 4];
                patch[r][0] = p4.x; patch[r][1] = p4.y; patch[r][2] = p4.z;
                patch[r][3] = p4.w; patch[r][4] = p2.x; patch[r][5] = p2.y;
            }
#pragma unroll
            for (int k = 0; k < 9; ++k) {
                int kr = k / 3, kc = k % 3;
                float4 w4 = *(const float4*)&sW[c * 288 + k * 32 + ocq * 4];
#pragma unroll
                for (int p = 0; p < 8; ++p) {
                    int pr = p >> 2, pcq = p & 3;
                    float vv = patch[pr + kr][pcq + kc];
                    acc[0][p] += vv * w4.x; acc[1][p] += vv * w4.y;
                    acc[2][p] += vv * w4.z; acc[3][p] += vv * w4.w;
                }
            }
        }
    }
    float* dst = outP + (size_t)half * 4194304;
#pragma unroll
    for (int j = 0; j < 4; ++j) {
        int oc = oc0 + ocq * 4 + j;
#pragma unroll
        for (int pr = 0; pr < 2; ++pr) {
            float4 o4 = make_float4(acc[j][pr * 4 + 0], acc[j][pr * 4 + 1],
                                    acc[j][pr * 4 + 2], acc[j][pr * 4 + 3]);
            *(float4*)&dst[((size_t)(n * 256 + oc) * 16 + 2 * rg + pr) * 16 + 4 * cg] = o4;
        }
    }
}

// y3[i] = (P0[i] + P1[i]) + bias[oc]  (in-place over P0; deterministic)
__global__ void k_comb3(const float* __restrict__ P, const float* __restrict__ bias,
                        float* __restrict__ y3) {
    size_t idx = (size_t)blockIdx.x * 256 + threadIdx.x;  // 4,194,304
    int oc = (int)((idx >> 8) & 255);
    y3[idx] = (P[idx] + P[idx + 4194304]) + bias[oc];
}

// per-(clip,channel) BN stats
__global__ void k_bn_stats(const float* __restrict__ buf, const float* __restrict__ g,
                           const float* __restrict__ be, float* __restrict__ scale,
                           float* __restrict__ shift, int C, int HW) {
    int c = blockIdx.x, ch = blockIdx.y, tid = threadIdx.x;
    float s = 0.f, s2 = 0.f;
    for (int b = 0; b < 4; ++b) {
        const float* p = buf + ((size_t)(c * 4 + b) * C + ch) * HW;
        for (int i = tid; i < HW; i += 256) { float v = p[i]; s += v; s2 += v * v; }
    }
    __shared__ float rs[256], rq[256];
    rs[tid] = s; rq[tid] = s2; __syncthreads();
    for (int k = 128; k > 0; k >>= 1) {
        if (tid < k) { rs[tid] += rs[tid + k]; rq[tid] += rq[tid + k]; }
        __syncthreads();
    }
    if (tid == 0) {
        float inv = 1.f / (float)(4 * HW);
        float m = rs[0] * inv, var = rq[0] * inv - m * m;
        float sc = g[ch] * rsqrtf(var + 1e-5f);
        scale[c * C + ch] = sc;
        shift[c * C + ch] = be[ch] - m * sc;
    }
}

__global__ void k_bn_apply_pool(const float* __restrict__ in, const float* __restrict__ scale,
                                const float* __restrict__ shift, float* __restrict__ out,
                                int C, int H, int W) {
    int OH = H >> 1, OW = W >> 1;
    size_t idx = (size_t)blockIdx.x * 256 + threadIdx.x;
    int ow = (int)(idx % OW);
    size_t r = idx / OW;
    int oh = (int)(r % OH); r /= OH;
    int ch = (int)(r % C);
    int n = (int)(r / C);
    int c = n >> 2;
    float sc = scale[c * C + ch], sh = shift[c * C + ch];
    const float* p = in + (((size_t)n * C + ch) * H + 2 * oh) * W + 2 * ow;
    float m = 0.f;
    m = fmaxf(m, p[0] * sc + sh);
    m = fmaxf(m, p[1] * sc + sh);
    m = fmaxf(m, p[W] * sc + sh);
    m = fmaxf(m, p[W + 1] * sc + sh);
    out[idx] = m;
}

// ---- post-conv3 chain ----
__global__ void k_bn_apply_avgpool4(const float* __restrict__ in, const float* __restrict__ scale,
                                    const float* __restrict__ shift, float* __restrict__ out) {
    size_t idx = (size_t)blockIdx.x * 256 + threadIdx.x;  // 262,144
    int j = (int)(idx & 3), i = (int)(idx >> 2) & 3;
    int ch = (int)(idx >> 4) & 255, n = (int)(idx >> 12);
    int c = n >> 2;
    float sc = scale[c * 256 + ch], sh = shift[c * 256 + ch];
    const float* p = in + (((size_t)n * 256 + ch) * 16 + i * 4) * 16 + j * 4;
    float s = 0.f;
#pragma unroll
    for (int r = 0; r < 4; ++r)
#pragma unroll
        for (int q = 0; q < 4; ++q) s += fmaxf(p[r * 16 + q] * sc + sh, 0.f);
    out[idx] = s * (1.f / 16.f);
}

__global__ void k_tconv(const float* __restrict__ x3p, const float* __restrict__ tw,
                        const float* __restrict__ tb, float* __restrict__ y4) {
    size_t idx = (size_t)blockIdx.x * 256 + threadIdx.x;  // 262,144
    int p = (int)(idx & 15), o = (int)(idx >> 4) & 255, n = (int)(idx >> 12);
    const float* xr = x3p + (size_t)n * 4096 + p;
    float a = tb[o];
    for (int i = 0; i < 256; ++i) a += xr[i * 16] * tw[((size_t)o * 256 + i) * 3 + 1];
    y4[idx] = a;
}

__global__ void k_bn_apply(const float* __restrict__ in, const float* __restrict__ scale,
                           const float* __restrict__ shift, float* __restrict__ out) {
    size_t idx = (size_t)blockIdx.x * 256 + threadIdx.x;  // 262,144
    int ch = (int)(idx >> 4) & 255, n = (int)(idx >> 12);
    int c = n >> 2;
    float sc = scale[c * 256 + ch], sh = shift[c * 256 + ch];
    out[idx] = fmaxf(in[idx] * sc + sh, 0.f);
}

// ============================================================================
// proj as deterministic split-K GEMM with row permutation in fin.
// ============================================================================
__global__ __launch_bounds__(256) void k_proj_part(
        const float* __restrict__ A, const float* __restrict__ B, float* __restrict__ PP) {
    __shared__ __align__(16) float As[64 * 68];
    __shared__ __align__(16) float Bs[64 * 68];
    int n0 = blockIdx.x * 64, ks = blockIdx.y;
    int tid = threadIdx.x, tm = tid >> 4, tn = tid & 15;
    float acc[4][4];
#pragma unroll
    for (int i = 0; i < 4; ++i)
#pragma unroll
        for (int j = 0; j < 4; ++j) acc[i][j] = 0.f;
    int kb = ks * 512;
    for (int k0 = kb; k0 < kb + 512; k0 += 64) {
        __syncthreads();
        for (int e = tid; e < 4096; e += 256) {
            int m = e >> 6, k = e & 63;
            As[k * 68 + m] = A[(size_t)m * 4096 + k0 + k];
            Bs[k * 68 + m] = B[(size_t)(n0 + m) * 4096 + k0 + k];
        }
        __syncthreads();
        for (int k = 0; k < 64; ++k) {
            float4 a4 = *(const float4*)&As[k * 68 + tm * 4];
            float4 b4 = *(const float4*)&Bs[k * 68 + tn * 4];
            acc[0][0] += a4.x * b4.x; acc[0][1] += a4.x * b4.y;
            acc[0][2] += a4.x * b4.z; acc[0][3] += a4.x * b4.w;
            acc[1][0] += a4.y * b4.x; acc[1][1] += a4.y * b4.y;
            acc[1][2] += a4.y * b4.z; acc[1][3] += a4.y * b4.w;
            acc[2][0] += a4.z * b4.x; acc[2][1] += a4.z * b4.y;
            acc[2][2] += a4.z * b4.z; acc[2][3] += a4.z * b4.w;
            acc[3][0] += a4.w * b4.x; acc[3][1] += a4.w * b4.y;
            acc[3][2] += a4.w * b4.z; acc[3][3] += a4.w * b4.w;
        }
    }
#pragma unroll
    for (int i = 0; i < 4; ++i)
#pragma unroll
        for (int j = 0; j < 4; ++j)
            PP[((size_t)(ks * 64 + tm * 4 + i)) * 512 + n0 + tn * 4 + j] = acc[i][j];
}

__global__ void k_proj_fin(const float* __restrict__ PP, const float* __restrict__ pb,
                           float* __restrict__ feat) {
    int e = blockIdx.x * 256 + threadIdx.x;  // 32768
    int n = e & 511;
    int m = e >> 9;               // x4 row (clip-major): m = c*4 + b
    float s = pb[n];
#pragma unroll
    for (int ks = 0; ks < 8; ++ks) s += PP[(size_t)ks * 32768 + e];
    int c = m >> 2, b = m & 3;
    int ro = b * 16 + c;          // feat row (batch-major)
    feat[(size_t)ro * 512 + n] = s;
}

// VQ argmin; min distance -> commitArr[row] (deterministic)
__global__ void k_vq(const float* __restrict__ feat, const float* __restrict__ cb,
                     float* __restrict__ quant, float* __restrict__ commitArr) {
    int row = blockIdx.x, tid = threadIdx.x;
    __shared__ float f[512];
    for (int k = tid; k < 512; k += 256) f[k] = feat[(size_t)row * 512 + k];
    __syncthreads();
    float best = 3.4e38f; int bidx = 0;
    for (int j = tid; j < 1024; j += 256) {
        const float* c = cb + (size_t)j * 512;
        float d2 = 0.f;
        for (int k = 0; k < 512; ++k) { float t = f[k] - c[k]; d2 += t * t; }
        if (d2 < best) { best = d2; bidx = j; }
    }
    __shared__ float rd[256]; __shared__ int ri[256];
    rd[tid] = best; ri[tid] = bidx; __syncthreads();
    for (int k = 128; k > 0; k >>= 1) {
        if (tid < k) {
            float od = rd[tid + k]; int oi = ri[tid + k];
            if (od < rd[tid] || (od == rd[tid] && oi < ri[tid])) { rd[tid] = od; ri[tid] = oi; }
        }
        __syncthreads();
    }
    __shared__ int wsel;
    if (tid == 0) { wsel = ri[0]; commitArr[row] = rd[0]; }
    __syncthreads();
    const float* c = cb + (size_t)wsel * 512;
    for (int k = tid; k < 512; k += 256) quant[(size_t)row * 512 + k] = c[k];
}

// ---- GRU helpers -----------------------------------------------------------
// Single-dim gi: gi[row*1536+d] = wih[d]·x + bih[d], exact k_gru_gi order.
__device__ __forceinline__ void gru_gi_one(
        const float* __restrict__ xsRow, const float* __restrict__ wih,
        const float* __restrict__ bih, float* __restrict__ gi, int row, int d) {
    const float4* xp = (const float4*)xsRow;
    const float4* wr = (const float4*)(wih + (size_t)d * 512);
    float a0 = 0.f, a1 = 0.f, a2 = 0.f, a3 = 0.f;
    for (int i = 0; i < 128; i += 4) {
        float4 w0 = wr[i], w1 = wr[i + 1], w2 = wr[i + 2], w3 = wr[i + 3];
        float4 x0 = xp[i], x1 = xp[i + 1], x2 = xp[i + 2], x3 = xp[i + 3];
        a0 += w0.x * x0.x + w0.y * x0.y + w0.z * x0.z + w0.w * x0.w;
        a1 += w1.x * x1.x + w1.y * x1.y + w1.z * x1.z + w1.w * x1.w;
        a2 += w2.x * x2.x + w2.y * x2.y + w2.z * x2.z + w2.w * x2.w;
        a3 += w3.x * x3.x + w3.y * x3.y + w3.z * x3.z + w3.w * x3.w;
    }
    gi[(size_t)row * 1536 + d] = (a0 + a1) + (a2 + a3) + bih[d];
}

// One GRU step for 4 h-dims (blk selects the dim group), exact k_gru_step2.
__device__ __forceinline__ void gru_step_body(
        const float* __restrict__ gi, const float* __restrict__ whh,
        const float* __restrict__ bhh, float* __restrict__ hseq, int t, int blk) {
    int wv = threadIdx.x >> 6, lane = threadIdx.x & 63;
    int d = blk * 4 + wv;
    const float4* w0p = (const float4*)(whh + (size_t)d * 512);
    const float4* w1p = (const float4*)(whh + (size_t)(512 + d) * 512);
    const float4* w2p = (const float4*)(whh + (size_t)(1024 + d) * 512);
    float4 w0a = w0p[lane * 2], w0b = w0p[lane * 2 + 1];
    float4 w1a = w1p[lane * 2], w1b = w1p[lane * 2 + 1];
    float4 w2a = w2p[lane * 2], w2b = w2p[lane * 2 + 1];
    float bh0 = bhh[d], bh1 = bhh[512 + d], bh2 = bhh[1024 + d];
    for (int b = 0; b < 4; ++b) {
        float4 ha = make_float4(0, 0, 0, 0), hb = ha;
        float hpd = 0.f;
        if (t > 0) {
            const float4* hp = (const float4*)(hseq + (size_t)(b * 16 + t - 1) * 512);
            ha = hp[lane * 2]; hb = hp[lane * 2 + 1];
            hpd = hseq[(size_t)(b * 16 + t - 1) * 512 + d];
        }
        float s0 = w0a.x * ha.x + w0a.y * ha.y + w0a.z * ha.z + w0a.w * ha.w
                 + w0b.x * hb.x + w0b.y * hb.y + w0b.z * hb.z + w0b.w * hb.w;
        float s1 = w1a.x * ha.x + w1a.y * ha.y + w1a.z * ha.z + w1a.w * ha.w
                 + w1b.x * hb.x + w1b.y * hb.y + w1b.z * hb.z + w1b.w * hb.w;
        float s2 = w2a.x * ha.x + w2a.y * ha.y + w2a.z * ha.z + w2a.w * ha.w
                 + w2b.x * hb.x + w2b.y * hb.y + w2b.z * hb.z + w2b.w * hb.w;
#pragma unroll
        for (int m = 1; m < 64; m <<= 1) {
            s0 += __shfl_xor(s0, m);
            s1 += __shfl_xor(s1, m);
            s2 += __shfl_xor(s2, m);
        }
        const float* gr = gi + (size_t)(b * 16 + t) * 1536;
        float rr = 1.f / (1.f + expf(-(gr[d] + s0 + bh0)));
        float zz = 1.f / (1.f + expf(-(gr[512 + d] + s1 + bh1)));
        float nn = tanhf(gr[1024 + d] + rr * (s2 + bh2));
        if (lane == 0)
            hseq[(size_t)(b * 16 + t) * 512 + d] = (1.f - zz) * nn + zz * hpd;
    }
}

// Layer-1 gi, spread: grid 360 = 60 rows x 6 parts, 1 dim/thread.
__global__ void k_gru_gi6(const float* __restrict__ x, const float* __restrict__ wih,
                          const float* __restrict__ bih, float* __restrict__ gi) {
    int g = blockIdx.x;
    int r = g / 6, part = g % 6;
    int b = r / 15, t = r % 15;
    int row = b * 16 + t;
    __shared__ float xsRow[512];
    for (int k = threadIdx.x; k < 512; k += 256) xsRow[k] = x[(size_t)row * 512 + k];
    __syncthreads();
    gru_gi_one(xsRow, wih, bih, gi, row, part * 256 + threadIdx.x);
}

// ============================================================================
// GRU pipeline launch t = 0..16 (17 launches replace 30 steps + gi2 kernel):
//   blocks   0..127 : layer-1 step t        (t in [0,14])
//   blocks 128..255 : layer-2 step t-2      (t in [2,16])
//   blocks 256..279 : gi2 rows for time t-1 (t in [1,15]); 6 blocks x 256
//                     dims per batch row, x = h1[t-1] (written last launch).
// All sections touch disjoint rows -> no intra-launch dependency.
// ============================================================================
__global__ __launch_bounds__(256) void k_gru_pipe(
        const float* __restrict__ gi1, const float* __restrict__ whh0,
        const float* __restrict__ bhh0, float* __restrict__ h1,
        const float* __restrict__ wih1, const float* __restrict__ bih1,
        float* __restrict__ gi2, const float* __restrict__ whh1,
        const float* __restrict__ bhh1, float* __restrict__ h2, int t) {
    int bid = blockIdx.x;
    if (bid < 128) {
        if (t < 15) gru_step_body(gi1, whh0, bhh0, h1, t, bid);
    } else if (bid < 256) {
        if (t >= 2) gru_step_body(gi2, whh1, bhh1, h2, t - 2, bid - 128);
    } else {
        if (t >= 1 && t <= 15) {
            int local = bid - 256;          // 0..23
            int b = local / 6, part = local % 6;
            int row = b * 16 + (t - 1);
            __shared__ float xsRow[512];
            for (int k = threadIdx.x; k < 512; k += 256)
                xsRow[k] = h1[(size_t)row * 512 + k];
            __syncthreads();
            gru_gi_one(xsRow, wih1, bih1, gi2, row, part * 256 + threadIdx.x);
        }
    }
}

// ctx loss partials -> ctxArr[block] (deterministic)
__global__ void k_ctx_loss(const float* __restrict__ h2, const float* __restrict__ feat,
                           float* __restrict__ ctxArr) {
    int tid = threadIdx.x;
    size_t idx = (size_t)blockIdx.x * 256 + tid;  // 30720
    int d = (int)(idx & 511);
    int rt = (int)(idx >> 9);
    int t = rt % 15, b = rt / 15;
    float diff = h2[(size_t)(b * 16 + t) * 512 + d] - feat[(size_t)(b * 16 + t + 1) * 512 + d];
    float v = diff * diff;
#pragma unroll
    for (int m = 1; m < 64; m <<= 1) v += __shfl_xor(v, m);
    __shared__ float ws[4];
    if ((tid & 63) == 0) ws[tid >> 6] = v;
    __syncthreads();
    if (tid == 0) ctxArr[blockIdx.x] = ((ws[0] + ws[1]) + (ws[2] + ws[3]));
}

__global__ void k_word_vq(const float* __restrict__ quant, const float* __restrict__ wcb,
                          float* __restrict__ wemb, float* __restrict__ out_widx) {
    int row = blockIdx.x;  // b*8+wi
    int b = row >> 3, wi = row & 7;
    int tid = threadIdx.x;
    __shared__ float f[512];
    for (int k = tid; k < 512; k += 256)
        f[k] = 0.5f * (quant[(size_t)(b * 16 + 2 * wi) * 512 + k] +
                       quant[(size_t)(b * 16 + 2 * wi + 1) * 512 + k]);
    __syncthreads();
    const float* cp = wcb + (size_t)tid * 512;
    float d2 = 0.f;
    for (int k = 0; k < 512; ++k) { float t = f[k] - cp[k]; d2 += t * t; }
    __shared__ float rd[256]; __shared__ int ri[256];
    rd[tid] = d2; ri[tid] = tid; __syncthreads();
    for (int k = 128; k > 0; k >>= 1) {
        if (tid < k) {
            float od = rd[tid + k]; int oi = ri[tid + k];
            if (od < rd[tid] || (od == rd[tid] && oi < ri[tid])) { rd[tid] = od; ri[tid] = oi; }
        }
        __syncthreads();
    }
    __shared__ int wsel;
    if (tid == 0) { wsel = ri[0]; out_widx[row] = (float)ri[0]; }
    __syncthreads();
    const float* cb = wcb + (size_t)wsel * 512;
    for (int k = tid; k < 512; k += 256) wemb[(size_t)row * 512 + k] = cb[k];
}

// alignment partials -> alignArr[row] (deterministic)
__global__ void k_align(const float* __restrict__ wemb, const float* __restrict__ aw,
                        const float* __restrict__ ab, float* __restrict__ alignArr) {
    int row = blockIdx.x, tid = threadIdx.x;
    __shared__ float e[512];
    for (int k = tid; k < 512; k += 256) e[k] = wemb[(size_t)row * 512 + k];
    __syncthreads();
    float local = 0.f;
    for (int d = tid; d < 512; d += 256) {
        const float* wr = aw + (size_t)d * 512;
        float a = ab[d] - e[d];
        for (int k = 0; k < 512; ++k) a += e[k] * wr[k];
        local += a * a;
    }
    __shared__ float rs[256];
    rs[tid] = local; __syncthreads();
    for (int k = 128; k > 0; k >>= 1) { if (tid < k) rs[tid] += rs[tid + k]; __syncthreads(); }
    if (tid == 0) alignArr[row] = rs[0];
}

__global__ void k_ctx(const float* __restrict__ wemb, float* __restrict__ ctx) {
    int e = blockIdx.x * 256 + threadIdx.x;  // 2048
    int b = e >> 9, d = e & 511;
    float s = 0.f;
#pragma unroll
    for (int wi = 0; wi < 8; ++wi) s += wemb[(size_t)(b * 8 + wi) * 512 + d];
    ctx[e] = s * 0.125f;
}

// small-M (M=4) GEMV: C[4,N] = A[4,K] @ B[N,K]^T + bias, optional relu.
__global__ void k_smallM(const float* __restrict__ A, const float* __restrict__ B,
                         const float* __restrict__ bias, float* __restrict__ C,
                         int N, int K, int relu) {
    __shared__ float xs[4096];
    int tid = threadIdx.x;
    for (int e = tid; e < 4 * K; e += 256) xs[e] = A[e];
    __syncthreads();
    int r = tid >> 4, kt = tid & 15;
    int n = blockIdx.x * 16 + r;
    float acc[4] = {0, 0, 0, 0};
    if (n < N) {
        int iters = K >> 6;
        for (int i = 0; i < iters; ++i) {
            int k = i * 64 + kt * 4;
            float4 w = *(const float4*)&B[(size_t)n * K + k];
#pragma unroll
            for (int b = 0; b < 4; ++b) {
                float4 x = *(const float4*)&xs[b * K + k];
                acc[b] += w.x * x.x + w.y * x.y + w.z * x.z + w.w * x.w;
            }
        }
    }
#pragma unroll
    for (int b = 0; b < 4; ++b) {
#pragma unroll
        for (int m = 1; m < 16; m <<= 1) acc[b] += __shfl_xor(acc[b], m);
    }
    if (kt == 0 && n < N) {
#pragma unroll
        for (int b = 0; b < 4; ++b) {
            float v = acc[b] + bias[n];
            if (relu) v = fmaxf(v, 0.f);
            C[(size_t)b * N + n] = v;
        }
    }
}

// log-softmax CE + deterministic fixed-order sum of all loss partials
__global__ void k_final(const float* __restrict__ logits, const int* __restrict__ tokens,
                        const float* __restrict__ commitArr, const float* __restrict__ ctxArr,
                        const float* __restrict__ alignArr, float* __restrict__ out_total) {
    int tid = threadIdx.x;
    __shared__ float rs[256];
    __shared__ float sM;
    float tr = 0.f;
    for (int b = 0; b < 4; ++b) {
        const float* lg = logits + (size_t)b * 3000;
        float m = -1e30f;
        for (int d = tid; d < 3000; d += 256) m = fmaxf(m, lg[d]);
        rs[tid] = m; __syncthreads();
        for (int k = 128; k > 0; k >>= 1) { if (tid < k) rs[tid] = fmaxf(rs[tid], rs[tid + k]); __syncthreads(); }
        if (tid == 0) sM = rs[0];
        __syncthreads();
        float M = sM;
        float s = 0.f;
        for (int d = tid; d < 3000; d += 256) s += expf(lg[d] - M);
        rs[tid] = s; __syncthreads();
        for (int k = 128; k > 0; k >>= 1) { if (tid < k) rs[tid] += rs[tid + k]; __syncthreads(); }
        if (tid == 0) {
            int t0 = tokens[b * 10];
            tr += -(lg[t0] - M - logf(rs[0]));
        }
        __syncthreads();
    }
    if (tid == 0) {
        float c0 = 0.f;
        for (int i = 0; i < 64; ++i) c0 += commitArr[i];
        float c1 = 0.f;
        for (int i = 0; i < 120; ++i) c1 += ctxArr[i];
        float c2 = 0.f;
        for (int i = 0; i < 32; ++i) c2 += alignArr[i];
        float total = 1.25f * c0 * (1.f / 32768.f)
                    + 0.1f  * c1 * (1.f / 30720.f)
                    + 0.1f  * c2 * (1.f / 16384.f)
                    + tr;
        *out_total = total;
    }
}

extern "C" void kernel_launch(void* const* d_in, const int* in_sizes, int n_in,
                              void* d_out, int out_size, void* d_ws, size_t ws_size,
                              hipStream_t stream) {
    (void)in_sizes; (void)n_in; (void)out_size; (void)ws_size;
    const float* videos   = (const float*)d_in[0];
    const float* conv1_w  = (const float*)d_in[1];
    const float* conv1_b  = (const float*)d_in[2];
    const float* bn1_g    = (const float*)d_in[3];
    const float* bn1_b    = (const float*)d_in[4];
    const float* conv2_w  = (const float*)d_in[5];
    const float* conv2_b  = (const float*)d_in[6];
    const float* bn2_g    = (const float*)d_in[7];
    const float* bn2_b    = (const float*)d_in[8];
    const float* conv3_w  = (const float*)d_in[9];
    const float* conv3_b  = (const float*)d_in[10];
    const float* bn3_g    = (const float*)d_in[11];
    const float* bn3_b    = (const float*)d_in[12];
    const float* tconv_w  = (const float*)d_in[13];
    const float* tconv_b  = (const float*)d_in[14];
    const float* bn4_g    = (const float*)d_in[15];
    const float* bn4_b    = (const float*)d_in[16];
    const float* proj_w   = (const float*)d_in[17];
    const float* proj_b   = (const float*)d_in[18];
    const float* codebook = (const float*)d_in[19];
    const float* word_cb  = (const float*)d_in[20];
    const float* align_w  = (const float*)d_in[21];
    const float* align_b  = (const float*)d_in[22];
    const float* gru_wih0 = (const float*)d_in[23];
    const float* gru_whh0 = (const float*)d_in[24];
    const float* gru_bih0 = (const float*)d_in[25];
    const float* gru_bhh0 = (const float*)d_in[26];
    const float* gru_wih1 = (const float*)d_in[27];
    const float* gru_whh1 = (const float*)d_in[28];
    const float* gru_bih1 = (const float*)d_in[29];
    const float* gru_bhh1 = (const float*)d_in[30];
    const float* dec1_w   = (const float*)d_in[31];
    const float* dec1_b   = (const float*)d_in[32];
    const float* dec2_w   = (const float*)d_in[33];
    const float* dec2_b   = (const float*)d_in[34];
    const float* dec3_w   = (const float*)d_in[35];
    const float* dec3_b   = (const float*)d_in[36];
    const int*   tokens   = (const int*)d_in[37];

    float* wsf    = (float*)d_ws;
    float* out    = (float*)d_out;
    float* x1p    = wsf + OFF_X1P;
    float* x2p    = wsf + OFF_X2P;
    float* y2     = wsf + OFF_Y2;
    float* y3     = wsf + OFF_Y3;   // also conv3 partial base (P0; P1 at +4,194,304)
    float* x3p    = wsf + OFF_X3P;
    float* y4     = wsf + OFF_Y4;
    float* x4     = wsf + OFF_X4;
    float* feat   = wsf + OFF_FEAT;
    float* quant  = wsf + OFF_QUANT;
    float* gi1    = wsf + OFF_GI1;
    float* gi2    = wsf + OFF_GI2;
    float* h1     = wsf + OFF_H1;
    float* h2     = wsf + OFF_H2;
    float* wemb   = wsf + OFF_WEMB;
    float* ctx    = wsf + OFF_CTX;
    float* hh1    = wsf + OFF_HH1;
    float* hh2    = wsf + OFF_HH2;
    float* logit  = wsf + OFF_LOG;
    float* pp     = wsf + OFF_PP;
    float* sc     = wsf + OFF_SC;
    float* sh     = wsf + OFF_SH;
    float* accP   = wsf + OFF_ACCP;
    float* commitA= wsf + OFF_COMMIT;
    float* ctxA   = wsf + OFF_CTXA;
    float* alignA = wsf + OFF_ALIGNA;

    // conv1 + bn1 + pool
    k_conv1_stats3<<<dim3(4, 4, 64), 256, 0, stream>>>(videos, conv1_w, conv1_b, accP);
    k_conv1_fin<<<4, 256, 0, stream>>>(accP, bn1_g, bn1_b, sc, sh);
    k_conv1_apply3<<<dim3(4, 4, 64), 256, 0, stream>>>(videos, conv1_w, conv1_b, sc, sh, x1p);
    // conv2 + bn2 + pool
    k_conv2<<<dim3(4, 4, 64), 256, 0, stream>>>(x1p, conv2_w, conv2_b, y2);
    k_bn_stats<<<dim3(16, 128), 256, 0, stream>>>(y2, bn2_g, bn2_b, sc, sh, 128, 1024);
    k_bn_apply_pool<<<8192, 256, 0, stream>>>(y2, sc, sh, x2p, 128, 32, 32);
    // conv3 (split-IC 2-way -> 16 waves/CU) + combine + bn3 + chain
    k_conv3p<<<dim3(8, 64, 2), 256, 0, stream>>>(x2p, conv3_w, y3);
    k_comb3<<<16384, 256, 0, stream>>>(y3, conv3_b, y3);
    k_bn_stats<<<dim3(16, 256), 256, 0, stream>>>(y3, bn3_g, bn3_b, sc, sh, 256, 256);
    k_bn_apply_avgpool4<<<1024, 256, 0, stream>>>(y3, sc, sh, x3p);
    k_tconv<<<1024, 256, 0, stream>>>(x3p, tconv_w, tconv_b, y4);
    k_bn_stats<<<dim3(16, 256), 256, 0, stream>>>(y4, bn4_g, bn4_b, sc, sh, 256, 16);
    k_bn_apply<<<1024, 256, 0, stream>>>(y4, sc, sh, x4);
    // projection (deterministic split-K GEMM, row permutation in fin)
    k_proj_part<<<dim3(8, 8), 256, 0, stream>>>(x4, proj_w, pp);
    k_proj_fin<<<128, 256, 0, stream>>>(pp, proj_b, feat);
    k_vq<<<64, 256, 0, stream>>>(feat, codebook, quant, commitA);
    // GRU: layer-1 gi (spread over all CUs), then 17-launch two-layer pipeline
    k_gru_gi6<<<360, 256, 0, stream>>>(quant, gru_wih0, gru_bih0, gi1);
    for (int t = 0; t <= 16; ++t)
        k_gru_pipe<<<280, 256, 0, stream>>>(gi1, gru_whh0, gru_bhh0, h1,
                                            gru_wih1, gru_bih1, gi2,
                                            gru_whh1, gru_bhh1, h2, t);
    k_ctx_loss<<<120, 256, 0, stream>>>(h2, feat, ctxA);
    // word VQ + alignment
    k_word_vq<<<32, 256, 0, stream>>>(quant, word_cb, wemb, out);
    k_align<<<32, 256, 0, stream>>>(wemb, align_w, align_b, alignA);
    // decoder
    k_ctx<<<8, 256, 0, stream>>>(wemb, ctx);
    k_smallM<<<32, 256, 0, stream>>>(ctx, dec1_w, dec1_b, hh1, 512, 512, 1);
    k_smallM<<<64, 256, 0, stream>>>(hh1, dec2_w, dec2_b, hh2, 1024, 512, 1);
    k_smallM<<<188, 256, 0, stream>>>(hh2, dec3_w, dec3_b, logit, 3000, 1024, 0);
    k_final<<<1, 256, 0, stream>>>(logit, tokens, commitA, ctxA, alignA, out + 32);
}

// Round 10
// 1095.147 us; speedup vs baseline: 1.0420x; 1.0008x over previous
//
#include <hip/hip_runtime.h>

// ============================================================================
// SignLLM forward, fp32. B=4, T=32 -> nc=16 clips, D=512.
// Output: d_out[0..31] = widx (4,8) as float, d_out[32] = total loss.
// R20: BUG FIX. R18/R19 failed identically (absmax 242) -> guilt pinned on
// the BN3 fusion; root cause: k_bn_stats3p used inv = 1/262144 instead of
// 1/1024 (mean/var over 4 batch x 256 px = 1024 elems, as in the generic
// k_bn_stats with HW=256). Single-constant fix; everything else = R19:
// fused stats/apply read (P0[i]+P1[i])+bias directly (expression-identical
// to R17's comb3+stats+avgpool -> bit-identical, absmax 0.0 expected).
// The R18 tail piggyback remains reverted (unproven-guilty, retry later).
// conv3 = R17 split-IC (177us). conv2 = R13. GRU pipeline = R15.
// Zero atomics anywhere (deterministic).
// ============================================================================

// ---- workspace layout (float offsets), peak ~12.62M floats = 50.5 MB ----
static const size_t OFF_X1P  = 0;         // (64,64,32,32)  4,194,304  [dead after conv2]
static const size_t OFF_Y2   = 4194304;   // (64,128,32,32) 8,388,608  -> ends 12,582,912
static const size_t OFF_X2P  = 0;         // (64,128,16,16) 2,097,152  [x1p dead]
static const size_t OFF_Y3   = 4194304;   // conv3 partial P0 (4,194,304)
static const size_t OFF_Y3P1 = 8388608;   // conv3 partial P1 (4,194,304) -> ends 12,582,912
static const size_t OFF_X3P  = 2097152;   // 262,144
static const size_t OFF_Y4   = 2359296;   // 262,144
static const size_t OFF_X4   = 2621440;   // 262,144
static const size_t OFF_FEAT = 2883584;   // (64,512) 32,768
static const size_t OFF_QUANT= 2916352;   // 32,768
static const size_t OFF_GI1  = 2949120;   // (64,1536) 98,304 (rows b*16+t)
static const size_t OFF_GI2  = 3047424;   // 98,304
static const size_t OFF_H1   = 3145728;   // (64,512) rows b*16+t
static const size_t OFF_H2   = 3178496;   // 32,768
static const size_t OFF_WEMB = 3211264;   // (32,512) 16,384
static const size_t OFF_CTX  = 3227648;   // 2,048
static const size_t OFF_HH1  = 3229696;   // 2,048
static const size_t OFF_HH2  = 3231744;   // 4,096
static const size_t OFF_LOG  = 3235840;   // 12,000 -> ends 3,247,840
static const size_t OFF_PP   = 3247840;   // proj partials (8,64,512) 262,144
// long-lived block PAST y2's end (12,582,912):
static const size_t OFF_SC    = 12582912; // 4,096
static const size_t OFF_SH    = 12587008; // 4,096
static const size_t OFF_ACCP  = 12591104; // 32,768: conv1 stats (s:16384, q:16384)
static const size_t OFF_COMMIT= 12623872; // 64
static const size_t OFF_CTXA  = 12623936; // 120
static const size_t OFF_ALIGNA= 12624056; // 32

// ============================================================================
// conv1 (IC=3, 64x64, pad 1, mid temporal slice). Block = (ocg, rq, n),
// 256 thr = 2x2px x 16oc. Deterministic per-(c,oc,b,rq) stats partials.
// ============================================================================
__global__ __launch_bounds__(256) void k_conv1_stats3(
        const float* __restrict__ videos, const float* __restrict__ w1,
        const float* __restrict__ b1, float* __restrict__ accP) {
    __shared__ float sP[3 * 18 * 66];
    __shared__ float wsm[3 * 9 * 16];
    __shared__ float sRed[4][16], qRed[4][16];
    int oc0 = blockIdx.x * 16, rq = blockIdx.y, n = blockIdx.z;
    int c = n >> 2, b = n & 3;
    int tid = threadIdx.x;
    int rp = tid >> 5, cq = tid & 31;
    for (int e = tid; e < 3564; e += 256) {
        int ic = e / 1188, rem = e % 1188;
        int r = rem / 66, col = rem % 66;
        int gr = rq * 16 - 1 + r, gc = col - 1;
        float v = 0.f;
        if (gr >= 0 && gr < 64 && gc >= 0 && gc < 64)
            v = videos[((size_t)(b * 3 + ic) * 32 + 2 * c) * 4096 + gr * 64 + gc];
        sP[e] = v;
    }
    for (int e = tid; e < 432; e += 256) {
        int ic = e / 144, rem = e % 144, k = rem / 16, j = rem % 16;
        wsm[e] = w1[((size_t)((oc0 + j) * 3 + ic) * 3 + 1) * 9 + k];
    }
    __syncthreads();
    float acc[4][16];
#pragma unroll
    for (int p = 0; p < 4; ++p)
#pragma unroll
        for (int j = 0; j < 16; ++j) acc[p][j] = 0.f;
#pragma unroll
    for (int ic = 0; ic < 3; ++ic) {
        const float* base = &sP[ic * 1188 + (2 * rp) * 66 + 2 * cq];
        float patch[4][4];
#pragma unroll
        for (int r = 0; r < 4; ++r)
#pragma unroll
            for (int q = 0; q < 4; ++q) patch[r][q] = base[r * 66 + q];
#pragma unroll
        for (int k = 0; k < 9; ++k) {
            int kr = k / 3, kc = k % 3;
            float4 w0 = *(const float4*)&wsm[(ic * 9 + k) * 16 + 0];
            float4 w1v = *(const float4*)&wsm[(ic * 9 + k) * 16 + 4];
            float4 w2 = *(const float4*)&wsm[(ic * 9 + k) * 16 + 8];
            float4 w3 = *(const float4*)&wsm[(ic * 9 + k) * 16 + 12];
#pragma unroll
            for (int p = 0; p < 4; ++p) {
                float vv = patch[(p >> 1) + kr][(p & 1) + kc];
                acc[p][0]  += vv * w0.x; acc[p][1]  += vv * w0.y;
                acc[p][2]  += vv * w0.z; acc[p][3]  += vv * w0.w;
                acc[p][4]  += vv * w1v.x; acc[p][5]  += vv * w1v.y;
                acc[p][6]  += vv * w1v.z; acc[p][7]  += vv * w1v.w;
                acc[p][8]  += vv * w2.x; acc[p][9]  += vv * w2.y;
                acc[p][10] += vv * w2.z; acc[p][11] += vv * w2.w;
                acc[p][12] += vv * w3.x; acc[p][13] += vv * w3.y;
                acc[p][14] += vv * w3.z; acc[p][15] += vv * w3.w;
            }
        }
    }
    int lane = tid & 63, wave = tid >> 6;
#pragma unroll
    for (int j = 0; j < 16; ++j) {
        float bj = b1[oc0 + j];
        float s = 0.f, q = 0.f;
#pragma unroll
        for (int p = 0; p < 4; ++p) {
            float a = acc[p][j] + bj;
            s += a; q += a * a;
        }
#pragma unroll
        for (int m = 1; m < 64; m <<= 1) {
            s += __shfl_xor(s, m);
            q += __shfl_xor(q, m);
        }
        if (lane == 0) { sRed[wave][j] = s; qRed[wave][j] = q; }
    }
    __syncthreads();
    if (tid < 16) {
        float s = ((sRed[0][tid] + sRed[1][tid]) + (sRed[2][tid] + sRed[3][tid]));
        float q = ((qRed[0][tid] + qRed[1][tid]) + (qRed[2][tid] + qRed[3][tid]));
        int oc = oc0 + tid;
        size_t slot = (((size_t)(c * 64 + oc)) * 4 + b) * 4 + rq;
        accP[slot] = s;
        accP[16384 + slot] = q;
    }
}

__global__ void k_conv1_fin(const float* __restrict__ accP, const float* __restrict__ g1,
                            const float* __restrict__ be1, float* __restrict__ sc,
                            float* __restrict__ sh) {
    int e = blockIdx.x * 256 + threadIdx.x;
    if (e >= 1024) return;
    int oc = e & 63;
    const float* ps = accP + (size_t)e * 16;
    const float* pq = accP + 16384 + (size_t)e * 16;
    float s = 0.f, q = 0.f;
#pragma unroll
    for (int i = 0; i < 16; ++i) { s += ps[i]; q += pq[i]; }
    float m = s * (1.f / 16384.f);
    float var = q * (1.f / 16384.f) - m * m;
    float sf = g1[oc] * rsqrtf(var + 1e-5f);
    sc[e] = sf;
    sh[e] = be1[oc] - m * sf;
}

__global__ __launch_bounds__(256) void k_conv1_apply3(
        const float* __restrict__ videos, const float* __restrict__ w1,
        const float* __restrict__ b1, const float* __restrict__ sc,
        const float* __restrict__ sh, float* __restrict__ x1p) {
    __shared__ float sP[3 * 18 * 66];
    __shared__ float wsm[3 * 9 * 16];
    int oc0 = blockIdx.x * 16, rq = blockIdx.y, n = blockIdx.z;
    int c = n >> 2, b = n & 3;
    int tid = threadIdx.x;
    int rp = tid >> 5, cq = tid & 31;
    for (int e = tid; e < 3564; e += 256) {
        int ic = e / 1188, rem = e % 1188;
        int r = rem / 66, col = rem % 66;
        int gr = rq * 16 - 1 + r, gc = col - 1;
        float v = 0.f;
        if (gr >= 0 && gr < 64 && gc >= 0 && gc < 64)
            v = videos[((size_t)(b * 3 + ic) * 32 + 2 * c) * 4096 + gr * 64 + gc];
        sP[e] = v;
    }
    for (int e = tid; e < 432; e += 256) {
        int ic = e / 144, rem = e % 144, k = rem / 16, j = rem % 16;
        wsm[e] = w1[((size_t)((oc0 + j) * 3 + ic) * 3 + 1) * 9 + k];
    }
    __syncthreads();
    float acc[4][16];
#pragma unroll
    for (int p = 0; p < 4; ++p)
#pragma unroll
        for (int j = 0; j < 16; ++j) acc[p][j] = 0.f;
#pragma unroll
    for (int ic = 0; ic < 3; ++ic) {
        const float* base = &sP[ic * 1188 + (2 * rp) * 66 + 2 * cq];
        float patch[4][4];
#pragma unroll
        for (int r = 0; r < 4; ++r)
#pragma unroll
            for (int q = 0; q < 4; ++q) patch[r][q] = base[r * 66 + q];
#pragma unroll
        for (int k = 0; k < 9; ++k) {
            int kr = k / 3, kc = k % 3;
            float4 w0 = *(const float4*)&wsm[(ic * 9 + k) * 16 + 0];
            float4 w1v = *(const float4*)&wsm[(ic * 9 + k) * 16 + 4];
            float4 w2 = *(const float4*)&wsm[(ic * 9 + k) * 16 + 8];
            float4 w3 = *(const float4*)&wsm[(ic * 9 + k) * 16 + 12];
#pragma unroll
            for (int p = 0; p < 4; ++p) {
                float vv = patch[(p >> 1) + kr][(p & 1) + kc];
                acc[p][0]  += vv * w0.x; acc[p][1]  += vv * w0.y;
                acc[p][2]  += vv * w0.z; acc[p][3]  += vv * w0.w;
                acc[p][4]  += vv * w1v.x; acc[p][5]  += vv * w1v.y;
                acc[p][6]  += vv * w1v.z; acc[p][7]  += vv * w1v.w;
                acc[p][8]  += vv * w2.x; acc[p][9]  += vv * w2.y;
                acc[p][10] += vv * w2.z; acc[p][11] += vv * w2.w;
                acc[p][12] += vv * w3.x; acc[p][13] += vv * w3.y;
                acc[p][14] += vv * w3.z; acc[p][15] += vv * w3.w;
            }
        }
    }
#pragma unroll
    for (int j = 0; j < 16; ++j) {
        int oc = oc0 + j;
        float bj = b1[oc];
        float scj = sc[c * 64 + oc], shj = sh[c * 64 + oc];
        float m = -1e30f;
#pragma unroll
        for (int p = 0; p < 4; ++p) m = fmaxf(m, (acc[p][j] + bj) * scj + shj);
        x1p[((size_t)n * 64 + oc) * 1024 + (rq * 8 + rp) * 32 + cq] = fmaxf(m, 0.f);
    }
}

// ============================================================================
// conv2: IC=64, 32x32, OC=128. Block = 32 oc x 8-row slab x 1 clip.
// grid (4 ocg, 4 slab, 64 n) = 1024 blocks. Thread = 4 oc x (2x4 px).
// Input halo stride 36 -> patch rows load as b128+b64. (R13 form.)
// ============================================================================
__global__ __launch_bounds__(256) void k_conv2(
        const float* __restrict__ in, const float* __restrict__ wt,
        const float* __restrict__ bias, float* __restrict__ out) {
    __shared__ __align__(16) float sIn[8 * 10 * 36];   // 2880
    __shared__ __align__(16) float sW[8 * 9 * 32];     // 2304
    int oc0 = blockIdx.x * 32, r0 = blockIdx.y * 8, n = blockIdx.z;
    int tid = threadIdx.x;
    int ocq = tid >> 5;          // 0..7
    int rg = (tid >> 3) & 3;     // rows r0+2rg, r0+2rg+1
    int cg = tid & 7;            // cols 4cg..4cg+3
    float acc[4][8];
#pragma unroll
    for (int j = 0; j < 4; ++j)
#pragma unroll
        for (int p = 0; p < 8; ++p) acc[j][p] = 0.f;

    for (int ic0 = 0; ic0 < 64; ic0 += 8) {
        __syncthreads();
        for (int e = tid; e < 2720; e += 256) {      // 8 ch x 10 rows x 34 cols
            int ch = e / 340, rem = e % 340;
            int r = rem / 34, col = rem % 34;
            int gr = r0 - 1 + r, gc = col - 1;
            float v = 0.f;
            if (gr >= 0 && gr < 32 && gc >= 0 && gc < 32)
                v = in[((size_t)(n * 64 + ic0 + ch) * 32 + gr) * 32 + gc];
            sIn[ch * 360 + r * 36 + col] = v;
        }
        for (int e = tid; e < 2304; e += 256) {
            int c = e / 288, r1 = e % 288, k = r1 / 32, j = r1 % 32;
            sW[e] = wt[((size_t)(oc0 + j) * 64 + ic0 + c) * 27 + 9 + k];
        }
        __syncthreads();
        for (int c = 0; c < 8; ++c) {
            const float* base = &sIn[c * 360 + (2 * rg) * 36 + 4 * cg];
            float patch[4][6];
#pragma unroll
            for (int r = 0; r < 4; ++r) {
                float4 p4 = *(const float4*)&base[r * 36];
                float2 p2 = *(const float2*)&base[r * 36 + 4];
                patch[r][0] = p4.x; patch[r][1] = p4.y; patch[r][2] = p4.z;
                patch[r][3] = p4.w; patch[r][4] = p2.x; patch[r][5] = p2.y;
            }
#pragma unroll
            for (int k = 0; k < 9; ++k) {
                int kr = k / 3, kc = k % 3;
                float4 w4 = *(const float4*)&sW[c * 288 + k * 32 + ocq * 4];
#pragma unroll
                for (int p = 0; p < 8; ++p) {
                    int pr = p >> 2, pcq = p & 3;
                    float vv = patch[pr + kr][pcq + kc];
                    acc[0][p] += vv * w4.x; acc[1][p] += vv * w4.y;
                    acc[2][p] += vv * w4.z; acc[3][p] += vv * w4.w;
                }
            }
        }
    }
#pragma unroll
    for (int j = 0; j < 4; ++j) {
        int oc = oc0 + ocq * 4 + j;
        float bj = bias[oc];
#pragma unroll
        for (int pr = 0; pr < 2; ++pr) {
            float4 o4 = make_float4(acc[j][pr * 4 + 0] + bj, acc[j][pr * 4 + 1] + bj,
                                    acc[j][pr * 4 + 2] + bj, acc[j][pr * 4 + 3] + bj);
            *(float4*)&out[((size_t)(n * 128 + oc) * 32 + r0 + 2 * rg + pr) * 32 + 4 * cg] = o4;
        }
    }
}

// ============================================================================
// conv3 split-IC partial: grid (8 ocg, 64 n, 2 half) = 1024 blocks -> 16
// waves/CU. Writes NO-bias partial sums to P[half]. Inner loop = R13.
// ============================================================================
__global__ __launch_bounds__(256) void k_conv3p(
        const float* __restrict__ in, const float* __restrict__ wt,
        float* __restrict__ outP) {
    __shared__ __align__(16) float sIn[8 * 18 * 20];   // 2880
    __shared__ __align__(16) float sW[8 * 9 * 32];     // 2304
    int oc0 = blockIdx.x * 32, n = blockIdx.y, half = blockIdx.z;
    int tid = threadIdx.x;
    int ocq = tid >> 5;          // 0..7
    int rg = (tid >> 2) & 7;     // rows 2rg, 2rg+1
    int cg = tid & 3;            // cols 4cg..4cg+3
    float acc[4][8];
#pragma unroll
    for (int j = 0; j < 4; ++j)
#pragma unroll
        for (int p = 0; p < 8; ++p) acc[j][p] = 0.f;

    int icB = half * 64;
    for (int ic0 = icB; ic0 < icB + 64; ic0 += 8) {
        __syncthreads();
        for (int e = tid; e < 2592; e += 256) {      // 8 ch x 18 rows x 18 cols
            int ch = e / 324, rem = e % 324;
            int r = rem / 18, cc = rem % 18;
            int gr = r - 1, gc = cc - 1;
            float v = 0.f;
            if (gr >= 0 && gr < 16 && gc >= 0 && gc < 16)
                v = in[((size_t)(n * 128 + ic0 + ch) * 16 + gr) * 16 + gc];
            sIn[ch * 360 + r * 20 + cc] = v;
        }
        for (int e = tid; e < 2304; e += 256) {
            int c = e / 288, r1 = e % 288, k = r1 / 32, j = r1 % 32;
            sW[e] = wt[((size_t)(oc0 + j) * 128 + ic0 + c) * 27 + 9 + k];
        }
        __syncthreads();
        for (int c = 0; c < 8; ++c) {
            const float* base = &sIn[c * 360 + (2 * rg) * 20 + 4 * cg];
            float patch[4][6];
#pragma unroll
            for (int r = 0; r < 4; ++r) {
                float4 p4 = *(const float4*)&base[r * 20];
                float2 p2 = *(const float2*)&base[r * 20 + 4];
                patch[r][0] = p4.x; patch[r][1] = p4.y; patch[r][2] = p4.z;
                patch[r][3] = p4.w; patch[r][4] = p2.x; patch[r][5] = p2.y;
            }
#pragma unroll
            for (int k = 0; k < 9; ++k) {
                int kr = k / 3, kc = k % 3;
                float4 w4 = *(const float4*)&sW[c * 288 + k * 32 + ocq * 4];
#pragma unroll
                for (int p = 0; p < 8; ++p) {
                    int pr = p >> 2, pcq = p & 3;
                    float vv = patch[pr + kr][pcq + kc];
                    acc[0][p] += vv * w4.x; acc[1][p] += vv * w4.y;
                    acc[2][p] += vv * w4.z; acc[3][p] += vv * w4.w;
                }
            }
        }
    }
    float* dst = outP + (size_t)half * 4194304;
#pragma unroll
    for (int j = 0; j < 4; ++j) {
        int oc = oc0 + ocq * 4 + j;
#pragma unroll
        for (int pr = 0; pr < 2; ++pr) {
            float4 o4 = make_float4(acc[j][pr * 4 + 0], acc[j][pr * 4 + 1],
                                    acc[j][pr * 4 + 2], acc[j][pr * 4 + 3]);
            *(float4*)&dst[((size_t)(n * 256 + oc) * 16 + 2 * rg + pr) * 16 + 4 * cg] = o4;
        }
    }
}

// BN stats over y3 = (P0+P1)+bias, computed on the fly (same expression and
// order as the old k_comb3 + k_bn_stats pair -> bit-identical). C=256, HW=256.
// Mean/var over 4 batch x 256 px = 1024 elems (R20 fix: inv was 1/262144).
__global__ void k_bn_stats3p(const float* __restrict__ P, const float* __restrict__ bias,
                             const float* __restrict__ g, const float* __restrict__ be,
                             float* __restrict__ scale, float* __restrict__ shift) {
    int c = blockIdx.x, ch = blockIdx.y, tid = threadIdx.x;
    float bj = bias[ch];
    float s = 0.f, s2 = 0.f;
    for (int b = 0; b < 4; ++b) {
        size_t base = ((size_t)(c * 4 + b) * 256 + ch) * 256;
        for (int i = tid; i < 256; i += 256) {
            size_t idx = base + i;
            float v = (P[idx] + P[idx + 4194304]) + bj;
            s += v; s2 += v * v;
        }
    }
    __shared__ float rs[256], rq[256];
    rs[tid] = s; rq[tid] = s2; __syncthreads();
    for (int k = 128; k > 0; k >>= 1) {
        if (tid < k) { rs[tid] += rs[tid + k]; rq[tid] += rq[tid + k]; }
        __syncthreads();
    }
    if (tid == 0) {
        float inv = 1.f / 1024.f;   // 4 * HW(=256)  [R20 fix]
        float m = rs[0] * inv, var = rq[0] * inv - m * m;
        float sc = g[ch] * rsqrtf(var + 1e-5f);
        scale[c * 256 + ch] = sc;
        shift[c * 256 + ch] = be[ch] - m * sc;
    }
}

// bn+relu+avgpool4 over y3 = (P0+P1)+bias on the fly (bit-identical values).
__global__ void k_bn_apply_avgpool4p(const float* __restrict__ P, const float* __restrict__ bias,
                                     const float* __restrict__ scale, const float* __restrict__ shift,
                                     float* __restrict__ out) {
    size_t idx = (size_t)blockIdx.x * 256 + threadIdx.x;  // 262,144
    int j = (int)(idx & 3), i = (int)(idx >> 2) & 3;
    int ch = (int)(idx >> 4) & 255, n = (int)(idx >> 12);
    int c = n >> 2;
    float bj = bias[ch];
    float sc = scale[c * 256 + ch], sh = shift[c * 256 + ch];
    size_t base = (((size_t)n * 256 + ch) * 16 + i * 4) * 16 + j * 4;
    float s = 0.f;
#pragma unroll
    for (int r = 0; r < 4; ++r)
#pragma unroll
        for (int q = 0; q < 4; ++q) {
            size_t pidx = base + r * 16 + q;
            float v = (P[pidx] + P[pidx + 4194304]) + bj;
            s += fmaxf(v * sc + sh, 0.f);
        }
    out[idx] = s * (1.f / 16.f);
}

// per-(clip,channel) BN stats (generic; used for y2 and y4)
__global__ void k_bn_stats(const float* __restrict__ buf, const float* __restrict__ g,
                           const float* __restrict__ be, float* __restrict__ scale,
                           float* __restrict__ shift, int C, int HW) {
    int c = blockIdx.x, ch = blockIdx.y, tid = threadIdx.x;
    float s = 0.f, s2 = 0.f;
    for (int b = 0; b < 4; ++b) {
        const float* p = buf + ((size_t)(c * 4 + b) * C + ch) * HW;
        for (int i = tid; i < HW; i += 256) { float v = p[i]; s += v; s2 += v * v; }
    }
    __shared__ float rs[256], rq[256];
    rs[tid] = s; rq[tid] = s2; __syncthreads();
    for (int k = 128; k > 0; k >>= 1) {
        if (tid < k) { rs[tid] += rs[tid + k]; rq[tid] += rq[tid + k]; }
        __syncthreads();
    }
    if (tid == 0) {
        float inv = 1.f / (float)(4 * HW);
        float m = rs[0] * inv, var = rq[0] * inv - m * m;
        float sc = g[ch] * rsqrtf(var + 1e-5f);
        scale[c * C + ch] = sc;
        shift[c * C + ch] = be[ch] - m * sc;
    }
}

__global__ void k_bn_apply_pool(const float* __restrict__ in, const float* __restrict__ scale,
                                const float* __restrict__ shift, float* __restrict__ out,
                                int C, int H, int W) {
    int OH = H >> 1, OW = W >> 1;
    size_t idx = (size_t)blockIdx.x * 256 + threadIdx.x;
    int ow = (int)(idx % OW);
    size_t r = idx / OW;
    int oh = (int)(r % OH); r /= OH;
    int ch = (int)(r % C);
    int n = (int)(r / C);
    int c = n >> 2;
    float sc = scale[c * C + ch], sh = shift[c * C + ch];
    const float* p = in + (((size_t)n * C + ch) * H + 2 * oh) * W + 2 * ow;
    float m = 0.f;
    m = fmaxf(m, p[0] * sc + sh);
    m = fmaxf(m, p[1] * sc + sh);
    m = fmaxf(m, p[W] * sc + sh);
    m = fmaxf(m, p[W + 1] * sc + sh);
    out[idx] = m;
}

__global__ void k_tconv(const float* __restrict__ x3p, const float* __restrict__ tw,
                        const float* __restrict__ tb, float* __restrict__ y4) {
    size_t idx = (size_t)blockIdx.x * 256 + threadIdx.x;  // 262,144
    int p = (int)(idx & 15), o = (int)(idx >> 4) & 255, n = (int)(idx >> 12);
    const float* xr = x3p + (size_t)n * 4096 + p;
    float a = tb[o];
    for (int i = 0; i < 256; ++i) a += xr[i * 16] * tw[((size_t)o * 256 + i) * 3 + 1];
    y4[idx] = a;
}

__global__ void k_bn_apply(const float* __restrict__ in, const float* __restrict__ scale,
                           const float* __restrict__ shift, float* __restrict__ out) {
    size_t idx = (size_t)blockIdx.x * 256 + threadIdx.x;  // 262,144
    int ch = (int)(idx >> 4) & 255, n = (int)(idx >> 12);
    int c = n >> 2;
    float sc = scale[c * 256 + ch], sh = shift[c * 256 + ch];
    out[idx] = fmaxf(in[idx] * sc + sh, 0.f);
}

// ============================================================================
// proj as deterministic split-K GEMM with row permutation in fin.
// ============================================================================
__global__ __launch_bounds__(256) void k_proj_part(
        const float* __restrict__ A, const float* __restrict__ B, float* __restrict__ PP) {
    __shared__ __align__(16) float As[64 * 68];
    __shared__ __align__(16) float Bs[64 * 68];
    int n0 = blockIdx.x * 64, ks = blockIdx.y;
    int tid = threadIdx.x, tm = tid >> 4, tn = tid & 15;
    float acc[4][4];
#pragma unroll
    for (int i = 0; i < 4; ++i)
#pragma unroll
        for (int j = 0; j < 4; ++j) acc[i][j] = 0.f;
    int kb = ks * 512;
    for (int k0 = kb; k0 < kb + 512; k0 += 64) {
        __syncthreads();
        for (int e = tid; e < 4096; e += 256) {
            int m = e >> 6, k = e & 63;
            As[k * 68 + m] = A[(size_t)m * 4096 + k0 + k];
            Bs[k * 68 + m] = B[(size_t)(n0 + m) * 4096 + k0 + k];
        }
        __syncthreads();
        for (int k = 0; k < 64; ++k) {
            float4 a4 = *(const float4*)&As[k * 68 + tm * 4];
            float4 b4 = *(const float4*)&Bs[k * 68 + tn * 4];
            acc[0][0] += a4.x * b4.x; acc[0][1] += a4.x * b4.y;
            acc[0][2] += a4.x * b4.z; acc[0][3] += a4.x * b4.w;
            acc[1][0] += a4.y * b4.x; acc[1][1] += a4.y * b4.y;
            acc[1][2] += a4.y * b4.z; acc[1][3] += a4.y * b4.w;
            acc[2][0] += a4.z * b4.x; acc[2][1] += a4.z * b4.y;
            acc[2][2] += a4.z * b4.z; acc[2][3] += a4.z * b4.w;
            acc[3][0] += a4.w * b4.x; acc[3][1] += a4.w * b4.y;
            acc[3][2] += a4.w * b4.z; acc[3][3] += a4.w * b4.w;
        }
    }
#pragma unroll
    for (int i = 0; i < 4; ++i)
#pragma unroll
        for (int j = 0; j < 4; ++j)
            PP[((size_t)(ks * 64 + tm * 4 + i)) * 512 + n0 + tn * 4 + j] = acc[i][j];
}

__global__ void k_proj_fin(const float* __restrict__ PP, const float* __restrict__ pb,
                           float* __restrict__ feat) {
    int e = blockIdx.x * 256 + threadIdx.x;  // 32768
    int n = e & 511;
    int m = e >> 9;               // x4 row (clip-major): m = c*4 + b
    float s = pb[n];
#pragma unroll
    for (int ks = 0; ks < 8; ++ks) s += PP[(size_t)ks * 32768 + e];
    int c = m >> 2, b = m & 3;
    int ro = b * 16 + c;          // feat row (batch-major)
    feat[(size_t)ro * 512 + n] = s;
}

// VQ argmin; min distance -> commitArr[row] (deterministic)
__global__ void k_vq(const float* __restrict__ feat, const float* __restrict__ cb,
                     float* __restrict__ quant, float* __restrict__ commitArr) {
    int row = blockIdx.x, tid = threadIdx.x;
    __shared__ float f[512];
    for (int k = tid; k < 512; k += 256) f[k] = feat[(size_t)row * 512 + k];
    __syncthreads();
    float best = 3.4e38f; int bidx = 0;
    for (int j = tid; j < 1024; j += 256) {
        const float* c = cb + (size_t)j * 512;
        float d2 = 0.f;
        for (int k = 0; k < 512; ++k) { float t = f[k] - c[k]; d2 += t * t; }
        if (d2 < best) { best = d2; bidx = j; }
    }
    __shared__ float rd[256]; __shared__ int ri[256];
    rd[tid] = best; ri[tid] = bidx; __syncthreads();
    for (int k = 128; k > 0; k >>= 1) {
        if (tid < k) {
            float od = rd[tid + k]; int oi = ri[tid + k];
            if (od < rd[tid] || (od == rd[tid] && oi < ri[tid])) { rd[tid] = od; ri[tid] = oi; }
        }
        __syncthreads();
    }
    __shared__ int wsel;
    if (tid == 0) { wsel = ri[0]; commitArr[row] = rd[0]; }
    __syncthreads();
    const float* c = cb + (size_t)wsel * 512;
    for (int k = tid; k < 512; k += 256) quant[(size_t)row * 512 + k] = c[k];
}

// ---- GRU helpers -----------------------------------------------------------
__device__ __forceinline__ void gru_gi_one(
        const float* __restrict__ xsRow, const float* __restrict__ wih,
        const float* __restrict__ bih, float* __restrict__ gi, int row, int d) {
    const float4* xp = (const float4*)xsRow;
    const float4* wr = (const float4*)(wih + (size_t)d * 512);
    float a0 = 0.f, a1 = 0.f, a2 = 0.f, a3 = 0.f;
    for (int i = 0; i < 128; i += 4) {
        float4 w0 = wr[i], w1 = wr[i + 1], w2 = wr[i + 2], w3 = wr[i + 3];
        float4 x0 = xp[i], x1 = xp[i + 1], x2 = xp[i + 2], x3 = xp[i + 3];
        a0 += w0.x * x0.x + w0.y * x0.y + w0.z * x0.z + w0.w * x0.w;
        a1 += w1.x * x1.x + w1.y * x1.y + w1.z * x1.z + w1.w * x1.w;
        a2 += w2.x * x2.x + w2.y * x2.y + w2.z * x2.z + w2.w * x2.w;
        a3 += w3.x * x3.x + w3.y * x3.y + w3.z * x3.z + w3.w * x3.w;
    }
    gi[(size_t)row * 1536 + d] = (a0 + a1) + (a2 + a3) + bih[d];
}

__device__ __forceinline__ void gru_step_body(
        const float* __restrict__ gi, const float* __restrict__ whh,
        const float* __restrict__ bhh, float* __restrict__ hseq, int t, int blk) {
    int wv = threadIdx.x >> 6, lane = threadIdx.x & 63;
    int d = blk * 4 + wv;
    const float4* w0p = (const float4*)(whh + (size_t)d * 512);
    const float4* w1p = (const float4*)(whh + (size_t)(512 + d) * 512);
    const float4* w2p = (const float4*)(whh + (size_t)(1024 + d) * 512);
    float4 w0a = w0p[lane * 2], w0b = w0p[lane * 2 + 1];
    float4 w1a = w1p[lane * 2], w1b = w1p[lane * 2 + 1];
    float4 w2a = w2p[lane * 2], w2b = w2p[lane * 2 + 1];
    float bh0 = bhh[d], bh1 = bhh[512 + d], bh2 = bhh[1024 + d];
    for (int b = 0; b < 4; ++b) {
        float4 ha = make_float4(0, 0, 0, 0), hb = ha;
        float hpd = 0.f;
        if (t > 0) {
            const float4* hp = (const float4*)(hseq + (size_t)(b * 16 + t - 1) * 512);
            ha = hp[lane * 2]; hb = hp[lane * 2 + 1];
            hpd = hseq[(size_t)(b * 16 + t - 1) * 512 + d];
        }
        float s0 = w0a.x * ha.x + w0a.y * ha.y + w0a.z * ha.z + w0a.w * ha.w
                 + w0b.x * hb.x + w0b.y * hb.y + w0b.z * hb.z + w0b.w * hb.w;
        float s1 = w1a.x * ha.x + w1a.y * ha.y + w1a.z * ha.z + w1a.w * ha.w
                 + w1b.x * hb.x + w1b.y * hb.y + w1b.z * hb.z + w1b.w * hb.w;
        float s2 = w2a.x * ha.x + w2a.y * ha.y + w2a.z * ha.z + w2a.w * ha.w
                 + w2b.x * hb.x + w2b.y * hb.y + w2b.z * hb.z + w2b.w * hb.w;
#pragma unroll
        for (int m = 1; m < 64; m <<= 1) {
            s0 += __shfl_xor(s0, m);
            s1 += __shfl_xor(s1, m);
            s2 += __shfl_xor(s2, m);
        }
        const float* gr = gi + (size_t)(b * 16 + t) * 1536;
        float rr = 1.f / (1.f + expf(-(gr[d] + s0 + bh0)));
        float zz = 1.f / (1.f + expf(-(gr[512 + d] + s1 + bh1)));
        float nn = tanhf(gr[1024 + d] + rr * (s2 + bh2));
        if (lane == 0)
            hseq[(size_t)(b * 16 + t) * 512 + d] = (1.f - zz) * nn + zz * hpd;
    }
}

// Layer-1 gi, spread: grid 360 = 60 rows x 6 parts, 1 dim/thread.
__global__ void k_gru_gi6(const float* __restrict__ x, const float* __restrict__ wih,
                          const float* __restrict__ bih, float* __restrict__ gi) {
    int g = blockIdx.x;
    int r = g / 6, part = g % 6;
    int b = r / 15, t = r % 15;
    int row = b * 16 + t;
    __shared__ float xsRow[512];
    for (int k = threadIdx.x; k < 512; k += 256) xsRow[k] = x[(size_t)row * 512 + k];
    __syncthreads();
    gru_gi_one(xsRow, wih, bih, gi, row, part * 256 + threadIdx.x);
}

// ============================================================================
// GRU pipeline launch t = 0..16 (R15 form, grid 280):
//   blocks   0..127 : layer-1 step t        (t in [0,14])
//   blocks 128..255 : layer-2 step t-2      (t in [2,16])
//   blocks 256..279 : gi2 rows for time t-1 (t in [1,15])
// All sections touch disjoint rows -> no intra-launch dependency.
// ============================================================================
__global__ __launch_bounds__(256) void k_gru_pipe(
        const float* __restrict__ gi1, const float* __restrict__ whh0,
        const float* __restrict__ bhh0, float* __restrict__ h1,
        const float* __restrict__ wih1, const float* __restrict__ bih1,
        float* __restrict__ gi2, const float* __restrict__ whh1,
        const float* __restrict__ bhh1, float* __restrict__ h2, int t) {
    int bid = blockIdx.x;
    if (bid < 128) {
        if (t < 15) gru_step_body(gi1, whh0, bhh0, h1, t, bid);
    } else if (bid < 256) {
        if (t >= 2) gru_step_body(gi2, whh1, bhh1, h2, t - 2, bid - 128);
    } else {
        if (t >= 1 && t <= 15) {
            int local = bid - 256;          // 0..23
            int b = local / 6, part = local % 6;
            int row = b * 16 + (t - 1);
            __shared__ float xsRow[512];
            for (int k = threadIdx.x; k < 512; k += 256)
                xsRow[k] = h1[(size_t)row * 512 + k];
            __syncthreads();
            gru_gi_one(xsRow, wih1, bih1, gi2, row, part * 256 + threadIdx.x);
        }
    }
}

// ctx loss partials -> ctxArr[block] (deterministic)
__global__ void k_ctx_loss(const float* __restrict__ h2, const float* __restrict__ feat,
                           float* __restrict__ ctxArr) {
    int tid = threadIdx.x;
    size_t idx = (size_t)blockIdx.x * 256 + tid;  // 30720
    int d = (int)(idx & 511);
    int rt = (int)(idx >> 9);
    int t = rt % 15, b = rt / 15;
    float diff = h2[(size_t)(b * 16 + t) * 512 + d] - feat[(size_t)(b * 16 + t + 1) * 512 + d];
    float v = diff * diff;
#pragma unroll
    for (int m = 1; m < 64; m <<= 1) v += __shfl_xor(v, m);
    __shared__ float ws[4];
    if ((tid & 63) == 0) ws[tid >> 6] = v;
    __syncthreads();
    if (tid == 0) ctxArr[blockIdx.x] = ((ws[0] + ws[1]) + (ws[2] + ws[3]));
}

__global__ void k_word_vq(const float* __restrict__ quant, const float* __restrict__ wcb,
                          float* __restrict__ wemb, float* __restrict__ out_widx) {
    int row = blockIdx.x;  // b*8+wi
    int b = row >> 3, wi = row & 7;
    int tid = threadIdx.x;
    __shared__ float f[512];
    for (int k = tid; k < 512; k += 256)
        f[k] = 0.5f * (quant[(size_t)(b * 16 + 2 * wi) * 512 + k] +
                       quant[(size_t)(b * 16 + 2 * wi + 1) * 512 + k]);
    __syncthreads();
    const float* cp = wcb + (size_t)tid * 512;
    float d2 = 0.f;
    for (int k = 0; k < 512; ++k) { float t = f[k] - cp[k]; d2 += t * t; }
    __shared__ float rd[256]; __shared__ int ri[256];
    rd[tid] = d2; ri[tid] = tid; __syncthreads();
    for (int k = 128; k > 0; k >>= 1) {
        if (tid < k) {
            float od = rd[tid + k]; int oi = ri[tid + k];
            if (od < rd[tid] || (od == rd[tid] && oi < ri[tid])) { rd[tid] = od; ri[tid] = oi; }
        }
        __syncthreads();
    }
    __shared__ int wsel;
    if (tid == 0) { wsel = ri[0]; out_widx[row] = (float)ri[0]; }
    __syncthreads();
    const float* cb = wcb + (size_t)wsel * 512;
    for (int k = tid; k < 512; k += 256) wemb[(size_t)row * 512 + k] = cb[k];
}

// alignment partials -> alignArr[row] (deterministic)
__global__ void k_align(const float* __restrict__ wemb, const float* __restrict__ aw,
                        const float* __restrict__ ab, float* __restrict__ alignArr) {
    int row = blockIdx.x, tid = threadIdx.x;
    __shared__ float e[512];
    for (int k = tid; k < 512; k += 256) e[k] = wemb[(size_t)row * 512 + k];
    __syncthreads();
    float local = 0.f;
    for (int d = tid; d < 512; d += 256) {
        const float* wr = aw + (size_t)d * 512;
        float a = ab[d] - e[d];
        for (int k = 0; k < 512; ++k) a += e[k] * wr[k];
        local += a * a;
    }
    __shared__ float rs[256];
    rs[tid] = local; __syncthreads();
    for (int k = 128; k > 0; k >>= 1) { if (tid < k) rs[tid] += rs[tid + k]; __syncthreads(); }
    if (tid == 0) alignArr[row] = rs[0];
}

__global__ void k_ctx(const float* __restrict__ wemb, float* __restrict__ ctx) {
    int e = blockIdx.x * 256 + threadIdx.x;  // 2048
    int b = e >> 9, d = e & 511;
    float s = 0.f;
#pragma unroll
    for (int wi = 0; wi < 8; ++wi) s += wemb[(size_t)(b * 8 + wi) * 512 + d];
    ctx[e] = s * 0.125f;
}

// small-M (M=4) GEMV: C[4,N] = A[4,K] @ B[N,K]^T + bias, optional relu.
__global__ void k_smallM(const float* __restrict__ A, const float* __restrict__ B,
                         const float* __restrict__ bias, float* __restrict__ C,
                         int N, int K, int relu) {
    __shared__ float xs[4096];
    int tid = threadIdx.x;
    for (int e = tid; e < 4 * K; e += 256) xs[e] = A[e];
    __syncthreads();
    int r = tid >> 4, kt = tid & 15;
    int n = blockIdx.x * 16 + r;
    float acc[4] = {0, 0, 0, 0};
    if (n < N) {
        int iters = K >> 6;
        for (int i = 0; i < iters; ++i) {
            int k = i * 64 + kt * 4;
            float4 w = *(const float4*)&B[(size_t)n * K + k];
#pragma unroll
            for (int b = 0; b < 4; ++b) {
                float4 x = *(const float4*)&xs[b * K + k];
                acc[b] += w.x * x.x + w.y * x.y + w.z * x.z + w.w * x.w;
            }
        }
    }
#pragma unroll
    for (int b = 0; b < 4; ++b) {
#pragma unroll
        for (int m = 1; m < 16; m <<= 1) acc[b] += __shfl_xor(acc[b], m);
    }
    if (kt == 0 && n < N) {
#pragma unroll
        for (int b = 0; b < 4; ++b) {
            float v = acc[b] + bias[n];
            if (relu) v = fmaxf(v, 0.f);
            C[(size_t)b * N + n] = v;
        }
    }
}

// log-softmax CE + deterministic fixed-order sum of all loss partials
__global__ void k_final(const float* __restrict__ logits, const int* __restrict__ tokens,
                        const float* __restrict__ commitArr, const float* __restrict__ ctxArr,
                        const float* __restrict__ alignArr, float* __restrict__ out_total) {
    int tid = threadIdx.x;
    __shared__ float rs[256];
    __shared__ float sM;
    float tr = 0.f;
    for (int b = 0; b < 4; ++b) {
        const float* lg = logits + (size_t)b * 3000;
        float m = -1e30f;
        for (int d = tid; d < 3000; d += 256) m = fmaxf(m, lg[d]);
        rs[tid] = m; __syncthreads();
        for (int k = 128; k > 0; k >>= 1) { if (tid < k) rs[tid] = fmaxf(rs[tid], rs[tid + k]); __syncthreads(); }
        if (tid == 0) sM = rs[0];
        __syncthreads();
        float M = sM;
        float s = 0.f;
        for (int d = tid; d < 3000; d += 256) s += expf(lg[d] - M);
        rs[tid] = s; __syncthreads();
        for (int k = 128; k > 0; k >>= 1) { if (tid < k) rs[tid] += rs[tid + k]; __syncthreads(); }
        if (tid == 0) {
            int t0 = tokens[b * 10];
            tr += -(lg[t0] - M - logf(rs[0]));
        }
        __syncthreads();
    }
    if (tid == 0) {
        float c0 = 0.f;
        for (int i = 0; i < 64; ++i) c0 += commitArr[i];
        float c1 = 0.f;
        for (int i = 0; i < 120; ++i) c1 += ctxArr[i];
        float c2 = 0.f;
        for (int i = 0; i < 32; ++i) c2 += alignArr[i];
        float total = 1.25f * c0 * (1.f / 32768.f)
                    + 0.1f  * c1 * (1.f / 30720.f)
                    + 0.1f  * c2 * (1.f / 16384.f)
                    + tr;
        *out_total = total;
    }
}

extern "C" void kernel_launch(void* const* d_in, const int* in_sizes, int n_in,
                              void* d_out, int out_size, void* d_ws, size_t ws_size,
                              hipStream_t stream) {
    (void)in_sizes; (void)n_in; (void)out_size; (void)ws_size;
    const float* videos   = (const float*)d_in[0];
    const float* conv1_w  = (const float*)d_in[1];
    const float* conv1_b  = (const float*)d_in[2];
    const float* bn1_g    = (const float*)d_in[3];
    const float* bn1_b    = (const float*)d_in[4];
    const float* conv2_w  = (const float*)d_in[5];
    const float* conv2_b  = (const float*)d_in[6];
    const float* bn2_g    = (const float*)d_in[7];
    const float* bn2_b    = (const float*)d_in[8];
    const float* conv3_w  = (const float*)d_in[9];
    const float* conv3_b  = (const float*)d_in[10];
    const float* bn3_g    = (const float*)d_in[11];
    const float* bn3_b    = (const float*)d_in[12];
    const float* tconv_w  = (const float*)d_in[13];
    const float* tconv_b  = (const float*)d_in[14];
    const float* bn4_g    = (const float*)d_in[15];
    const float* bn4_b    = (const float*)d_in[16];
    const float* proj_w   = (const float*)d_in[17];
    const float* proj_b   = (const float*)d_in[18];
    const float* codebook = (const float*)d_in[19];
    const float* word_cb  = (const float*)d_in[20];
    const float* align_w  = (const float*)d_in[21];
    const float* align_b  = (const float*)d_in[22];
    const float* gru_wih0 = (const float*)d_in[23];
    const float* gru_whh0 = (const float*)d_in[24];
    const float* gru_bih0 = (const float*)d_in[25];
    const float* gru_bhh0 = (const float*)d_in[26];
    const float* gru_wih1 = (const float*)d_in[27];
    const float* gru_whh1 = (const float*)d_in[28];
    const float* gru_bih1 = (const float*)d_in[29];
    const float* gru_bhh1 = (const float*)d_in[30];
    const float* dec1_w   = (const float*)d_in[31];
    const float* dec1_b   = (const float*)d_in[32];
    const float* dec2_w   = (const float*)d_in[33];
    const float* dec2_b   = (const float*)d_in[34];
    const float* dec3_w   = (const float*)d_in[35];
    const float* dec3_b   = (const float*)d_in[36];
    const int*   tokens   = (const int*)d_in[37];

    float* wsf    = (float*)d_ws;
    float* out    = (float*)d_out;
    float* x1p    = wsf + OFF_X1P;
    float* x2p    = wsf + OFF_X2P;
    float* y2     = wsf + OFF_Y2;
    float* y3     = wsf + OFF_Y3;   // conv3 partial base (P0; P1 at +4,194,304)
    float* x3p    = wsf + OFF_X3P;
    float* y4     = wsf + OFF_Y4;
    float* x4     = wsf + OFF_X4;
    float* feat   = wsf + OFF_FEAT;
    float* quant  = wsf + OFF_QUANT;
    float* gi1    = wsf + OFF_GI1;
    float* gi2    = wsf + OFF_GI2;
    float* h1     = wsf + OFF_H1;
    float* h2     = wsf + OFF_H2;
    float* wemb   = wsf + OFF_WEMB;
    float* ctx    = wsf + OFF_CTX;
    float* hh1    = wsf + OFF_HH1;
    float* hh2    = wsf + OFF_HH2;
    float* logit  = wsf + OFF_LOG;
    float* pp     = wsf + OFF_PP;
    float* sc     = wsf + OFF_SC;
    float* sh     = wsf + OFF_SH;
    float* accP   = wsf + OFF_ACCP;
    float* commitA= wsf + OFF_COMMIT;
    float* ctxA   = wsf + OFF_CTXA;
    float* alignA = wsf + OFF_ALIGNA;

    // conv1 + bn1 + pool
    k_conv1_stats3<<<dim3(4, 4, 64), 256, 0, stream>>>(videos, conv1_w, conv1_b, accP);
    k_conv1_fin<<<4, 256, 0, stream>>>(accP, bn1_g, bn1_b, sc, sh);
    k_conv1_apply3<<<dim3(4, 4, 64), 256, 0, stream>>>(videos, conv1_w, conv1_b, sc, sh, x1p);
    // conv2 + bn2 + pool
    k_conv2<<<dim3(4, 4, 64), 256, 0, stream>>>(x1p, conv2_w, conv2_b, y2);
    k_bn_stats<<<dim3(16, 128), 256, 0, stream>>>(y2, bn2_g, bn2_b, sc, sh, 128, 1024);
    k_bn_apply_pool<<<8192, 256, 0, stream>>>(y2, sc, sh, x2p, 128, 32, 32);
    // conv3 (split-IC 2-way) + fused stats/apply over (P0+P1)+bias
    k_conv3p<<<dim3(8, 64, 2), 256, 0, stream>>>(x2p, conv3_w, y3);
    k_bn_stats3p<<<dim3(16, 256), 256, 0, stream>>>(y3, conv3_b, bn3_g, bn3_b, sc, sh);
    k_bn_apply_avgpool4p<<<1024, 256, 0, stream>>>(y3, conv3_b, sc, sh, x3p);
    k_tconv<<<1024, 256, 0, stream>>>(x3p, tconv_w, tconv_b, y4);
    k_bn_stats<<<dim3(16, 256), 256, 0, stream>>>(y4, bn4_g, bn4_b, sc, sh, 256, 16);
    k_bn_apply<<<1024, 256, 0, stream>>>(y4, sc, sh, x4);
    // projection (deterministic split-K GEMM, row permutation in fin)
    k_proj_part<<<dim3(8, 8), 256, 0, stream>>>(x4, proj_w, pp);
    k_proj_fin<<<128, 256, 0, stream>>>(pp, proj_b, feat);
    k_vq<<<64, 256, 0, stream>>>(feat, codebook, quant, commitA);
    // GRU: layer-1 gi (spread over all CUs), then 17-launch two-layer pipeline
    k_gru_gi6<<<360, 256, 0, stream>>>(quant, gru_wih0, gru_bih0, gi1);
    for (int t = 0; t <= 16; ++t)
        k_gru_pipe<<<280, 256, 0, stream>>>(gi1, gru_whh0, gru_bhh0, h1,
                                            gru_wih1, gru_bih1, gi2,
                                            gru_whh1, gru_bhh1, h2, t);
    k_ctx_loss<<<120, 256, 0, stream>>>(h2, feat, ctxA);
    // word VQ + alignment
    k_word_vq<<<32, 256, 0, stream>>>(quant, word_cb, wemb, out);
    k_align<<<32, 256, 0, stream>>>(wemb, align_w, align_b, alignA);
    // decoder
    k_ctx<<<8, 256, 0, stream>>>(wemb, ctx);
    k_smallM<<<32, 256, 0, stream>>>(ctx, dec1_w, dec1_b, hh1, 512, 512, 1);
    k_smallM<<<64, 256, 0, stream>>>(hh1, dec2_w, dec2_b, hh2, 1024, 512, 1);
    k_smallM<<<188, 256, 0, stream>>>(hh2, dec3_w, dec3_b, logit, 3000, 1024, 0);
    k_final<<<1, 256, 0, stream>>>(logit, tokens, commitA, ctxA, alignA, out + 32);
}

// Round 11
// 1052.388 us; speedup vs baseline: 1.0843x; 1.0406x over previous
//
#include <hip/hip_runtime.h>

// ============================================================================
// SignLLM forward, fp32. B=4, T=32 -> nc=16 clips, D=512.
// Output: d_out[0..31] = widx (4,8) as float, d_out[32] = total loss.
// R21: re-land the R18 tail piggyback on the FIXED R20 base. Evidence of
// innocence: R18 (fusion-bug + piggyback) and R19 (fusion-bug only) failed
// with byte-identical absmax (242.0) -> the piggyback computed the same
// (correct-given-inputs) widx as the standalone path; the sole bug was
// k_bn_stats3p's 1/262144 constant, fixed in R20 (1/1024, passed 1095us).
// Piggyback: word_vq/align/ctx/dec1/dec2/dec3 run as extra block sections
// of k_gru_pipe t=0..5 (grid 280->468; GPU ~99% idle during pipe launches).
// Each section reads only data finalized in a PREVIOUS launch; branches
// uniform per block; arithmetic verbatim -> bit-identical (absmax 0.0).
// conv3 = R17 split-IC + R20 BN fusion. conv2 = R13. 33 launches (was 39).
// Zero atomics anywhere (deterministic).
// ============================================================================

// ---- workspace layout (float offsets), peak ~12.62M floats = 50.5 MB ----
static const size_t OFF_X1P  = 0;         // (64,64,32,32)  4,194,304  [dead after conv2]
static const size_t OFF_Y2   = 4194304;   // (64,128,32,32) 8,388,608  -> ends 12,582,912
static const size_t OFF_X2P  = 0;         // (64,128,16,16) 2,097,152  [x1p dead]
static const size_t OFF_Y3   = 4194304;   // conv3 partial P0 (4,194,304)
static const size_t OFF_Y3P1 = 8388608;   // conv3 partial P1 (4,194,304) -> ends 12,582,912
static const size_t OFF_X3P  = 2097152;   // 262,144
static const size_t OFF_Y4   = 2359296;   // 262,144
static const size_t OFF_X4   = 2621440;   // 262,144
static const size_t OFF_FEAT = 2883584;   // (64,512) 32,768
static const size_t OFF_QUANT= 2916352;   // 32,768
static const size_t OFF_GI1  = 2949120;   // (64,1536) 98,304 (rows b*16+t)
static const size_t OFF_GI2  = 3047424;   // 98,304
static const size_t OFF_H1   = 3145728;   // (64,512) rows b*16+t
static const size_t OFF_H2   = 3178496;   // 32,768
static const size_t OFF_WEMB = 3211264;   // (32,512) 16,384
static const size_t OFF_CTX  = 3227648;   // 2,048
static const size_t OFF_HH1  = 3229696;   // 2,048
static const size_t OFF_HH2  = 3231744;   // 4,096
static const size_t OFF_LOG  = 3235840;   // 12,000 -> ends 3,247,840
static const size_t OFF_PP   = 3247840;   // proj partials (8,64,512) 262,144
// long-lived block PAST y2's end (12,582,912):
static const size_t OFF_SC    = 12582912; // 4,096
static const size_t OFF_SH    = 12587008; // 4,096
static const size_t OFF_ACCP  = 12591104; // 32,768: conv1 stats (s:16384, q:16384)
static const size_t OFF_COMMIT= 12623872; // 64
static const size_t OFF_CTXA  = 12623936; // 120
static const size_t OFF_ALIGNA= 12624056; // 32

// ============================================================================
// conv1 (IC=3, 64x64, pad 1, mid temporal slice). Block = (ocg, rq, n),
// 256 thr = 2x2px x 16oc. Deterministic per-(c,oc,b,rq) stats partials.
// ============================================================================
__global__ __launch_bounds__(256) void k_conv1_stats3(
        const float* __restrict__ videos, const float* __restrict__ w1,
        const float* __restrict__ b1, float* __restrict__ accP) {
    __shared__ float sP[3 * 18 * 66];
    __shared__ float wsm[3 * 9 * 16];
    __shared__ float sRed[4][16], qRed[4][16];
    int oc0 = blockIdx.x * 16, rq = blockIdx.y, n = blockIdx.z;
    int c = n >> 2, b = n & 3;
    int tid = threadIdx.x;
    int rp = tid >> 5, cq = tid & 31;
    for (int e = tid; e < 3564; e += 256) {
        int ic = e / 1188, rem = e % 1188;
        int r = rem / 66, col = rem % 66;
        int gr = rq * 16 - 1 + r, gc = col - 1;
        float v = 0.f;
        if (gr >= 0 && gr < 64 && gc >= 0 && gc < 64)
            v = videos[((size_t)(b * 3 + ic) * 32 + 2 * c) * 4096 + gr * 64 + gc];
        sP[e] = v;
    }
    for (int e = tid; e < 432; e += 256) {
        int ic = e / 144, rem = e % 144, k = rem / 16, j = rem % 16;
        wsm[e] = w1[((size_t)((oc0 + j) * 3 + ic) * 3 + 1) * 9 + k];
    }
    __syncthreads();
    float acc[4][16];
#pragma unroll
    for (int p = 0; p < 4; ++p)
#pragma unroll
        for (int j = 0; j < 16; ++j) acc[p][j] = 0.f;
#pragma unroll
    for (int ic = 0; ic < 3; ++ic) {
        const float* base = &sP[ic * 1188 + (2 * rp) * 66 + 2 * cq];
        float patch[4][4];
#pragma unroll
        for (int r = 0; r < 4; ++r)
#pragma unroll
            for (int q = 0; q < 4; ++q) patch[r][q] = base[r * 66 + q];
#pragma unroll
        for (int k = 0; k < 9; ++k) {
            int kr = k / 3, kc = k % 3;
            float4 w0 = *(const float4*)&wsm[(ic * 9 + k) * 16 + 0];
            float4 w1v = *(const float4*)&wsm[(ic * 9 + k) * 16 + 4];
            float4 w2 = *(const float4*)&wsm[(ic * 9 + k) * 16 + 8];
            float4 w3 = *(const float4*)&wsm[(ic * 9 + k) * 16 + 12];
#pragma unroll
            for (int p = 0; p < 4; ++p) {
                float vv = patch[(p >> 1) + kr][(p & 1) + kc];
                acc[p][0]  += vv * w0.x; acc[p][1]  += vv * w0.y;
                acc[p][2]  += vv * w0.z; acc[p][3]  += vv * w0.w;
                acc[p][4]  += vv * w1v.x; acc[p][5]  += vv * w1v.y;
                acc[p][6]  += vv * w1v.z; acc[p][7]  += vv * w1v.w;
                acc[p][8]  += vv * w2.x; acc[p][9]  += vv * w2.y;
                acc[p][10] += vv * w2.z; acc[p][11] += vv * w2.w;
                acc[p][12] += vv * w3.x; acc[p][13] += vv * w3.y;
                acc[p][14] += vv * w3.z; acc[p][15] += vv * w3.w;
            }
        }
    }
    int lane = tid & 63, wave = tid >> 6;
#pragma unroll
    for (int j = 0; j < 16; ++j) {
        float bj = b1[oc0 + j];
        float s = 0.f, q = 0.f;
#pragma unroll
        for (int p = 0; p < 4; ++p) {
            float a = acc[p][j] + bj;
            s += a; q += a * a;
        }
#pragma unroll
        for (int m = 1; m < 64; m <<= 1) {
            s += __shfl_xor(s, m);
            q += __shfl_xor(q, m);
        }
        if (lane == 0) { sRed[wave][j] = s; qRed[wave][j] = q; }
    }
    __syncthreads();
    if (tid < 16) {
        float s = ((sRed[0][tid] + sRed[1][tid]) + (sRed[2][tid] + sRed[3][tid]));
        float q = ((qRed[0][tid] + qRed[1][tid]) + (qRed[2][tid] + qRed[3][tid]));
        int oc = oc0 + tid;
        size_t slot = (((size_t)(c * 64 + oc)) * 4 + b) * 4 + rq;
        accP[slot] = s;
        accP[16384 + slot] = q;
    }
}

__global__ void k_conv1_fin(const float* __restrict__ accP, const float* __restrict__ g1,
                            const float* __restrict__ be1, float* __restrict__ sc,
                            float* __restrict__ sh) {
    int e = blockIdx.x * 256 + threadIdx.x;
    if (e >= 1024) return;
    int oc = e & 63;
    const float* ps = accP + (size_t)e * 16;
    const float* pq = accP + 16384 + (size_t)e * 16;
    float s = 0.f, q = 0.f;
#pragma unroll
    for (int i = 0; i < 16; ++i) { s += ps[i]; q += pq[i]; }
    float m = s * (1.f / 16384.f);
    float var = q * (1.f / 16384.f) - m * m;
    float sf = g1[oc] * rsqrtf(var + 1e-5f);
    sc[e] = sf;
    sh[e] = be1[oc] - m * sf;
}

__global__ __launch_bounds__(256) void k_conv1_apply3(
        const float* __restrict__ videos, const float* __restrict__ w1,
        const float* __restrict__ b1, const float* __restrict__ sc,
        const float* __restrict__ sh, float* __restrict__ x1p) {
    __shared__ float sP[3 * 18 * 66];
    __shared__ float wsm[3 * 9 * 16];
    int oc0 = blockIdx.x * 16, rq = blockIdx.y, n = blockIdx.z;
    int c = n >> 2, b = n & 3;
    int tid = threadIdx.x;
    int rp = tid >> 5, cq = tid & 31;
    for (int e = tid; e < 3564; e += 256) {
        int ic = e / 1188, rem = e % 1188;
        int r = rem / 66, col = rem % 66;
        int gr = rq * 16 - 1 + r, gc = col - 1;
        float v = 0.f;
        if (gr >= 0 && gr < 64 && gc >= 0 && gc < 64)
            v = videos[((size_t)(b * 3 + ic) * 32 + 2 * c) * 4096 + gr * 64 + gc];
        sP[e] = v;
    }
    for (int e = tid; e < 432; e += 256) {
        int ic = e / 144, rem = e % 144, k = rem / 16, j = rem % 16;
        wsm[e] = w1[((size_t)((oc0 + j) * 3 + ic) * 3 + 1) * 9 + k];
    }
    __syncthreads();
    float acc[4][16];
#pragma unroll
    for (int p = 0; p < 4; ++p)
#pragma unroll
        for (int j = 0; j < 16; ++j) acc[p][j] = 0.f;
#pragma unroll
    for (int ic = 0; ic < 3; ++ic) {
        const float* base = &sP[ic * 1188 + (2 * rp) * 66 + 2 * cq];
        float patch[4][4];
#pragma unroll
        for (int r = 0; r < 4; ++r)
#pragma unroll
            for (int q = 0; q < 4; ++q) patch[r][q] = base[r * 66 + q];
#pragma unroll
        for (int k = 0; k < 9; ++k) {
            int kr = k / 3, kc = k % 3;
            float4 w0 = *(const float4*)&wsm[(ic * 9 + k) * 16 + 0];
            float4 w1v = *(const float4*)&wsm[(ic * 9 + k) * 16 + 4];
            float4 w2 = *(const float4*)&wsm[(ic * 9 + k) * 16 + 8];
            float4 w3 = *(const float4*)&wsm[(ic * 9 + k) * 16 + 12];
#pragma unroll
            for (int p = 0; p < 4; ++p) {
                float vv = patch[(p >> 1) + kr][(p & 1) + kc];
                acc[p][0]  += vv * w0.x; acc[p][1]  += vv * w0.y;
                acc[p][2]  += vv * w0.z; acc[p][3]  += vv * w0.w;
                acc[p][4]  += vv * w1v.x; acc[p][5]  += vv * w1v.y;
                acc[p][6]  += vv * w1v.z; acc[p][7]  += vv * w1v.w;
                acc[p][8]  += vv * w2.x; acc[p][9]  += vv * w2.y;
                acc[p][10] += vv * w2.z; acc[p][11] += vv * w2.w;
                acc[p][12] += vv * w3.x; acc[p][13] += vv * w3.y;
                acc[p][14] += vv * w3.z; acc[p][15] += vv * w3.w;
            }
        }
    }
#pragma unroll
    for (int j = 0; j < 16; ++j) {
        int oc = oc0 + j;
        float bj = b1[oc];
        float scj = sc[c * 64 + oc], shj = sh[c * 64 + oc];
        float m = -1e30f;
#pragma unroll
        for (int p = 0; p < 4; ++p) m = fmaxf(m, (acc[p][j] + bj) * scj + shj);
        x1p[((size_t)n * 64 + oc) * 1024 + (rq * 8 + rp) * 32 + cq] = fmaxf(m, 0.f);
    }
}

// ============================================================================
// conv2: IC=64, 32x32, OC=128. Block = 32 oc x 8-row slab x 1 clip.
// grid (4 ocg, 4 slab, 64 n) = 1024 blocks. Thread = 4 oc x (2x4 px).
// Input halo stride 36 -> patch rows load as b128+b64. (R13 form.)
// ============================================================================
__global__ __launch_bounds__(256) void k_conv2(
        const float* __restrict__ in, const float* __restrict__ wt,
        const float* __restrict__ bias, float* __restrict__ out) {
    __shared__ __align__(16) float sIn[8 * 10 * 36];   // 2880
    __shared__ __align__(16) float sW[8 * 9 * 32];     // 2304
    int oc0 = blockIdx.x * 32, r0 = blockIdx.y * 8, n = blockIdx.z;
    int tid = threadIdx.x;
    int ocq = tid >> 5;          // 0..7
    int rg = (tid >> 3) & 3;     // rows r0+2rg, r0+2rg+1
    int cg = tid & 7;            // cols 4cg..4cg+3
    float acc[4][8];
#pragma unroll
    for (int j = 0; j < 4; ++j)
#pragma unroll
        for (int p = 0; p < 8; ++p) acc[j][p] = 0.f;

    for (int ic0 = 0; ic0 < 64; ic0 += 8) {
        __syncthreads();
        for (int e = tid; e < 2720; e += 256) {      // 8 ch x 10 rows x 34 cols
            int ch = e / 340, rem = e % 340;
            int r = rem / 34, col = rem % 34;
            int gr = r0 - 1 + r, gc = col - 1;
            float v = 0.f;
            if (gr >= 0 && gr < 32 && gc >= 0 && gc < 32)
                v = in[((size_t)(n * 64 + ic0 + ch) * 32 + gr) * 32 + gc];
            sIn[ch * 360 + r * 36 + col] = v;
        }
        for (int e = tid; e < 2304; e += 256) {
            int c = e / 288, r1 = e % 288, k = r1 / 32, j = r1 % 32;
            sW[e] = wt[((size_t)(oc0 + j) * 64 + ic0 + c) * 27 + 9 + k];
        }
        __syncthreads();
        for (int c = 0; c < 8; ++c) {
            const float* base = &sIn[c * 360 + (2 * rg) * 36 + 4 * cg];
            float patch[4][6];
#pragma unroll
            for (int r = 0; r < 4; ++r) {
                float4 p4 = *(const float4*)&base[r * 36];
                float2 p2 = *(const float2*)&base[r * 36 + 4];
                patch[r][0] = p4.x; patch[r][1] = p4.y; patch[r][2] = p4.z;
                patch[r][3] = p4.w; patch[r][4] = p2.x; patch[r][5] = p2.y;
            }
#pragma unroll
            for (int k = 0; k < 9; ++k) {
                int kr = k / 3, kc = k % 3;
                float4 w4 = *(const float4*)&sW[c * 288 + k * 32 + ocq * 4];
#pragma unroll
                for (int p = 0; p < 8; ++p) {
                    int pr = p >> 2, pcq = p & 3;
                    float vv = patch[pr + kr][pcq + kc];
                    acc[0][p] += vv * w4.x; acc[1][p] += vv * w4.y;
                    acc[2][p] += vv * w4.z; acc[3][p] += vv * w4.w;
                }
            }
        }
    }
#pragma unroll
    for (int j = 0; j < 4; ++j) {
        int oc = oc0 + ocq * 4 + j;
        float bj = bias[oc];
#pragma unroll
        for (int pr = 0; pr < 2; ++pr) {
            float4 o4 = make_float4(acc[j][pr * 4 + 0] + bj, acc[j][pr * 4 + 1] + bj,
                                    acc[j][pr * 4 + 2] + bj, acc[j][pr * 4 + 3] + bj);
            *(float4*)&out[((size_t)(n * 128 + oc) * 32 + r0 + 2 * rg + pr) * 32 + 4 * cg] = o4;
        }
    }
}

// ============================================================================
// conv3 split-IC partial: grid (8 ocg, 64 n, 2 half) = 1024 blocks -> 16
// waves/CU. Writes NO-bias partial sums to P[half]. Inner loop = R13.
// ============================================================================
__global__ __launch_bounds__(256) void k_conv3p(
        const float* __restrict__ in, const float* __restrict__ wt,
        float* __restrict__ outP) {
    __shared__ __align__(16) float sIn[8 * 18 * 20];   // 2880
    __shared__ __align__(16) float sW[8 * 9 * 32];     // 2304
    int oc0 = blockIdx.x * 32, n = blockIdx.y, half = blockIdx.z;
    int tid = threadIdx.x;
    int ocq = tid >> 5;          // 0..7
    int rg = (tid >> 2) & 7;     // rows 2rg, 2rg+1
    int cg = tid & 3;            // cols 4cg..4cg+3
    float acc[4][8];
#pragma unroll
    for (int j = 0; j < 4; ++j)
#pragma unroll
        for (int p = 0; p < 8; ++p) acc[j][p] = 0.f;

    int icB = half * 64;
    for (int ic0 = icB; ic0 < icB + 64; ic0 += 8) {
        __syncthreads();
        for (int e = tid; e < 2592; e += 256) {      // 8 ch x 18 rows x 18 cols
            int ch = e / 324, rem = e % 324;
            int r = rem / 18, cc = rem % 18;
            int gr = r - 1, gc = cc - 1;
            float v = 0.f;
            if (gr >= 0 && gr < 16 && gc >= 0 && gc < 16)
                v = in[((size_t)(n * 128 + ic0 + ch) * 16 + gr) * 16 + gc];
            sIn[ch * 360 + r * 20 + cc] = v;
        }
        for (int e = tid; e < 2304; e += 256) {
            int c = e / 288, r1 = e % 288, k = r1 / 32, j = r1 % 32;
            sW[e] = wt[((size_t)(oc0 + j) * 128 + ic0 + c) * 27 + 9 + k];
        }
        __syncthreads();
        for (int c = 0; c < 8; ++c) {
            const float* base = &sIn[c * 360 + (2 * rg) * 20 + 4 * cg];
            float patch[4][6];
#pragma unroll
            for (int r = 0; r < 4; ++r) {
                float4 p4 = *(const float4*)&base[r * 20];
                float2 p2 = *(const float2*)&base[r * 20 + 4];
                patch[r][0] = p4.x; patch[r][1] = p4.y; patch[r][2] = p4.z;
                patch[r][3] = p4.w; patch[r][4] = p2.x; patch[r][5] = p2.y;
            }
#pragma unroll
            for (int k = 0; k < 9; ++k) {
                int kr = k / 3, kc = k % 3;
                float4 w4 = *(const float4*)&sW[c * 288 + k * 32 + ocq * 4];
#pragma unroll
                for (int p = 0; p < 8; ++p) {
                    int pr = p >> 2, pcq = p & 3;
                    float vv = patch[pr + kr][pcq + kc];
                    acc[0][p] += vv * w4.x; acc[1][p] += vv * w4.y;
                    acc[2][p] += vv * w4.z; acc[3][p] += vv * w4.w;
                }
            }
        }
    }
    float* dst = outP + (size_t)half * 4194304;
#pragma unroll
    for (int j = 0; j < 4; ++j) {
        int oc = oc0 + ocq * 4 + j;
#pragma unroll
        for (int pr = 0; pr < 2; ++pr) {
            float4 o4 = make_float4(acc[j][pr * 4 + 0], acc[j][pr * 4 + 1],
                                    acc[j][pr * 4 + 2], acc[j][pr * 4 + 3]);
            *(float4*)&dst[((size_t)(n * 256 + oc) * 16 + 2 * rg + pr) * 16 + 4 * cg] = o4;
        }
    }
}

// BN stats over y3 = (P0+P1)+bias, computed on the fly. C=256, HW=256.
// Mean/var over 4 batch x 256 px = 1024 elems.
__global__ void k_bn_stats3p(const float* __restrict__ P, const float* __restrict__ bias,
                             const float* __restrict__ g, const float* __restrict__ be,
                             float* __restrict__ scale, float* __restrict__ shift) {
    int c = blockIdx.x, ch = blockIdx.y, tid = threadIdx.x;
    float bj = bias[ch];
    float s = 0.f, s2 = 0.f;
    for (int b = 0; b < 4; ++b) {
        size_t base = ((size_t)(c * 4 + b) * 256 + ch) * 256;
        for (int i = tid; i < 256; i += 256) {
            size_t idx = base + i;
            float v = (P[idx] + P[idx + 4194304]) + bj;
            s += v; s2 += v * v;
        }
    }
    __shared__ float rs[256], rq[256];
    rs[tid] = s; rq[tid] = s2; __syncthreads();
    for (int k = 128; k > 0; k >>= 1) {
        if (tid < k) { rs[tid] += rs[tid + k]; rq[tid] += rq[tid + k]; }
        __syncthreads();
    }
    if (tid == 0) {
        float inv = 1.f / 1024.f;   // 4 * HW(=256)
        float m = rs[0] * inv, var = rq[0] * inv - m * m;
        float sc = g[ch] * rsqrtf(var + 1e-5f);
        scale[c * 256 + ch] = sc;
        shift[c * 256 + ch] = be[ch] - m * sc;
    }
}

// bn+relu+avgpool4 over y3 = (P0+P1)+bias on the fly (bit-identical values).
__global__ void k_bn_apply_avgpool4p(const float* __restrict__ P, const float* __restrict__ bias,
                                     const float* __restrict__ scale, const float* __restrict__ shift,
                                     float* __restrict__ out) {
    size_t idx = (size_t)blockIdx.x * 256 + threadIdx.x;  // 262,144
    int j = (int)(idx & 3), i = (int)(idx >> 2) & 3;
    int ch = (int)(idx >> 4) & 255, n = (int)(idx >> 12);
    int c = n >> 2;
    float bj = bias[ch];
    float sc = scale[c * 256 + ch], sh = shift[c * 256 + ch];
    size_t base = (((size_t)n * 256 + ch) * 16 + i * 4) * 16 + j * 4;
    float s = 0.f;
#pragma unroll
    for (int r = 0; r < 4; ++r)
#pragma unroll
        for (int q = 0; q < 4; ++q) {
            size_t pidx = base + r * 16 + q;
            float v = (P[pidx] + P[pidx + 4194304]) + bj;
            s += fmaxf(v * sc + sh, 0.f);
        }
    out[idx] = s * (1.f / 16.f);
}

// per-(clip,channel) BN stats (generic; used for y2 and y4)
__global__ void k_bn_stats(const float* __restrict__ buf, const float* __restrict__ g,
                           const float* __restrict__ be, float* __restrict__ scale,
                           float* __restrict__ shift, int C, int HW) {
    int c = blockIdx.x, ch = blockIdx.y, tid = threadIdx.x;
    float s = 0.f, s2 = 0.f;
    for (int b = 0; b < 4; ++b) {
        const float* p = buf + ((size_t)(c * 4 + b) * C + ch) * HW;
        for (int i = tid; i < HW; i += 256) { float v = p[i]; s += v; s2 += v * v; }
    }
    __shared__ float rs[256], rq[256];
    rs[tid] = s; rq[tid] = s2; __syncthreads();
    for (int k = 128; k > 0; k >>= 1) {
        if (tid < k) { rs[tid] += rs[tid + k]; rq[tid] += rq[tid + k]; }
        __syncthreads();
    }
    if (tid == 0) {
        float inv = 1.f / (float)(4 * HW);
        float m = rs[0] * inv, var = rq[0] * inv - m * m;
        float sc = g[ch] * rsqrtf(var + 1e-5f);
        scale[c * C + ch] = sc;
        shift[c * C + ch] = be[ch] - m * sc;
    }
}

__global__ void k_bn_apply_pool(const float* __restrict__ in, const float* __restrict__ scale,
                                const float* __restrict__ shift, float* __restrict__ out,
                                int C, int H, int W) {
    int OH = H >> 1, OW = W >> 1;
    size_t idx = (size_t)blockIdx.x * 256 + threadIdx.x;
    int ow = (int)(idx % OW);
    size_t r = idx / OW;
    int oh = (int)(r % OH); r /= OH;
    int ch = (int)(r % C);
    int n = (int)(r / C);
    int c = n >> 2;
    float sc = scale[c * C + ch], sh = shift[c * C + ch];
    const float* p = in + (((size_t)n * C + ch) * H + 2 * oh) * W + 2 * ow;
    float m = 0.f;
    m = fmaxf(m, p[0] * sc + sh);
    m = fmaxf(m, p[1] * sc + sh);
    m = fmaxf(m, p[W] * sc + sh);
    m = fmaxf(m, p[W + 1] * sc + sh);
    out[idx] = m;
}

__global__ void k_tconv(const float* __restrict__ x3p, const float* __restrict__ tw,
                        const float* __restrict__ tb, float* __restrict__ y4) {
    size_t idx = (size_t)blockIdx.x * 256 + threadIdx.x;  // 262,144
    int p = (int)(idx & 15), o = (int)(idx >> 4) & 255, n = (int)(idx >> 12);
    const float* xr = x3p + (size_t)n * 4096 + p;
    float a = tb[o];
    for (int i = 0; i < 256; ++i) a += xr[i * 16] * tw[((size_t)o * 256 + i) * 3 + 1];
    y4[idx] = a;
}

__global__ void k_bn_apply(const float* __restrict__ in, const float* __restrict__ scale,
                           const float* __restrict__ shift, float* __restrict__ out) {
    size_t idx = (size_t)blockIdx.x * 256 + threadIdx.x;  // 262,144
    int ch = (int)(idx >> 4) & 255, n = (int)(idx >> 12);
    int c = n >> 2;
    float sc = scale[c * 256 + ch], sh = shift[c * 256 + ch];
    out[idx] = fmaxf(in[idx] * sc + sh, 0.f);
}

// ============================================================================
// proj as deterministic split-K GEMM with row permutation in fin.
// ============================================================================
__global__ __launch_bounds__(256) void k_proj_part(
        const float* __restrict__ A, const float* __restrict__ B, float* __restrict__ PP) {
    __shared__ __align__(16) float As[64 * 68];
    __shared__ __align__(16) float Bs[64 * 68];
    int n0 = blockIdx.x * 64, ks = blockIdx.y;
    int tid = threadIdx.x, tm = tid >> 4, tn = tid & 15;
    float acc[4][4];
#pragma unroll
    for (int i = 0; i < 4; ++i)
#pragma unroll
        for (int j = 0; j < 4; ++j) acc[i][j] = 0.f;
    int kb = ks * 512;
    for (int k0 = kb; k0 < kb + 512; k0 += 64) {
        __syncthreads();
        for (int e = tid; e < 4096; e += 256) {
            int m = e >> 6, k = e & 63;
            As[k * 68 + m] = A[(size_t)m * 4096 + k0 + k];
            Bs[k * 68 + m] = B[(size_t)(n0 + m) * 4096 + k0 + k];
        }
        __syncthreads();
        for (int k = 0; k < 64; ++k) {
            float4 a4 = *(const float4*)&As[k * 68 + tm * 4];
            float4 b4 = *(const float4*)&Bs[k * 68 + tn * 4];
            acc[0][0] += a4.x * b4.x; acc[0][1] += a4.x * b4.y;
            acc[0][2] += a4.x * b4.z; acc[0][3] += a4.x * b4.w;
            acc[1][0] += a4.y * b4.x; acc[1][1] += a4.y * b4.y;
            acc[1][2] += a4.y * b4.z; acc[1][3] += a4.y * b4.w;
            acc[2][0] += a4.z * b4.x; acc[2][1] += a4.z * b4.y;
            acc[2][2] += a4.z * b4.z; acc[2][3] += a4.z * b4.w;
            acc[3][0] += a4.w * b4.x; acc[3][1] += a4.w * b4.y;
            acc[3][2] += a4.w * b4.z; acc[3][3] += a4.w * b4.w;
        }
    }
#pragma unroll
    for (int i = 0; i < 4; ++i)
#pragma unroll
        for (int j = 0; j < 4; ++j)
            PP[((size_t)(ks * 64 + tm * 4 + i)) * 512 + n0 + tn * 4 + j] = acc[i][j];
}

__global__ void k_proj_fin(const float* __restrict__ PP, const float* __restrict__ pb,
                           float* __restrict__ feat) {
    int e = blockIdx.x * 256 + threadIdx.x;  // 32768
    int n = e & 511;
    int m = e >> 9;               // x4 row (clip-major): m = c*4 + b
    float s = pb[n];
#pragma unroll
    for (int ks = 0; ks < 8; ++ks) s += PP[(size_t)ks * 32768 + e];
    int c = m >> 2, b = m & 3;
    int ro = b * 16 + c;          // feat row (batch-major)
    feat[(size_t)ro * 512 + n] = s;
}

// VQ argmin; min distance -> commitArr[row] (deterministic)
__global__ void k_vq(const float* __restrict__ feat, const float* __restrict__ cb,
                     float* __restrict__ quant, float* __restrict__ commitArr) {
    int row = blockIdx.x, tid = threadIdx.x;
    __shared__ float f[512];
    for (int k = tid; k < 512; k += 256) f[k] = feat[(size_t)row * 512 + k];
    __syncthreads();
    float best = 3.4e38f; int bidx = 0;
    for (int j = tid; j < 1024; j += 256) {
        const float* c = cb + (size_t)j * 512;
        float d2 = 0.f;
        for (int k = 0; k < 512; ++k) { float t = f[k] - c[k]; d2 += t * t; }
        if (d2 < best) { best = d2; bidx = j; }
    }
    __shared__ float rd[256]; __shared__ int ri[256];
    rd[tid] = best; ri[tid] = bidx; __syncthreads();
    for (int k = 128; k > 0; k >>= 1) {
        if (tid < k) {
            float od = rd[tid + k]; int oi = ri[tid + k];
            if (od < rd[tid] || (od == rd[tid] && oi < ri[tid])) { rd[tid] = od; ri[tid] = oi; }
        }
        __syncthreads();
    }
    __shared__ int wsel;
    if (tid == 0) { wsel = ri[0]; commitArr[row] = rd[0]; }
    __syncthreads();
    const float* c = cb + (size_t)wsel * 512;
    for (int k = tid; k < 512; k += 256) quant[(size_t)row * 512 + k] = c[k];
}

// ---- GRU helpers -----------------------------------------------------------
__device__ __forceinline__ void gru_gi_one(
        const float* __restrict__ xsRow, const float* __restrict__ wih,
        const float* __restrict__ bih, float* __restrict__ gi, int row, int d) {
    const float4* xp = (const float4*)xsRow;
    const float4* wr = (const float4*)(wih + (size_t)d * 512);
    float a0 = 0.f, a1 = 0.f, a2 = 0.f, a3 = 0.f;
    for (int i = 0; i < 128; i += 4) {
        float4 w0 = wr[i], w1 = wr[i + 1], w2 = wr[i + 2], w3 = wr[i + 3];
        float4 x0 = xp[i], x1 = xp[i + 1], x2 = xp[i + 2], x3 = xp[i + 3];
        a0 += w0.x * x0.x + w0.y * x0.y + w0.z * x0.z + w0.w * x0.w;
        a1 += w1.x * x1.x + w1.y * x1.y + w1.z * x1.z + w1.w * x1.w;
        a2 += w2.x * x2.x + w2.y * x2.y + w2.z * x2.z + w2.w * x2.w;
        a3 += w3.x * x3.x + w3.y * x3.y + w3.z * x3.z + w3.w * x3.w;
    }
    gi[(size_t)row * 1536 + d] = (a0 + a1) + (a2 + a3) + bih[d];
}

__device__ __forceinline__ void gru_step_body(
        const float* __restrict__ gi, const float* __restrict__ whh,
        const float* __restrict__ bhh, float* __restrict__ hseq, int t, int blk) {
    int wv = threadIdx.x >> 6, lane = threadIdx.x & 63;
    int d = blk * 4 + wv;
    const float4* w0p = (const float4*)(whh + (size_t)d * 512);
    const float4* w1p = (const float4*)(whh + (size_t)(512 + d) * 512);
    const float4* w2p = (const float4*)(whh + (size_t)(1024 + d) * 512);
    float4 w0a = w0p[lane * 2], w0b = w0p[lane * 2 + 1];
    float4 w1a = w1p[lane * 2], w1b = w1p[lane * 2 + 1];
    float4 w2a = w2p[lane * 2], w2b = w2p[lane * 2 + 1];
    float bh0 = bhh[d], bh1 = bhh[512 + d], bh2 = bhh[1024 + d];
    for (int b = 0; b < 4; ++b) {
        float4 ha = make_float4(0, 0, 0, 0), hb = ha;
        float hpd = 0.f;
        if (t > 0) {
            const float4* hp = (const float4*)(hseq + (size_t)(b * 16 + t - 1) * 512);
            ha = hp[lane * 2]; hb = hp[lane * 2 + 1];
            hpd = hseq[(size_t)(b * 16 + t - 1) * 512 + d];
        }
        float s0 = w0a.x * ha.x + w0a.y * ha.y + w0a.z * ha.z + w0a.w * ha.w
                 + w0b.x * hb.x + w0b.y * hb.y + w0b.z * hb.z + w0b.w * hb.w;
        float s1 = w1a.x * ha.x + w1a.y * ha.y + w1a.z * ha.z + w1a.w * ha.w
                 + w1b.x * hb.x + w1b.y * hb.y + w1b.z * hb.z + w1b.w * hb.w;
        float s2 = w2a.x * ha.x + w2a.y * ha.y + w2a.z * ha.z + w2a.w * ha.w
                 + w2b.x * hb.x + w2b.y * hb.y + w2b.z * hb.z + w2b.w * hb.w;
#pragma unroll
        for (int m = 1; m < 64; m <<= 1) {
            s0 += __shfl_xor(s0, m);
            s1 += __shfl_xor(s1, m);
            s2 += __shfl_xor(s2, m);
        }
        const float* gr = gi + (size_t)(b * 16 + t) * 1536;
        float rr = 1.f / (1.f + expf(-(gr[d] + s0 + bh0)));
        float zz = 1.f / (1.f + expf(-(gr[512 + d] + s1 + bh1)));
        float nn = tanhf(gr[1024 + d] + rr * (s2 + bh2));
        if (lane == 0)
            hseq[(size_t)(b * 16 + t) * 512 + d] = (1.f - zz) * nn + zz * hpd;
    }
}

// small-M (M=4) GEMV section: C[4,N] = A[4,K] @ B[N,K]^T + bias, optional relu.
__device__ __forceinline__ void dev_smallM(float* xs, const float* __restrict__ A,
                                           const float* __restrict__ B,
                                           const float* __restrict__ bias,
                                           float* __restrict__ C,
                                           int N, int K, int relu, int blk) {
    int tid = threadIdx.x;
    for (int e = tid; e < 4 * K; e += 256) xs[e] = A[e];
    __syncthreads();
    int r = tid >> 4, kt = tid & 15;
    int n = blk * 16 + r;
    float acc[4] = {0, 0, 0, 0};
    if (n < N) {
        int iters = K >> 6;
        for (int i = 0; i < iters; ++i) {
            int k = i * 64 + kt * 4;
            float4 w = *(const float4*)&B[(size_t)n * K + k];
#pragma unroll
            for (int b = 0; b < 4; ++b) {
                float4 x = *(const float4*)&xs[b * K + k];
                acc[b] += w.x * x.x + w.y * x.y + w.z * x.z + w.w * x.w;
            }
        }
    }
#pragma unroll
    for (int b = 0; b < 4; ++b) {
#pragma unroll
        for (int m = 1; m < 16; m <<= 1) acc[b] += __shfl_xor(acc[b], m);
    }
    if (kt == 0 && n < N) {
#pragma unroll
        for (int b = 0; b < 4; ++b) {
            float v = acc[b] + bias[n];
            if (relu) v = fmaxf(v, 0.f);
            C[(size_t)b * N + n] = v;
        }
    }
}

// Layer-1 gi, spread: grid 360 = 60 rows x 6 parts, 1 dim/thread.
__global__ void k_gru_gi6(const float* __restrict__ x, const float* __restrict__ wih,
                          const float* __restrict__ bih, float* __restrict__ gi) {
    int g = blockIdx.x;
    int r = g / 6, part = g % 6;
    int b = r / 15, t = r % 15;
    int row = b * 16 + t;
    __shared__ float xsRow[512];
    for (int k = threadIdx.x; k < 512; k += 256) xsRow[k] = x[(size_t)row * 512 + k];
    __syncthreads();
    gru_gi_one(xsRow, wih, bih, gi, row, part * 256 + threadIdx.x);
}

// ============================================================================
// GRU pipeline launch t = 0..16, grid 468:
//   blocks   0..127 : layer-1 step t        (t in [0,14])
//   blocks 128..255 : layer-2 step t-2      (t in [2,16])
//   blocks 256..279 : gi2 rows for time t-1 (t in [1,15])
//   blocks 280..467 : piggybacked tail sections (each reads only data
//     finalized in a PREVIOUS launch; all writes disjoint from GRU rows):
//       t=0: word_vq (32 blk)  t=1: align (32)  t=2: ctx (8)
//       t=3: dec1 (32)         t=4: dec2 (64)   t=5: dec3 (188)
// ============================================================================
__global__ __launch_bounds__(256) void k_gru_pipe(
        const float* __restrict__ gi1, const float* __restrict__ whh0,
        const float* __restrict__ bhh0, float* __restrict__ h1,
        const float* __restrict__ wih1, const float* __restrict__ bih1,
        float* __restrict__ gi2, const float* __restrict__ whh1,
        const float* __restrict__ bhh1, float* __restrict__ h2,
        const float* __restrict__ quant, const float* __restrict__ wcb,
        float* __restrict__ wemb, float* __restrict__ out_widx,
        const float* __restrict__ aw, const float* __restrict__ ab,
        float* __restrict__ alignArr, float* __restrict__ ctxB,
        const float* __restrict__ dec1_w, const float* __restrict__ dec1_b,
        float* __restrict__ hh1, const float* __restrict__ dec2_w,
        const float* __restrict__ dec2_b, float* __restrict__ hh2,
        const float* __restrict__ dec3_w, const float* __restrict__ dec3_b,
        float* __restrict__ logit, int t) {
    __shared__ float shbuf[4096];
    __shared__ float redf[256];
    __shared__ int   redi[256];
    __shared__ int   wsel_s;
    int bid = blockIdx.x;
    int tid = threadIdx.x;
    if (bid < 128) {
        if (t < 15) gru_step_body(gi1, whh0, bhh0, h1, t, bid);
    } else if (bid < 256) {
        if (t >= 2) gru_step_body(gi2, whh1, bhh1, h2, t - 2, bid - 128);
    } else if (bid < 280) {
        if (t >= 1 && t <= 15) {
            int local = bid - 256;          // 0..23
            int b = local / 6, part = local % 6;
            int row = b * 16 + (t - 1);
            for (int k = tid; k < 512; k += 256)
                shbuf[k] = h1[(size_t)row * 512 + k];
            __syncthreads();
            gru_gi_one(shbuf, wih1, bih1, gi2, row, part * 256 + tid);
        }
    } else {
        int tb = bid - 280;
        if (t == 0) {
            if (tb < 32) {
                // word_vq row=tb (verbatim k_word_vq arithmetic)
                int b = tb >> 3, wi = tb & 7;
                for (int k = tid; k < 512; k += 256)
                    shbuf[k] = 0.5f * (quant[(size_t)(b * 16 + 2 * wi) * 512 + k] +
                                       quant[(size_t)(b * 16 + 2 * wi + 1) * 512 + k]);
                __syncthreads();
                const float* cp = wcb + (size_t)tid * 512;
                float d2 = 0.f;
                for (int k = 0; k < 512; ++k) { float tt = shbuf[k] - cp[k]; d2 += tt * tt; }
                redf[tid] = d2; redi[tid] = tid; __syncthreads();
                for (int k = 128; k > 0; k >>= 1) {
                    if (tid < k) {
                        float od = redf[tid + k]; int oi = redi[tid + k];
                        if (od < redf[tid] || (od == redf[tid] && oi < redi[tid])) {
                            redf[tid] = od; redi[tid] = oi;
                        }
                    }
                    __syncthreads();
                }
                if (tid == 0) { wsel_s = redi[0]; out_widx[tb] = (float)redi[0]; }
                __syncthreads();
                const float* cb = wcb + (size_t)wsel_s * 512;
                for (int k = tid; k < 512; k += 256)
                    wemb[(size_t)tb * 512 + k] = cb[k];
            }
        } else if (t == 1) {
            if (tb < 32) {
                // align row=tb (verbatim k_align arithmetic)
                for (int k = tid; k < 512; k += 256)
                    shbuf[k] = wemb[(size_t)tb * 512 + k];
                __syncthreads();
                float local = 0.f;
                for (int d = tid; d < 512; d += 256) {
                    const float* wr = aw + (size_t)d * 512;
                    float a = ab[d] - shbuf[d];
                    for (int k = 0; k < 512; ++k) a += shbuf[k] * wr[k];
                    local += a * a;
                }
                redf[tid] = local; __syncthreads();
                for (int k = 128; k > 0; k >>= 1) {
                    if (tid < k) redf[tid] += redf[tid + k];
                    __syncthreads();
                }
                if (tid == 0) alignArr[tb] = redf[0];
            }
        } else if (t == 2) {
            if (tb < 8) {
                int e = tb * 256 + tid;   // 2048
                int b = e >> 9, d = e & 511;
                float s = 0.f;
#pragma unroll
                for (int wi = 0; wi < 8; ++wi) s += wemb[(size_t)(b * 8 + wi) * 512 + d];
                ctxB[e] = s * 0.125f;
            }
        } else if (t == 3) {
            if (tb < 32) dev_smallM(shbuf, ctxB, dec1_w, dec1_b, hh1, 512, 512, 1, tb);
        } else if (t == 4) {
            if (tb < 64) dev_smallM(shbuf, hh1, dec2_w, dec2_b, hh2, 1024, 512, 1, tb);
        } else if (t == 5) {
            if (tb < 188) dev_smallM(shbuf, hh2, dec3_w, dec3_b, logit, 3000, 1024, 0, tb);
        }
    }
}

// ctx loss partials -> ctxArr[block] (deterministic)
__global__ void k_ctx_loss(const float* __restrict__ h2, const float* __restrict__ feat,
                           float* __restrict__ ctxArr) {
    int tid = threadIdx.x;
    size_t idx = (size_t)blockIdx.x * 256 + tid;  // 30720
    int d = (int)(idx & 511);
    int rt = (int)(idx >> 9);
    int t = rt % 15, b = rt / 15;
    float diff = h2[(size_t)(b * 16 + t) * 512 + d] - feat[(size_t)(b * 16 + t + 1) * 512 + d];
    float v = diff * diff;
#pragma unroll
    for (int m = 1; m < 64; m <<= 1) v += __shfl_xor(v, m);
    __shared__ float ws[4];
    if ((tid & 63) == 0) ws[tid >> 6] = v;
    __syncthreads();
    if (tid == 0) ctxArr[blockIdx.x] = ((ws[0] + ws[1]) + (ws[2] + ws[3]));
}

// log-softmax CE + deterministic fixed-order sum of all loss partials
__global__ void k_final(const float* __restrict__ logits, const int* __restrict__ tokens,
                        const float* __restrict__ commitArr, const float* __restrict__ ctxArr,
                        const float* __restrict__ alignArr, float* __restrict__ out_total) {
    int tid = threadIdx.x;
    __shared__ float rs[256];
    __shared__ float sM;
    float tr = 0.f;
    for (int b = 0; b < 4; ++b) {
        const float* lg = logits + (size_t)b * 3000;
        float m = -1e30f;
        for (int d = tid; d < 3000; d += 256) m = fmaxf(m, lg[d]);
        rs[tid] = m; __syncthreads();
        for (int k = 128; k > 0; k >>= 1) { if (tid < k) rs[tid] = fmaxf(rs[tid], rs[tid + k]); __syncthreads(); }
        if (tid == 0) sM = rs[0];
        __syncthreads();
        float M = sM;
        float s = 0.f;
        for (int d = tid; d < 3000; d += 256) s += expf(lg[d] - M);
        rs[tid] = s; __syncthreads();
        for (int k = 128; k > 0; k >>= 1) { if (tid < k) rs[tid] += rs[tid + k]; __syncthreads(); }
        if (tid == 0) {
            int t0 = tokens[b * 10];
            tr += -(lg[t0] - M - logf(rs[0]));
        }
        __syncthreads();
    }
    if (tid == 0) {
        float c0 = 0.f;
        for (int i = 0; i < 64; ++i) c0 += commitArr[i];
        float c1 = 0.f;
        for (int i = 0; i < 120; ++i) c1 += ctxArr[i];
        float c2 = 0.f;
        for (int i = 0; i < 32; ++i) c2 += alignArr[i];
        float total = 1.25f * c0 * (1.f / 32768.f)
                    + 0.1f  * c1 * (1.f / 30720.f)
                    + 0.1f  * c2 * (1.f / 16384.f)
                    + tr;
        *out_total = total;
    }
}

extern "C" void kernel_launch(void* const* d_in, const int* in_sizes, int n_in,
                              void* d_out, int out_size, void* d_ws, size_t ws_size,
                              hipStream_t stream) {
    (void)in_sizes; (void)n_in; (void)out_size; (void)ws_size;
    const float* videos   = (const float*)d_in[0];
    const float* conv1_w  = (const float*)d_in[1];
    const float* conv1_b  = (const float*)d_in[2];
    const float* bn1_g    = (const float*)d_in[3];
    const float* bn1_b    = (const float*)d_in[4];
    const float* conv2_w  = (const float*)d_in[5];
    const float* conv2_b  = (const float*)d_in[6];
    const float* bn2_g    = (const float*)d_in[7];
    const float* bn2_b    = (const float*)d_in[8];
    const float* conv3_w  = (const float*)d_in[9];
    const float* conv3_b  = (const float*)d_in[10];
    const float* bn3_g    = (const float*)d_in[11];
    const float* bn3_b    = (const float*)d_in[12];
    const float* tconv_w  = (const float*)d_in[13];
    const float* tconv_b  = (const float*)d_in[14];
    const float* bn4_g    = (const float*)d_in[15];
    const float* bn4_b    = (const float*)d_in[16];
    const float* proj_w   = (const float*)d_in[17];
    const float* proj_b   = (const float*)d_in[18];
    const float* codebook = (const float*)d_in[19];
    const float* word_cb  = (const float*)d_in[20];
    const float* align_w  = (const float*)d_in[21];
    const float* align_b  = (const float*)d_in[22];
    const float* gru_wih0 = (const float*)d_in[23];
    const float* gru_whh0 = (const float*)d_in[24];
    const float* gru_bih0 = (const float*)d_in[25];
    const float* gru_bhh0 = (const float*)d_in[26];
    const float* gru_wih1 = (const float*)d_in[27];
    const float* gru_whh1 = (const float*)d_in[28];
    const float* gru_bih1 = (const float*)d_in[29];
    const float* gru_bhh1 = (const float*)d_in[30];
    const float* dec1_w   = (const float*)d_in[31];
    const float* dec1_b   = (const float*)d_in[32];
    const float* dec2_w   = (const float*)d_in[33];
    const float* dec2_b   = (const float*)d_in[34];
    const float* dec3_w   = (const float*)d_in[35];
    const float* dec3_b   = (const float*)d_in[36];
    const int*   tokens   = (const int*)d_in[37];

    float* wsf    = (float*)d_ws;
    float* out    = (float*)d_out;
    float* x1p    = wsf + OFF_X1P;
    float* x2p    = wsf + OFF_X2P;
    float* y2     = wsf + OFF_Y2;
    float* y3     = wsf + OFF_Y3;   // conv3 partial base (P0; P1 at +4,194,304)
    float* x3p    = wsf + OFF_X3P;
    float* y4     = wsf + OFF_Y4;
    float* x4     = wsf + OFF_X4;
    float* feat   = wsf + OFF_FEAT;
    float* quant  = wsf + OFF_QUANT;
    float* gi1    = wsf + OFF_GI1;
    float* gi2    = wsf + OFF_GI2;
    float* h1     = wsf + OFF_H1;
    float* h2     = wsf + OFF_H2;
    float* wemb   = wsf + OFF_WEMB;
    float* ctx    = wsf + OFF_CTX;
    float* hh1    = wsf + OFF_HH1;
    float* hh2    = wsf + OFF_HH2;
    float* logit  = wsf + OFF_LOG;
    float* pp     = wsf + OFF_PP;
    float* sc     = wsf + OFF_SC;
    float* sh     = wsf + OFF_SH;
    float* accP   = wsf + OFF_ACCP;
    float* commitA= wsf + OFF_COMMIT;
    float* ctxA   = wsf + OFF_CTXA;
    float* alignA = wsf + OFF_ALIGNA;

    // conv1 + bn1 + pool
    k_conv1_stats3<<<dim3(4, 4, 64), 256, 0, stream>>>(videos, conv1_w, conv1_b, accP);
    k_conv1_fin<<<4, 256, 0, stream>>>(accP, bn1_g, bn1_b, sc, sh);
    k_conv1_apply3<<<dim3(4, 4, 64), 256, 0, stream>>>(videos, conv1_w, conv1_b, sc, sh, x1p);
    // conv2 + bn2 + pool
    k_conv2<<<dim3(4, 4, 64), 256, 0, stream>>>(x1p, conv2_w, conv2_b, y2);
    k_bn_stats<<<dim3(16, 128), 256, 0, stream>>>(y2, bn2_g, bn2_b, sc, sh, 128, 1024);
    k_bn_apply_pool<<<8192, 256, 0, stream>>>(y2, sc, sh, x2p, 128, 32, 32);
    // conv3 (split-IC 2-way) + fused stats/apply over (P0+P1)+bias
    k_conv3p<<<dim3(8, 64, 2), 256, 0, stream>>>(x2p, conv3_w, y3);
    k_bn_stats3p<<<dim3(16, 256), 256, 0, stream>>>(y3, conv3_b, bn3_g, bn3_b, sc, sh);
    k_bn_apply_avgpool4p<<<1024, 256, 0, stream>>>(y3, conv3_b, sc, sh, x3p);
    k_tconv<<<1024, 256, 0, stream>>>(x3p, tconv_w, tconv_b, y4);
    k_bn_stats<<<dim3(16, 256), 256, 0, stream>>>(y4, bn4_g, bn4_b, sc, sh, 256, 16);
    k_bn_apply<<<1024, 256, 0, stream>>>(y4, sc, sh, x4);
    // projection (deterministic split-K GEMM, row permutation in fin)
    k_proj_part<<<dim3(8, 8), 256, 0, stream>>>(x4, proj_w, pp);
    k_proj_fin<<<128, 256, 0, stream>>>(pp, proj_b, feat);
    k_vq<<<64, 256, 0, stream>>>(feat, codebook, quant, commitA);
    // GRU pipeline with piggybacked tail (word_vq/align/ctx/dec1/dec2/dec3)
    k_gru_gi6<<<360, 256, 0, stream>>>(quant, gru_wih0, gru_bih0, gi1);
    for (int t = 0; t <= 16; ++t)
        k_gru_pipe<<<468, 256, 0, stream>>>(gi1, gru_whh0, gru_bhh0, h1,
                                            gru_wih1, gru_bih1, gi2,
                                            gru_whh1, gru_bhh1, h2,
                                            quant, word_cb, wemb, out,
                                            align_w, align_b, alignA, ctx,
                                            dec1_w, dec1_b, hh1,
                                            dec2_w, dec2_b, hh2,
                                            dec3_w, dec3_b, logit, t);
    k_ctx_loss<<<120, 256, 0, stream>>>(h2, feat, ctxA);
    k_final<<<1, 256, 0, stream>>>(logit, tokens, commitA, ctxA, alignA, out + 32);
}

// Round 13
// 1039.736 us; speedup vs baseline: 1.0975x; 1.0122x over previous
//
#include <hip/hip_runtime.h>

// ============================================================================
// SignLLM forward, fp32. B=4, T=32 -> nc=16 clips, D=512.
// Output: d_out[0..31] = widx (4,8) as float, d_out[32] = total loss.
// R23 = R21 restore (known-good: 1052.4us, absmax 0.0). R22's cooperative
// kernel FAILED SILENTLY: hipLaunchCooperativeKernel is not capturable into
// the harness's hipGraph (error ignored -> GRU region never ran -> widx=0,
// absmax 233 = max ref widx). Cooperative launch retired for this harness;
// the 17-launch pipe (launch boundary = sync) is the graph-compatible floor
// for the serial GRU dependence.
// Structure: conv3 split-IC (R17) + BN3 fusion (R20); conv2 = R13; GRU
// 17-launch pipeline with tail piggyback t=0..5 (R21). 33 launches.
// Zero atomics anywhere (deterministic).
// ============================================================================

// ---- workspace layout (float offsets), peak ~12.62M floats = 50.5 MB ----
static const size_t OFF_X1P  = 0;         // (64,64,32,32)  4,194,304  [dead after conv2]
static const size_t OFF_Y2   = 4194304;   // (64,128,32,32) 8,388,608  -> ends 12,582,912
static const size_t OFF_X2P  = 0;         // (64,128,16,16) 2,097,152  [x1p dead]
static const size_t OFF_Y3   = 4194304;   // conv3 partial P0 (4,194,304)
static const size_t OFF_Y3P1 = 8388608;   // conv3 partial P1 (4,194,304) -> ends 12,582,912
static const size_t OFF_X3P  = 2097152;   // 262,144
static const size_t OFF_Y4   = 2359296;   // 262,144
static const size_t OFF_X4   = 2621440;   // 262,144
static const size_t OFF_FEAT = 2883584;   // (64,512) 32,768
static const size_t OFF_QUANT= 2916352;   // 32,768
static const size_t OFF_GI1  = 2949120;   // (64,1536) 98,304 (rows b*16+t)
static const size_t OFF_GI2  = 3047424;   // 98,304
static const size_t OFF_H1   = 3145728;   // (64,512) rows b*16+t
static const size_t OFF_H2   = 3178496;   // 32,768
static const size_t OFF_WEMB = 3211264;   // (32,512) 16,384
static const size_t OFF_CTX  = 3227648;   // 2,048
static const size_t OFF_HH1  = 3229696;   // 2,048
static const size_t OFF_HH2  = 3231744;   // 4,096
static const size_t OFF_LOG  = 3235840;   // 12,000 -> ends 3,247,840
static const size_t OFF_PP   = 3247840;   // proj partials (8,64,512) 262,144
// long-lived block PAST y2's end (12,582,912):
static const size_t OFF_SC    = 12582912; // 4,096
static const size_t OFF_SH    = 12587008; // 4,096
static const size_t OFF_ACCP  = 12591104; // 32,768: conv1 stats (s:16384, q:16384)
static const size_t OFF_COMMIT= 12623872; // 64
static const size_t OFF_CTXA  = 12623936; // 120
static const size_t OFF_ALIGNA= 12624056; // 32

// ============================================================================
// conv1 (IC=3, 64x64, pad 1, mid temporal slice). Block = (ocg, rq, n),
// 256 thr = 2x2px x 16oc. Deterministic per-(c,oc,b,rq) stats partials.
// ============================================================================
__global__ __launch_bounds__(256) void k_conv1_stats3(
        const float* __restrict__ videos, const float* __restrict__ w1,
        const float* __restrict__ b1, float* __restrict__ accP) {
    __shared__ float sP[3 * 18 * 66];
    __shared__ float wsm[3 * 9 * 16];
    __shared__ float sRed[4][16], qRed[4][16];
    int oc0 = blockIdx.x * 16, rq = blockIdx.y, n = blockIdx.z;
    int c = n >> 2, b = n & 3;
    int tid = threadIdx.x;
    int rp = tid >> 5, cq = tid & 31;
    for (int e = tid; e < 3564; e += 256) {
        int ic = e / 1188, rem = e % 1188;
        int r = rem / 66, col = rem % 66;
        int gr = rq * 16 - 1 + r, gc = col - 1;
        float v = 0.f;
        if (gr >= 0 && gr < 64 && gc >= 0 && gc < 64)
            v = videos[((size_t)(b * 3 + ic) * 32 + 2 * c) * 4096 + gr * 64 + gc];
        sP[e] = v;
    }
    for (int e = tid; e < 432; e += 256) {
        int ic = e / 144, rem = e % 144, k = rem / 16, j = rem % 16;
        wsm[e] = w1[((size_t)((oc0 + j) * 3 + ic) * 3 + 1) * 9 + k];
    }
    __syncthreads();
    float acc[4][16];
#pragma unroll
    for (int p = 0; p < 4; ++p)
#pragma unroll
        for (int j = 0; j < 16; ++j) acc[p][j] = 0.f;
#pragma unroll
    for (int ic = 0; ic < 3; ++ic) {
        const float* base = &sP[ic * 1188 + (2 * rp) * 66 + 2 * cq];
        float patch[4][4];
#pragma unroll
        for (int r = 0; r < 4; ++r)
#pragma unroll
            for (int q = 0; q < 4; ++q) patch[r][q] = base[r * 66 + q];
#pragma unroll
        for (int k = 0; k < 9; ++k) {
            int kr = k / 3, kc = k % 3;
            float4 w0 = *(const float4*)&wsm[(ic * 9 + k) * 16 + 0];
            float4 w1v = *(const float4*)&wsm[(ic * 9 + k) * 16 + 4];
            float4 w2 = *(const float4*)&wsm[(ic * 9 + k) * 16 + 8];
            float4 w3 = *(const float4*)&wsm[(ic * 9 + k) * 16 + 12];
#pragma unroll
            for (int p = 0; p < 4; ++p) {
                float vv = patch[(p >> 1) + kr][(p & 1) + kc];
                acc[p][0]  += vv * w0.x; acc[p][1]  += vv * w0.y;
                acc[p][2]  += vv * w0.z; acc[p][3]  += vv * w0.w;
                acc[p][4]  += vv * w1v.x; acc[p][5]  += vv * w1v.y;
                acc[p][6]  += vv * w1v.z; acc[p][7]  += vv * w1v.w;
                acc[p][8]  += vv * w2.x; acc[p][9]  += vv * w2.y;
                acc[p][10] += vv * w2.z; acc[p][11] += vv * w2.w;
                acc[p][12] += vv * w3.x; acc[p][13] += vv * w3.y;
                acc[p][14] += vv * w3.z; acc[p][15] += vv * w3.w;
            }
        }
    }
    int lane = tid & 63, wave = tid >> 6;
#pragma unroll
    for (int j = 0; j < 16; ++j) {
        float bj = b1[oc0 + j];
        float s = 0.f, q = 0.f;
#pragma unroll
        for (int p = 0; p < 4; ++p) {
            float a = acc[p][j] + bj;
            s += a; q += a * a;
        }
#pragma unroll
        for (int m = 1; m < 64; m <<= 1) {
            s += __shfl_xor(s, m);
            q += __shfl_xor(q, m);
        }
        if (lane == 0) { sRed[wave][j] = s; qRed[wave][j] = q; }
    }
    __syncthreads();
    if (tid < 16) {
        float s = ((sRed[0][tid] + sRed[1][tid]) + (sRed[2][tid] + sRed[3][tid]));
        float q = ((qRed[0][tid] + qRed[1][tid]) + (qRed[2][tid] + qRed[3][tid]));
        int oc = oc0 + tid;
        size_t slot = (((size_t)(c * 64 + oc)) * 4 + b) * 4 + rq;
        accP[slot] = s;
        accP[16384 + slot] = q;
    }
}

__global__ void k_conv1_fin(const float* __restrict__ accP, const float* __restrict__ g1,
                            const float* __restrict__ be1, float* __restrict__ sc,
                            float* __restrict__ sh) {
    int e = blockIdx.x * 256 + threadIdx.x;
    if (e >= 1024) return;
    int oc = e & 63;
    const float* ps = accP + (size_t)e * 16;
    const float* pq = accP + 16384 + (size_t)e * 16;
    float s = 0.f, q = 0.f;
#pragma unroll
    for (int i = 0; i < 16; ++i) { s += ps[i]; q += pq[i]; }
    float m = s * (1.f / 16384.f);
    float var = q * (1.f / 16384.f) - m * m;
    float sf = g1[oc] * rsqrtf(var + 1e-5f);
    sc[e] = sf;
    sh[e] = be1[oc] - m * sf;
}

__global__ __launch_bounds__(256) void k_conv1_apply3(
        const float* __restrict__ videos, const float* __restrict__ w1,
        const float* __restrict__ b1, const float* __restrict__ sc,
        const float* __restrict__ sh, float* __restrict__ x1p) {
    __shared__ float sP[3 * 18 * 66];
    __shared__ float wsm[3 * 9 * 16];
    int oc0 = blockIdx.x * 16, rq = blockIdx.y, n = blockIdx.z;
    int c = n >> 2, b = n & 3;
    int tid = threadIdx.x;
    int rp = tid >> 5, cq = tid & 31;
    for (int e = tid; e < 3564; e += 256) {
        int ic = e / 1188, rem = e % 1188;
        int r = rem / 66, col = rem % 66;
        int gr = rq * 16 - 1 + r, gc = col - 1;
        float v = 0.f;
        if (gr >= 0 && gr < 64 && gc >= 0 && gc < 64)
            v = videos[((size_t)(b * 3 + ic) * 32 + 2 * c) * 4096 + gr * 64 + gc];
        sP[e] = v;
    }
    for (int e = tid; e < 432; e += 256) {
        int ic = e / 144, rem = e % 144, k = rem / 16, j = rem % 16;
        wsm[e] = w1[((size_t)((oc0 + j) * 3 + ic) * 3 + 1) * 9 + k];
    }
    __syncthreads();
    float acc[4][16];
#pragma unroll
    for (int p = 0; p < 4; ++p)
#pragma unroll
        for (int j = 0; j < 16; ++j) acc[p][j] = 0.f;
#pragma unroll
    for (int ic = 0; ic < 3; ++ic) {
        const float* base = &sP[ic * 1188 + (2 * rp) * 66 + 2 * cq];
        float patch[4][4];
#pragma unroll
        for (int r = 0; r < 4; ++r)
#pragma unroll
            for (int q = 0; q < 4; ++q) patch[r][q] = base[r * 66 + q];
#pragma unroll
        for (int k = 0; k < 9; ++k) {
            int kr = k / 3, kc = k % 3;
            float4 w0 = *(const float4*)&wsm[(ic * 9 + k) * 16 + 0];
            float4 w1v = *(const float4*)&wsm[(ic * 9 + k) * 16 + 4];
            float4 w2 = *(const float4*)&wsm[(ic * 9 + k) * 16 + 8];
            float4 w3 = *(const float4*)&wsm[(ic * 9 + k) * 16 + 12];
#pragma unroll
            for (int p = 0; p < 4; ++p) {
                float vv = patch[(p >> 1) + kr][(p & 1) + kc];
                acc[p][0]  += vv * w0.x; acc[p][1]  += vv * w0.y;
                acc[p][2]  += vv * w0.z; acc[p][3]  += vv * w0.w;
                acc[p][4]  += vv * w1v.x; acc[p][5]  += vv * w1v.y;
                acc[p][6]  += vv * w1v.z; acc[p][7]  += vv * w1v.w;
                acc[p][8]  += vv * w2.x; acc[p][9]  += vv * w2.y;
                acc[p][10] += vv * w2.z; acc[p][11] += vv * w2.w;
                acc[p][12] += vv * w3.x; acc[p][13] += vv * w3.y;
                acc[p][14] += vv * w3.z; acc[p][15] += vv * w3.w;
            }
        }
    }
#pragma unroll
    for (int j = 0; j < 16; ++j) {
        int oc = oc0 + j;
        float bj = b1[oc];
        float scj = sc[c * 64 + oc], shj = sh[c * 64 + oc];
        float m = -1e30f;
#pragma unroll
        for (int p = 0; p < 4; ++p) m = fmaxf(m, (acc[p][j] + bj) * scj + shj);
        x1p[((size_t)n * 64 + oc) * 1024 + (rq * 8 + rp) * 32 + cq] = fmaxf(m, 0.f);
    }
}

// ============================================================================
// conv2: IC=64, 32x32, OC=128. Block = 32 oc x 8-row slab x 1 clip.
// grid (4 ocg, 4 slab, 64 n) = 1024 blocks. Thread = 4 oc x (2x4 px).
// Input halo stride 36 -> patch rows load as b128+b64. (R13 form.)
// ============================================================================
__global__ __launch_bounds__(256) void k_conv2(
        const float* __restrict__ in, const float* __restrict__ wt,
        const float* __restrict__ bias, float* __restrict__ out) {
    __shared__ __align__(16) float sIn[8 * 10 * 36];   // 2880
    __shared__ __align__(16) float sW[8 * 9 * 32];     // 2304
    int oc0 = blockIdx.x * 32, r0 = blockIdx.y * 8, n = blockIdx.z;
    int tid = threadIdx.x;
    int ocq = tid >> 5;          // 0..7
    int rg = (tid >> 3) & 3;     // rows r0+2rg, r0+2rg+1
    int cg = tid & 7;            // cols 4cg..4cg+3
    float acc[4][8];
#pragma unroll
    for (int j = 0; j < 4; ++j)
#pragma unroll
        for (int p = 0; p < 8; ++p) acc[j][p] = 0.f;

    for (int ic0 = 0; ic0 < 64; ic0 += 8) {
        __syncthreads();
        for (int e = tid; e < 2720; e += 256) {      // 8 ch x 10 rows x 34 cols
            int ch = e / 340, rem = e % 340;
            int r = rem / 34, col = rem % 34;
            int gr = r0 - 1 + r, gc = col - 1;
            float v = 0.f;
            if (gr >= 0 && gr < 32 && gc >= 0 && gc < 32)
                v = in[((size_t)(n * 64 + ic0 + ch) * 32 + gr) * 32 + gc];
            sIn[ch * 360 + r * 36 + col] = v;
        }
        for (int e = tid; e < 2304; e += 256) {
            int c = e / 288, r1 = e % 288, k = r1 / 32, j = r1 % 32;
            sW[e] = wt[((size_t)(oc0 + j) * 64 + ic0 + c) * 27 + 9 + k];
        }
        __syncthreads();
        for (int c = 0; c < 8; ++c) {
            const float* base = &sIn[c * 360 + (2 * rg) * 36 + 4 * cg];
            float patch[4][6];
#pragma unroll
            for (int r = 0; r < 4; ++r) {
                float4 p4 = *(const float4*)&base[r * 36];
                float2 p2 = *(const float2*)&base[r * 36 + 4];
                patch[r][0] = p4.x; patch[r][1] = p4.y; patch[r][2] = p4.z;
                patch[r][3] = p4.w; patch[r][4] = p2.x; patch[r][5] = p2.y;
            }
#pragma unroll
            for (int k = 0; k < 9; ++k) {
                int kr = k / 3, kc = k % 3;
                float4 w4 = *(const float4*)&sW[c * 288 + k * 32 + ocq * 4];
#pragma unroll
                for (int p = 0; p < 8; ++p) {
                    int pr = p >> 2, pcq = p & 3;
                    float vv = patch[pr + kr][pcq + kc];
                    acc[0][p] += vv * w4.x; acc[1][p] += vv * w4.y;
                    acc[2][p] += vv * w4.z; acc[3][p] += vv * w4.w;
                }
            }
        }
    }
#pragma unroll
    for (int j = 0; j < 4; ++j) {
        int oc = oc0 + ocq * 4 + j;
        float bj = bias[oc];
#pragma unroll
        for (int pr = 0; pr < 2; ++pr) {
            float4 o4 = make_float4(acc[j][pr * 4 + 0] + bj, acc[j][pr * 4 + 1] + bj,
                                    acc[j][pr * 4 + 2] + bj, acc[j][pr * 4 + 3] + bj);
            *(float4*)&out[((size_t)(n * 128 + oc) * 32 + r0 + 2 * rg + pr) * 32 + 4 * cg] = o4;
        }
    }
}

// ============================================================================
// conv3 split-IC partial: grid (8 ocg, 64 n, 2 half) = 1024 blocks -> 16
// waves/CU. Writes NO-bias partial sums to P[half]. Inner loop = R13.
// ============================================================================
__global__ __launch_bounds__(256) void k_conv3p(
        const float* __restrict__ in, const float* __restrict__ wt,
        float* __restrict__ outP) {
    __shared__ __align__(16) float sIn[8 * 18 * 20];   // 2880
    __shared__ __align__(16) float sW[8 * 9 * 32];     // 2304
    int oc0 = blockIdx.x * 32, n = blockIdx.y, half = blockIdx.z;
    int tid = threadIdx.x;
    int ocq = tid >> 5;          // 0..7
    int rg = (tid >> 2) & 7;     // rows 2rg, 2rg+1
    int cg = tid & 3;            // cols 4cg..4cg+3
    float acc[4][8];
#pragma unroll
    for (int j = 0; j < 4; ++j)
#pragma unroll
        for (int p = 0; p < 8; ++p) acc[j][p] = 0.f;

    int icB = half * 64;
    for (int ic0 = icB; ic0 < icB + 64; ic0 += 8) {
        __syncthreads();
        for (int e = tid; e < 2592; e += 256) {      // 8 ch x 18 rows x 18 cols
            int ch = e / 324, rem = e % 324;
            int r = rem / 18, cc = rem % 18;
            int gr = r - 1, gc = cc - 1;
            float v = 0.f;
            if (gr >= 0 && gr < 16 && gc >= 0 && gc < 16)
                v = in[((size_t)(n * 128 + ic0 + ch) * 16 + gr) * 16 + gc];
            sIn[ch * 360 + r * 20 + cc] = v;
        }
        for (int e = tid; e < 2304; e += 256) {
            int c = e / 288, r1 = e % 288, k = r1 / 32, j = r1 % 32;
            sW[e] = wt[((size_t)(oc0 + j) * 128 + ic0 + c) * 27 + 9 + k];
        }
        __syncthreads();
        for (int c = 0; c < 8; ++c) {
            const float* base = &sIn[c * 360 + (2 * rg) * 20 + 4 * cg];
            float patch[4][6];
#pragma unroll
            for (int r = 0; r < 4; ++r) {
                float4 p4 = *(const float4*)&base[r * 20];
                float2 p2 = *(const float2*)&base[r * 20 + 4];
                patch[r][0] = p4.x; patch[r][1] = p4.y; patch[r][2] = p4.z;
                patch[r][3] = p4.w; patch[r][4] = p2.x; patch[r][5] = p2.y;
            }
#pragma unroll
            for (int k = 0; k < 9; ++k) {
                int kr = k / 3, kc = k % 3;
                float4 w4 = *(const float4*)&sW[c * 288 + k * 32 + ocq * 4];
#pragma unroll
                for (int p = 0; p < 8; ++p) {
                    int pr = p >> 2, pcq = p & 3;
                    float vv = patch[pr + kr][pcq + kc];
                    acc[0][p] += vv * w4.x; acc[1][p] += vv * w4.y;
                    acc[2][p] += vv * w4.z; acc[3][p] += vv * w4.w;
                }
            }
        }
    }
    float* dst = outP + (size_t)half * 4194304;
#pragma unroll
    for (int j = 0; j < 4; ++j) {
        int oc = oc0 + ocq * 4 + j;
#pragma unroll
        for (int pr = 0; pr < 2; ++pr) {
            float4 o4 = make_float4(acc[j][pr * 4 + 0], acc[j][pr * 4 + 1],
                                    acc[j][pr * 4 + 2], acc[j][pr * 4 + 3]);
            *(float4*)&dst[((size_t)(n * 256 + oc) * 16 + 2 * rg + pr) * 16 + 4 * cg] = o4;
        }
    }
}

// BN stats over y3 = (P0+P1)+bias, computed on the fly. C=256, HW=256.
// Mean/var over 4 batch x 256 px = 1024 elems.
__global__ void k_bn_stats3p(const float* __restrict__ P, const float* __restrict__ bias,
                             const float* __restrict__ g, const float* __restrict__ be,
                             float* __restrict__ scale, float* __restrict__ shift) {
    int c = blockIdx.x, ch = blockIdx.y, tid = threadIdx.x;
    float bj = bias[ch];
    float s = 0.f, s2 = 0.f;
    for (int b = 0; b < 4; ++b) {
        size_t base = ((size_t)(c * 4 + b) * 256 + ch) * 256;
        for (int i = tid; i < 256; i += 256) {
            size_t idx = base + i;
            float v = (P[idx] + P[idx + 4194304]) + bj;
            s += v; s2 += v * v;
        }
    }
    __shared__ float rs[256], rq[256];
    rs[tid] = s; rq[tid] = s2; __syncthreads();
    for (int k = 128; k > 0; k >>= 1) {
        if (tid < k) { rs[tid] += rs[tid + k]; rq[tid] += rq[tid + k]; }
        __syncthreads();
    }
    if (tid == 0) {
        float inv = 1.f / 1024.f;   // 4 * HW(=256)
        float m = rs[0] * inv, var = rq[0] * inv - m * m;
        float sc = g[ch] * rsqrtf(var + 1e-5f);
        scale[c * 256 + ch] = sc;
        shift[c * 256 + ch] = be[ch] - m * sc;
    }
}

// bn+relu+avgpool4 over y3 = (P0+P1)+bias on the fly (bit-identical values).
__global__ void k_bn_apply_avgpool4p(const float* __restrict__ P, const float* __restrict__ bias,
                                     const float* __restrict__ scale, const float* __restrict__ shift,
                                     float* __restrict__ out) {
    size_t idx = (size_t)blockIdx.x * 256 + threadIdx.x;  // 262,144
    int j = (int)(idx & 3), i = (int)(idx >> 2) & 3;
    int ch = (int)(idx >> 4) & 255, n = (int)(idx >> 12);
    int c = n >> 2;
    float bj = bias[ch];
    float sc = scale[c * 256 + ch], sh = shift[c * 256 + ch];
    size_t base = (((size_t)n * 256 + ch) * 16 + i * 4) * 16 + j * 4;
    float s = 0.f;
#pragma unroll
    for (int r = 0; r < 4; ++r)
#pragma unroll
        for (int q = 0; q < 4; ++q) {
            size_t pidx = base + r * 16 + q;
            float v = (P[pidx] + P[pidx + 4194304]) + bj;
            s += fmaxf(v * sc + sh, 0.f);
        }
    out[idx] = s * (1.f / 16.f);
}

// per-(clip,channel) BN stats (generic; used for y2 and y4)
__global__ void k_bn_stats(const float* __restrict__ buf, const float* __restrict__ g,
                           const float* __restrict__ be, float* __restrict__ scale,
                           float* __restrict__ shift, int C, int HW) {
    int c = blockIdx.x, ch = blockIdx.y, tid = threadIdx.x;
    float s = 0.f, s2 = 0.f;
    for (int b = 0; b < 4; ++b) {
        const float* p = buf + ((size_t)(c * 4 + b) * C + ch) * HW;
        for (int i = tid; i < HW; i += 256) { float v = p[i]; s += v; s2 += v * v; }
    }
    __shared__ float rs[256], rq[256];
    rs[tid] = s; rq[tid] = s2; __syncthreads();
    for (int k = 128; k > 0; k >>= 1) {
        if (tid < k) { rs[tid] += rs[tid + k]; rq[tid] += rq[tid + k]; }
        __syncthreads();
    }
    if (tid == 0) {
        float inv = 1.f / (float)(4 * HW);
        float m = rs[0] * inv, var = rq[0] * inv - m * m;
        float sc = g[ch] * rsqrtf(var + 1e-5f);
        scale[c * C + ch] = sc;
        shift[c * C + ch] = be[ch] - m * sc;
    }
}

__global__ void k_bn_apply_pool(const float* __restrict__ in, const float* __restrict__ scale,
                                const float* __restrict__ shift, float* __restrict__ out,
                                int C, int H, int W) {
    int OH = H >> 1, OW = W >> 1;
    size_t idx = (size_t)blockIdx.x * 256 + threadIdx.x;
    int ow = (int)(idx % OW);
    size_t r = idx / OW;
    int oh = (int)(r % OH); r /= OH;
    int ch = (int)(r % C);
    int n = (int)(r / C);
    int c = n >> 2;
    float sc = scale[c * C + ch], sh = shift[c * C + ch];
    const float* p = in + (((size_t)n * C + ch) * H + 2 * oh) * W + 2 * ow;
    float m = 0.f;
    m = fmaxf(m, p[0] * sc + sh);
    m = fmaxf(m, p[1] * sc + sh);
    m = fmaxf(m, p[W] * sc + sh);
    m = fmaxf(m, p[W + 1] * sc + sh);
    out[idx] = m;
}

__global__ void k_tconv(const float* __restrict__ x3p, const float* __restrict__ tw,
                        const float* __restrict__ tb, float* __restrict__ y4) {
    size_t idx = (size_t)blockIdx.x * 256 + threadIdx.x;  // 262,144
    int p = (int)(idx & 15), o = (int)(idx >> 4) & 255, n = (int)(idx >> 12);
    const float* xr = x3p + (size_t)n * 4096 + p;
    float a = tb[o];
    for (int i = 0; i < 256; ++i) a += xr[i * 16] * tw[((size_t)o * 256 + i) * 3 + 1];
    y4[idx] = a;
}

__global__ void k_bn_apply(const float* __restrict__ in, const float* __restrict__ scale,
                           const float* __restrict__ shift, float* __restrict__ out) {
    size_t idx = (size_t)blockIdx.x * 256 + threadIdx.x;  // 262,144
    int ch = (int)(idx >> 4) & 255, n = (int)(idx >> 12);
    int c = n >> 2;
    float sc = scale[c * 256 + ch], sh = shift[c * 256 + ch];
    out[idx] = fmaxf(in[idx] * sc + sh, 0.f);
}

// ============================================================================
// proj as deterministic split-K GEMM with row permutation in fin.
// ============================================================================
__global__ __launch_bounds__(256) void k_proj_part(
        const float* __restrict__ A, const float* __restrict__ B, float* __restrict__ PP) {
    __shared__ __align__(16) float As[64 * 68];
    __shared__ __align__(16) float Bs[64 * 68];
    int n0 = blockIdx.x * 64, ks = blockIdx.y;
    int tid = threadIdx.x, tm = tid >> 4, tn = tid & 15;
    float acc[4][4];
#pragma unroll
    for (int i = 0; i < 4; ++i)
#pragma unroll
        for (int j = 0; j < 4; ++j) acc[i][j] = 0.f;
    int kb = ks * 512;
    for (int k0 = kb; k0 < kb + 512; k0 += 64) {
        __syncthreads();
        for (int e = tid; e < 4096; e += 256) {
            int m = e >> 6, k = e & 63;
            As[k * 68 + m] = A[(size_t)m * 4096 + k0 + k];
            Bs[k * 68 + m] = B[(size_t)(n0 + m) * 4096 + k0 + k];
        }
        __syncthreads();
        for (int k = 0; k < 64; ++k) {
            float4 a4 = *(const float4*)&As[k * 68 + tm * 4];
            float4 b4 = *(const float4*)&Bs[k * 68 + tn * 4];
            acc[0][0] += a4.x * b4.x; acc[0][1] += a4.x * b4.y;
            acc[0][2] += a4.x * b4.z; acc[0][3] += a4.x * b4.w;
            acc[1][0] += a4.y * b4.x; acc[1][1] += a4.y * b4.y;
            acc[1][2] += a4.y * b4.z; acc[1][3] += a4.y * b4.w;
            acc[2][0] += a4.z * b4.x; acc[2][1] += a4.z * b4.y;
            acc[2][2] += a4.z * b4.z; acc[2][3] += a4.z * b4.w;
            acc[3][0] += a4.w * b4.x; acc[3][1] += a4.w * b4.y;
            acc[3][2] += a4.w * b4.z; acc[3][3] += a4.w * b4.w;
        }
    }
#pragma unroll
    for (int i = 0; i < 4; ++i)
#pragma unroll
        for (int j = 0; j < 4; ++j)
            PP[((size_t)(ks * 64 + tm * 4 + i)) * 512 + n0 + tn * 4 + j] = acc[i][j];
}

__global__ void k_proj_fin(const float* __restrict__ PP, const float* __restrict__ pb,
                           float* __restrict__ feat) {
    int e = blockIdx.x * 256 + threadIdx.x;  // 32768
    int n = e & 511;
    int m = e >> 9;               // x4 row (clip-major): m = c*4 + b
    float s = pb[n];
#pragma unroll
    for (int ks = 0; ks < 8; ++ks) s += PP[(size_t)ks * 32768 + e];
    int c = m >> 2, b = m & 3;
    int ro = b * 16 + c;          // feat row (batch-major)
    feat[(size_t)ro * 512 + n] = s;
}

// VQ argmin; min distance -> commitArr[row] (deterministic)
__global__ void k_vq(const float* __restrict__ feat, const float* __restrict__ cb,
                     float* __restrict__ quant, float* __restrict__ commitArr) {
    int row = blockIdx.x, tid = threadIdx.x;
    __shared__ float f[512];
    for (int k = tid; k < 512; k += 256) f[k] = feat[(size_t)row * 512 + k];
    __syncthreads();
    float best = 3.4e38f; int bidx = 0;
    for (int j = tid; j < 1024; j += 256) {
        const float* c = cb + (size_t)j * 512;
        float d2 = 0.f;
        for (int k = 0; k < 512; ++k) { float t = f[k] - c[k]; d2 += t * t; }
        if (d2 < best) { best = d2; bidx = j; }
    }
    __shared__ float rd[256]; __shared__ int ri[256];
    rd[tid] = best; ri[tid] = bidx; __syncthreads();
    for (int k = 128; k > 0; k >>= 1) {
        if (tid < k) {
            float od = rd[tid + k]; int oi = ri[tid + k];
            if (od < rd[tid] || (od == rd[tid] && oi < ri[tid])) { rd[tid] = od; ri[tid] = oi; }
        }
        __syncthreads();
    }
    __shared__ int wsel;
    if (tid == 0) { wsel = ri[0]; commitArr[row] = rd[0]; }
    __syncthreads();
    const float* c = cb + (size_t)wsel * 512;
    for (int k = tid; k < 512; k += 256) quant[(size_t)row * 512 + k] = c[k];
}

// ---- GRU helpers -----------------------------------------------------------
__device__ __forceinline__ void gru_gi_one(
        const float* __restrict__ xsRow, const float* __restrict__ wih,
        const float* __restrict__ bih, float* __restrict__ gi, int row, int d) {
    const float4* xp = (const float4*)xsRow;
    const float4* wr = (const float4*)(wih + (size_t)d * 512);
    float a0 = 0.f, a1 = 0.f, a2 = 0.f, a3 = 0.f;
    for (int i = 0; i < 128; i += 4) {
        float4 w0 = wr[i], w1 = wr[i + 1], w2 = wr[i + 2], w3 = wr[i + 3];
        float4 x0 = xp[i], x1 = xp[i + 1], x2 = xp[i + 2], x3 = xp[i + 3];
        a0 += w0.x * x0.x + w0.y * x0.y + w0.z * x0.z + w0.w * x0.w;
        a1 += w1.x * x1.x + w1.y * x1.y + w1.z * x1.z + w1.w * x1.w;
        a2 += w2.x * x2.x + w2.y * x2.y + w2.z * x2.z + w2.w * x2.w;
        a3 += w3.x * x3.x + w3.y * x3.y + w3.z * x3.z + w3.w * x3.w;
    }
    gi[(size_t)row * 1536 + d] = (a0 + a1) + (a2 + a3) + bih[d];
}

__device__ __forceinline__ void gru_step_body(
        const float* __restrict__ gi, const float* __restrict__ whh,
        const float* __restrict__ bhh, float* __restrict__ hseq, int t, int blk) {
    int wv = threadIdx.x >> 6, lane = threadIdx.x & 63;
    int d = blk * 4 + wv;
    const float4* w0p = (const float4*)(whh + (size_t)d * 512);
    const float4* w1p = (const float4*)(whh + (size_t)(512 + d) * 512);
    const float4* w2p = (const float4*)(whh + (size_t)(1024 + d) * 512);
    float4 w0a = w0p[lane * 2], w0b = w0p[lane * 2 + 1];
    float4 w1a = w1p[lane * 2], w1b = w1p[lane * 2 + 1];
    float4 w2a = w2p[lane * 2], w2b = w2p[lane * 2 + 1];
    float bh0 = bhh[d], bh1 = bhh[512 + d], bh2 = bhh[1024 + d];
    for (int b = 0; b < 4; ++b) {
        float4 ha = make_float4(0, 0, 0, 0), hb = ha;
        float hpd = 0.f;
        if (t > 0) {
            const float4* hp = (const float4*)(hseq + (size_t)(b * 16 + t - 1) * 512);
            ha = hp[lane * 2]; hb = hp[lane * 2 + 1];
            hpd = hseq[(size_t)(b * 16 + t - 1) * 512 + d];
        }
        float s0 = w0a.x * ha.x + w0a.y * ha.y + w0a.z * ha.z + w0a.w * ha.w
                 + w0b.x * hb.x + w0b.y * hb.y + w0b.z * hb.z + w0b.w * hb.w;
        float s1 = w1a.x * ha.x + w1a.y * ha.y + w1a.z * ha.z + w1a.w * ha.w
                 + w1b.x * hb.x + w1b.y * hb.y + w1b.z * hb.z + w1b.w * hb.w;
        float s2 = w2a.x * ha.x + w2a.y * ha.y + w2a.z * ha.z + w2a.w * ha.w
                 + w2b.x * hb.x + w2b.y * hb.y + w2b.z * hb.z + w2b.w * hb.w;
#pragma unroll
        for (int m = 1; m < 64; m <<= 1) {
            s0 += __shfl_xor(s0, m);
            s1 += __shfl_xor(s1, m);
            s2 += __shfl_xor(s2, m);
        }
        const float* gr = gi + (size_t)(b * 16 + t) * 1536;
        float rr = 1.f / (1.f + expf(-(gr[d] + s0 + bh0)));
        float zz = 1.f / (1.f + expf(-(gr[512 + d] + s1 + bh1)));
        float nn = tanhf(gr[1024 + d] + rr * (s2 + bh2));
        if (lane == 0)
            hseq[(size_t)(b * 16 + t) * 512 + d] = (1.f - zz) * nn + zz * hpd;
    }
}

// small-M (M=4) GEMV section: C[4,N] = A[4,K] @ B[N,K]^T + bias, optional relu.
__device__ __forceinline__ void dev_smallM(float* xs, const float* __restrict__ A,
                                           const float* __restrict__ B,
                                           const float* __restrict__ bias,
                                           float* __restrict__ C,
                                           int N, int K, int relu, int blk) {
    int tid = threadIdx.x;
    for (int e = tid; e < 4 * K; e += 256) xs[e] = A[e];
    __syncthreads();
    int r = tid >> 4, kt = tid & 15;
    int n = blk * 16 + r;
    float acc[4] = {0, 0, 0, 0};
    if (n < N) {
        int iters = K >> 6;
        for (int i = 0; i < iters; ++i) {
            int k = i * 64 + kt * 4;
            float4 w = *(const float4*)&B[(size_t)n * K + k];
#pragma unroll
            for (int b = 0; b < 4; ++b) {
                float4 x = *(const float4*)&xs[b * K + k];
                acc[b] += w.x * x.x + w.y * x.y + w.z * x.z + w.w * x.w;
            }
        }
    }
#pragma unroll
    for (int b = 0; b < 4; ++b) {
#pragma unroll
        for (int m = 1; m < 16; m <<= 1) acc[b] += __shfl_xor(acc[b], m);
    }
    if (kt == 0 && n < N) {
#pragma unroll
        for (int b = 0; b < 4; ++b) {
            float v = acc[b] + bias[n];
            if (relu) v = fmaxf(v, 0.f);
            C[(size_t)b * N + n] = v;
        }
    }
}

// Layer-1 gi, spread: grid 360 = 60 rows x 6 parts, 1 dim/thread.
__global__ void k_gru_gi6(const float* __restrict__ x, const float* __restrict__ wih,
                          const float* __restrict__ bih, float* __restrict__ gi) {
    int g = blockIdx.x;
    int r = g / 6, part = g % 6;
    int b = r / 15, t = r % 15;
    int row = b * 16 + t;
    __shared__ float xsRow[512];
    for (int k = threadIdx.x; k < 512; k += 256) xsRow[k] = x[(size_t)row * 512 + k];
    __syncthreads();
    gru_gi_one(xsRow, wih, bih, gi, row, part * 256 + threadIdx.x);
}

// ============================================================================
// GRU pipeline launch t = 0..16, grid 468:
//   blocks   0..127 : layer-1 step t        (t in [0,14])
//   blocks 128..255 : layer-2 step t-2      (t in [2,16])
//   blocks 256..279 : gi2 rows for time t-1 (t in [1,15])
//   blocks 280..467 : piggybacked tail sections (each reads only data
//     finalized in a PREVIOUS launch; all writes disjoint from GRU rows):
//       t=0: word_vq (32 blk)  t=1: align (32)  t=2: ctx (8)
//       t=3: dec1 (32)         t=4: dec2 (64)   t=5: dec3 (188)
// ============================================================================
__global__ __launch_bounds__(256) void k_gru_pipe(
        const float* __restrict__ gi1, const float* __restrict__ whh0,
        const float* __restrict__ bhh0, float* __restrict__ h1,
        const float* __restrict__ wih1, const float* __restrict__ bih1,
        float* __restrict__ gi2, const float* __restrict__ whh1,
        const float* __restrict__ bhh1, float* __restrict__ h2,
        const float* __restrict__ quant, const float* __restrict__ wcb,
        float* __restrict__ wemb, float* __restrict__ out_widx,
        const float* __restrict__ aw, const float* __restrict__ ab,
        float* __restrict__ alignArr, float* __restrict__ ctxB,
        const float* __restrict__ dec1_w, const float* __restrict__ dec1_b,
        float* __restrict__ hh1, const float* __restrict__ dec2_w,
        const float* __restrict__ dec2_b, float* __restrict__ hh2,
        const float* __restrict__ dec3_w, const float* __restrict__ dec3_b,
        float* __restrict__ logit, int t) {
    __shared__ float shbuf[4096];
    __shared__ float redf[256];
    __shared__ int   redi[256];
    __shared__ int   wsel_s;
    int bid = blockIdx.x;
    int tid = threadIdx.x;
    if (bid < 128) {
        if (t < 15) gru_step_body(gi1, whh0, bhh0, h1, t, bid);
    } else if (bid < 256) {
        if (t >= 2) gru_step_body(gi2, whh1, bhh1, h2, t - 2, bid - 128);
    } else if (bid < 280) {
        if (t >= 1 && t <= 15) {
            int local = bid - 256;          // 0..23
            int b = local / 6, part = local % 6;
            int row = b * 16 + (t - 1);
            for (int k = tid; k < 512; k += 256)
                shbuf[k] = h1[(size_t)row * 512 + k];
            __syncthreads();
            gru_gi_one(shbuf, wih1, bih1, gi2, row, part * 256 + tid);
        }
    } else {
        int tb = bid - 280;
        if (t == 0) {
            if (tb < 32) {
                // word_vq row=tb (verbatim k_word_vq arithmetic)
                int b = tb >> 3, wi = tb & 7;
                for (int k = tid; k < 512; k += 256)
                    shbuf[k] = 0.5f * (quant[(size_t)(b * 16 + 2 * wi) * 512 + k] +
                                       quant[(size_t)(b * 16 + 2 * wi + 1) * 512 + k]);
                __syncthreads();
                const float* cp = wcb + (size_t)tid * 512;
                float d2 = 0.f;
                for (int k = 0; k < 512; ++k) { float tt = shbuf[k] - cp[k]; d2 += tt * tt; }
                redf[tid] = d2; redi[tid] = tid; __syncthreads();
                for (int k = 128; k > 0; k >>= 1) {
                    if (tid < k) {
                        float od = redf[tid + k]; int oi = redi[tid + k];
                        if (od < redf[tid] || (od == redf[tid] && oi < redi[tid])) {
                            redf[tid] = od; redi[tid] = oi;
                        }
                    }
                    __syncthreads();
                }
                if (tid == 0) { wsel_s = redi[0]; out_widx[tb] = (float)redi[0]; }
                __syncthreads();
                const float* cb = wcb + (size_t)wsel_s * 512;
                for (int k = tid; k < 512; k += 256)
                    wemb[(size_t)tb * 512 + k] = cb[k];
            }
        } else if (t == 1) {
            if (tb < 32) {
                // align row=tb (verbatim k_align arithmetic)
                for (int k = tid; k < 512; k += 256)
                    shbuf[k] = wemb[(size_t)tb * 512 + k];
                __syncthreads();
                float local = 0.f;
                for (int d = tid; d < 512; d += 256) {
                    const float* wr = aw + (size_t)d * 512;
                    float a = ab[d] - shbuf[d];
                    for (int k = 0; k < 512; ++k) a += shbuf[k] * wr[k];
                    local += a * a;
                }
                redf[tid] = local; __syncthreads();
                for (int k = 128; k > 0; k >>= 1) {
                    if (tid < k) redf[tid] += redf[tid + k];
                    __syncthreads();
                }
                if (tid == 0) alignArr[tb] = redf[0];
            }
        } else if (t == 2) {
            if (tb < 8) {
                int e = tb * 256 + tid;   // 2048
                int b = e >> 9, d = e & 511;
                float s = 0.f;
#pragma unroll
                for (int wi = 0; wi < 8; ++wi) s += wemb[(size_t)(b * 8 + wi) * 512 + d];
                ctxB[e] = s * 0.125f;
            }
        } else if (t == 3) {
            if (tb < 32) dev_smallM(shbuf, ctxB, dec1_w, dec1_b, hh1, 512, 512, 1, tb);
        } else if (t == 4) {
            if (tb < 64) dev_smallM(shbuf, hh1, dec2_w, dec2_b, hh2, 1024, 512, 1, tb);
        } else if (t == 5) {
            if (tb < 188) dev_smallM(shbuf, hh2, dec3_w, dec3_b, logit, 3000, 1024, 0, tb);
        }
    }
}

// ctx loss partials -> ctxArr[block] (deterministic)
__global__ void k_ctx_loss(const float* __restrict__ h2, const float* __restrict__ feat,
                           float* __restrict__ ctxArr) {
    int tid = threadIdx.x;
    size_t idx = (size_t)blockIdx.x * 256 + tid;  // 30720
    int d = (int)(idx & 511);
    int rt = (int)(idx >> 9);
    int t = rt % 15, b = rt / 15;
    float diff = h2[(size_t)(b * 16 + t) * 512 + d] - feat[(size_t)(b * 16 + t + 1) * 512 + d];
    float v = diff * diff;
#pragma unroll
    for (int m = 1; m < 64; m <<= 1) v += __shfl_xor(v, m);
    __shared__ float ws[4];
    if ((tid & 63) == 0) ws[tid >> 6] = v;
    __syncthreads();
    if (tid == 0) ctxArr[blockIdx.x] = ((ws[0] + ws[1]) + (ws[2] + ws[3]));
}

// log-softmax CE + deterministic fixed-order sum of all loss partials
__global__ void k_final(const float* __restrict__ logits, const int* __restrict__ tokens,
                        const float* __restrict__ commitArr, const float* __restrict__ ctxArr,
                        const float* __restrict__ alignArr, float* __restrict__ out_total) {
    int tid = threadIdx.x;
    __shared__ float rs[256];
    __shared__ float sM;
    float tr = 0.f;
    for (int b = 0; b < 4; ++b) {
        const float* lg = logits + (size_t)b * 3000;
        float m = -1e30f;
        for (int d = tid; d < 3000; d += 256) m = fmaxf(m, lg[d]);
        rs[tid] = m; __syncthreads();
        for (int k = 128; k > 0; k >>= 1) { if (tid < k) rs[tid] = fmaxf(rs[tid], rs[tid + k]); __syncthreads(); }
        if (tid == 0) sM = rs[0];
        __syncthreads();
        float M = sM;
        float s = 0.f;
        for (int d = tid; d < 3000; d += 256) s += expf(lg[d] - M);
        rs[tid] = s; __syncthreads();
        for (int k = 128; k > 0; k >>= 1) { if (tid < k) rs[tid] += rs[tid + k]; __syncthreads(); }
        if (tid == 0) {
            int t0 = tokens[b * 10];
            tr += -(lg[t0] - M - logf(rs[0]));
        }
        __syncthreads();
    }
    if (tid == 0) {
        float c0 = 0.f;
        for (int i = 0; i < 64; ++i) c0 += commitArr[i];
        float c1 = 0.f;
        for (int i = 0; i < 120; ++i) c1 += ctxArr[i];
        float c2 = 0.f;
        for (int i = 0; i < 32; ++i) c2 += alignArr[i];
        float total = 1.25f * c0 * (1.f / 32768.f)
                    + 0.1f  * c1 * (1.f / 30720.f)
                    + 0.1f  * c2 * (1.f / 16384.f)
                    + tr;
        *out_total = total;
    }
}

extern "C" void kernel_launch(void* const* d_in, const int* in_sizes, int n_in,
                              void* d_out, int out_size, void* d_ws, size_t ws_size,
                              hipStream_t stream) {
    (void)in_sizes; (void)n_in; (void)out_size; (void)ws_size;
    const float* videos   = (const float*)d_in[0];
    const float* conv1_w  = (const float*)d_in[1];
    const float* conv1_b  = (const float*)d_in[2];
    const float* bn1_g    = (const float*)d_in[3];
    const float* bn1_b    = (const float*)d_in[4];
    const float* conv2_w  = (const float*)d_in[5];
    const float* conv2_b  = (const float*)d_in[6];
    const float* bn2_g    = (const float*)d_in[7];
    const float* bn2_b    = (const float*)d_in[8];
    const float* conv3_w  = (const float*)d_in[9];
    const float* conv3_b  = (const float*)d_in[10];
    const float* bn3_g    = (const float*)d_in[11];
    const float* bn3_b    = (const float*)d_in[12];
    const float* tconv_w  = (const float*)d_in[13];
    const float* tconv_b  = (const float*)d_in[14];
    const float* bn4_g    = (const float*)d_in[15];
    const float* bn4_b    = (const float*)d_in[16];
    const float* proj_w   = (const float*)d_in[17];
    const float* proj_b   = (const float*)d_in[18];
    const float* codebook = (const float*)d_in[19];
    const float* word_cb  = (const float*)d_in[20];
    const float* align_w  = (const float*)d_in[21];
    const float* align_b  = (const float*)d_in[22];
    const float* gru_wih0 = (const float*)d_in[23];
    const float* gru_whh0 = (const float*)d_in[24];
    const float* gru_bih0 = (const float*)d_in[25];
    const float* gru_bhh0 = (const float*)d_in[26];
    const float* gru_wih1 = (const float*)d_in[27];
    const float* gru_whh1 = (const float*)d_in[28];
    const float* gru_bih1 = (const float*)d_in[29];
    const float* gru_bhh1 = (const float*)d_in[30];
    const float* dec1_w   = (const float*)d_in[31];
    const float* dec1_b   = (const float*)d_in[32];
    const float* dec2_w   = (const float*)d_in[33];
    const float* dec2_b   = (const float*)d_in[34];
    const float* dec3_w   = (const float*)d_in[35];
    const float* dec3_b   = (const float*)d_in[36];
    const int*   tokens   = (const int*)d_in[37];

    float* wsf    = (float*)d_ws;
    float* out    = (float*)d_out;
    float* x1p    = wsf + OFF_X1P;
    float* x2p    = wsf + OFF_X2P;
    float* y2     = wsf + OFF_Y2;
    float* y3     = wsf + OFF_Y3;   // conv3 partial base (P0; P1 at +4,194,304)
    float* x3p    = wsf + OFF_X3P;
    float* y4     = wsf + OFF_Y4;
    float* x4     = wsf + OFF_X4;
    float* feat   = wsf + OFF_FEAT;
    float* quant  = wsf + OFF_QUANT;
    float* gi1    = wsf + OFF_GI1;
    float* gi2    = wsf + OFF_GI2;
    float* h1     = wsf + OFF_H1;
    float* h2     = wsf + OFF_H2;
    float* wemb   = wsf + OFF_WEMB;
    float* ctx    = wsf + OFF_CTX;
    float* hh1    = wsf + OFF_HH1;
    float* hh2    = wsf + OFF_HH2;
    float* logit  = wsf + OFF_LOG;
    float* pp     = wsf + OFF_PP;
    float* sc     = wsf + OFF_SC;
    float* sh     = wsf + OFF_SH;
    float* accP   = wsf + OFF_ACCP;
    float* commitA= wsf + OFF_COMMIT;
    float* ctxA   = wsf + OFF_CTXA;
    float* alignA = wsf + OFF_ALIGNA;

    // conv1 + bn1 + pool
    k_conv1_stats3<<<dim3(4, 4, 64), 256, 0, stream>>>(videos, conv1_w, conv1_b, accP);
    k_conv1_fin<<<4, 256, 0, stream>>>(accP, bn1_g, bn1_b, sc, sh);
    k_conv1_apply3<<<dim3(4, 4, 64), 256, 0, stream>>>(videos, conv1_w, conv1_b, sc, sh, x1p);
    // conv2 + bn2 + pool
    k_conv2<<<dim3(4, 4, 64), 256, 0, stream>>>(x1p, conv2_w, conv2_b, y2);
    k_bn_stats<<<dim3(16, 128), 256, 0, stream>>>(y2, bn2_g, bn2_b, sc, sh, 128, 1024);
    k_bn_apply_pool<<<8192, 256, 0, stream>>>(y2, sc, sh, x2p, 128, 32, 32);
    // conv3 (split-IC 2-way) + fused stats/apply over (P0+P1)+bias
    k_conv3p<<<dim3(8, 64, 2), 256, 0, stream>>>(x2p, conv3_w, y3);
    k_bn_stats3p<<<dim3(16, 256), 256, 0, stream>>>(y3, conv3_b, bn3_g, bn3_b, sc, sh);
    k_bn_apply_avgpool4p<<<1024, 256, 0, stream>>>(y3, conv3_b, sc, sh, x3p);
    k_tconv<<<1024, 256, 0, stream>>>(x3p, tconv_w, tconv_b, y4);
    k_bn_stats<<<dim3(16, 256), 256, 0, stream>>>(y4, bn4_g, bn4_b, sc, sh, 256, 16);
    k_bn_apply<<<1024, 256, 0, stream>>>(y4, sc, sh, x4);
    // projection (deterministic split-K GEMM, row permutation in fin)
    k_proj_part<<<dim3(8, 8), 256, 0, stream>>>(x4, proj_w, pp);
    k_proj_fin<<<128, 256, 0, stream>>>(pp, proj_b, feat);
    k_vq<<<64, 256, 0, stream>>>(feat, codebook, quant, commitA);
    // GRU pipeline with piggybacked tail (word_vq/align/ctx/dec1/dec2/dec3)
    k_gru_gi6<<<360, 256, 0, stream>>>(quant, gru_wih0, gru_bih0, gi1);
    for (int t = 0; t <= 16; ++t)
        k_gru_pipe<<<468, 256, 0, stream>>>(gi1, gru_whh0, gru_bhh0, h1,
                                            gru_wih1, gru_bih1, gi2,
                                            gru_whh1, gru_bhh1, h2,
                                            quant, word_cb, wemb, out,
                                            align_w, align_b, alignA, ctx,
                                            dec1_w, dec1_b, hh1,
                                            dec2_w, dec2_b, hh2,
                                            dec3_w, dec3_b, logit, t);
    k_ctx_loss<<<120, 256, 0, stream>>>(h2, feat, ctxA);
    k_final<<<1, 256, 0, stream>>>(logit, tokens, commitA, ctxA, alignA, out + 32);
}